// Round 12
// baseline (1857.440 us; speedup 1.0000x reference)
//
#include <hip/hip_runtime.h>
#include <hip/hip_bf16.h>
#include <math.h>

#define B_  4
#define S_  2048
#define D_  1024
#define R_  128
#define NC_ 64
#define NK_ 32768
#define SD_ 64
#define KK_ 8

typedef __attribute__((ext_vector_type(8))) short short8v;  // 8 bf16 (4 VGPRs)
typedef __attribute__((ext_vector_type(4))) float f32x4;

// ---------------- ws layout (float offsets) ----------------
static const size_t OFF_XB    = 0;         // [8192][64]
static const size_t OFF_TP    = 524288;    // [8192][64]
static const size_t OFF_APOW  = 1048576;   // [65][64][64]
static const size_t OFF_P     = 1314816;   // [32][4][64]
static const size_t OFF_HPROJ = 1323008;   // [4][1024]
static const size_t OFF_LOGIT = 1327104;   // [4][2048]
static const size_t OFF_IMP   = 1335296;   // [4][2048]
static const size_t OFF_NW    = 1343488;   // [4][64]
static const size_t OFF_SC    = 1343744;   // [4][1024][128]; dead after k_Q -> reused as pci[4][8192][8] int
static const size_t OFF_Q     = 0;         // [8192][128] aliases XB+TP (stream-ordered safe)
static const size_t OFF_TIDX  = 1868032;   // [8192][8] int
static const size_t OFF_TW    = 1933568;   // [8192][8]  -> 1999104
// MFMA path extras (bf16 split of K), only used when ws_size is large enough:
static const size_t OFF_KHI   = 1999104;   // [32768][128] ushort -> 2,097,152 floats
static const size_t OFF_KLO   = 4096256;   // [32768][128] ushort -> 2,097,152 floats
static const size_t WS_NEED_MFMA = (size_t)6193408 * 4;   // bytes

// -------- output layout (FLOAT32 offsets) --------
static const size_t O_OUT  = 0;
static const size_t O_IMP  = 8388608;
static const size_t O_NW   = 8396800;
static const size_t O_TIDX = 8397056;
static const size_t O_TW   = 8462592;

__device__ __forceinline__ ushort bf_bits(__hip_bfloat16 h){ return *reinterpret_cast<ushort*>(&h); }

// ============ Apow init ============
__global__ __launch_bounds__(256) void k_init_apow(const float* __restrict__ A, float* __restrict__ Apow){
  int t = blockIdx.x*256 + threadIdx.x;
  if (t < 4096){ int i = t>>6, j = t&63; Apow[t] = (i==j) ? 1.f : 0.f; }
  else Apow[t] = A[t-4096];
}

// ============ batched 64x64x64 matmul (f64 accumulate) ============
__global__ __launch_bounds__(256) void k_matstage(float* __restrict__ Apow, int dst0, int lhs, int rhs0){
  __shared__ float L[64][68];
  __shared__ float Rm[64][68];
  const float* Lp = Apow + (size_t)lhs*4096;
  const float* Rp = Apow + (size_t)(rhs0 + blockIdx.x)*4096;
  int t = threadIdx.x;
  #pragma unroll 1
  for (int p=0;p<4;p++){
    int f = p*256+t; int i = f>>4, jq = f&15;
    float4 v = ((const float4*)Lp)[f];
    L[i][jq*4+0]=v.x; L[i][jq*4+1]=v.y; L[i][jq*4+2]=v.z; L[i][jq*4+3]=v.w;
    float4 w = ((const float4*)Rp)[f];
    Rm[i][jq*4+0]=w.x; Rm[i][jq*4+1]=w.y; Rm[i][jq*4+2]=w.z; Rm[i][jq*4+3]=w.w;
  }
  __syncthreads();
  int j = t&63, rg = t>>6;
  double acc[16];
  #pragma unroll
  for (int ii=0;ii<16;ii++) acc[ii]=0.0;
  #pragma unroll 1
  for (int kk=0;kk<64;kk++){
    double rv = (double)Rm[kk][j];
    #pragma unroll
    for (int ii=0;ii<16;ii++) acc[ii] += (double)L[rg*16+ii][kk]*rv;
  }
  float* out = Apow + (size_t)(dst0 + blockIdx.x)*4096;
  #pragma unroll
  for (int ii=0;ii<16;ii++) out[(rg*16+ii)*64 + j] = (float)acc[ii];
}

// ============ xB + router logits GEMM (+ f64 row softmax -> token_pref) ============
__global__ __launch_bounds__(256) void k_xbr(const float* __restrict__ x, const float* __restrict__ Bm,
                                             const float* __restrict__ Wr,
                                             float* __restrict__ xB, float* __restrict__ tp){
  int row0 = blockIdx.x*64;
  __shared__ float Xt[64][36];
  __shared__ float Wt[32][132];
  __shared__ float SB[64][65];
  int t = threadIdx.x;
  int rg = t>>5, c = t&31;
  double accd[8][4];
  #pragma unroll
  for (int i=0;i<8;i++){
    #pragma unroll
    for (int j=0;j<4;j++) accd[i][j]=0.0;
  }
  #pragma unroll 1
  for (int kc=0;kc<32;kc++){
    int d0 = kc*32;
    #pragma unroll
    for (int p=0;p<2;p++){
      int f = p*256+t; int r = f>>3, dq = f&7;
      float4 v = *(const float4*)&x[(size_t)(row0+r)*1024 + d0 + dq*4];
      Xt[r][dq*4+0]=v.x; Xt[r][dq*4+1]=v.y; Xt[r][dq*4+2]=v.z; Xt[r][dq*4+3]=v.w;
    }
    #pragma unroll
    for (int p=0;p<2;p++){
      int f = p*256+t; int dd = f>>4, eq = f&15;
      float4 v = *(const float4*)&Bm[(size_t)(d0+dd)*64 + eq*4];
      Wt[dd][eq*4+0]=v.x; Wt[dd][eq*4+1]=v.y; Wt[dd][eq*4+2]=v.z; Wt[dd][eq*4+3]=v.w;
    }
    #pragma unroll
    for (int p=0;p<2;p++){
      int f = p*256+t; int n = f>>3, dq = f&7;
      float4 v = *(const float4*)&Wr[(size_t)n*1024 + d0 + dq*4];
      Wt[dq*4+0][64+n]=v.x; Wt[dq*4+1][64+n]=v.y; Wt[dq*4+2][64+n]=v.z; Wt[dq*4+3][64+n]=v.w;
    }
    __syncthreads();
    float accf[8][4];
    #pragma unroll
    for (int i=0;i<8;i++){
      #pragma unroll
      for (int j=0;j<4;j++) accf[i][j]=0.f;
    }
    #pragma unroll
    for (int k4=0;k4<8;k4++){
      float4 xv[8];
      #pragma unroll
      for (int i=0;i<8;i++) xv[i] = *(const float4*)&Xt[rg*8+i][k4*4];
      #pragma unroll
      for (int u=0;u<4;u++){
        int kk = k4*4+u;
        float wv[4];
        #pragma unroll
        for (int j=0;j<4;j++) wv[j] = Wt[kk][c+32*j];
        #pragma unroll
        for (int i=0;i<8;i++){
          float xs = (u==0)?xv[i].x:(u==1)?xv[i].y:(u==2)?xv[i].z:xv[i].w;
          #pragma unroll
          for (int j=0;j<4;j++) accf[i][j] += xs*wv[j];
        }
      }
    }
    #pragma unroll
    for (int i=0;i<8;i++){
      #pragma unroll
      for (int j=0;j<4;j++) accd[i][j] += (double)accf[i][j];
    }
    __syncthreads();
  }
  #pragma unroll
  for (int i=0;i<8;i++){
    int row = row0 + rg*8 + i;
    xB[(size_t)row*64 + c]      = (float)accd[i][0];
    xB[(size_t)row*64 + c + 32] = (float)accd[i][1];
    SB[rg*8+i][c]    = (float)accd[i][2];
    SB[rg*8+i][c+32] = (float)accd[i][3];
  }
  __syncthreads();
  if (t < 64){
    double m = -1.0e300;
    #pragma unroll 1
    for (int n=0;n<64;n++) m = fmax(m, (double)SB[t][n]);
    double s = 0.0;
    #pragma unroll 1
    for (int n=0;n<64;n++){ double e = exp((double)SB[t][n]-m); SB[t][n]=(float)e; s += e; }
    int row = row0 + t;
    #pragma unroll 1
    for (int n=0;n<64;n++) tp[(size_t)row*64 + n] = (float)((double)SB[t][n]/s);
  }
}

// ============ chunk partials (f64 accumulate) ============
__global__ __launch_bounds__(256) void k_P(const float* __restrict__ xB, const float* __restrict__ Apow,
                                           float* __restrict__ P){
  int cchunk = blockIdx.x; int t = threadIdx.x;
  int b = t>>6, e = t&63;
  double acc = 0.0;
  #pragma unroll 1
  for (int l=0;l<64;l++){
    const float* xr = &xB[((size_t)b*2048 + cchunk*64 + l)*64];
    const float* Ap = &Apow[(size_t)(63-l)*4096];
    #pragma unroll
    for (int k4=0;k4<16;k4++){
      float4 xv = *(const float4*)&xr[k4*4];
      acc += (double)xv.x*(double)Ap[(k4*4+0)*64+e];
      acc += (double)xv.y*(double)Ap[(k4*4+1)*64+e];
      acc += (double)xv.z*(double)Ap[(k4*4+2)*64+e];
      acc += (double)xv.w*(double)Ap[(k4*4+3)*64+e];
    }
  }
  P[cchunk*256 + t] = (float)acc;
}

// ============ Horner combine (f64) + h_proj ============
__global__ __launch_bounds__(256) void k_scan(const float* __restrict__ Apow, const float* __restrict__ P,
                                              const float* __restrict__ Wimp, float* __restrict__ hproj){
  __shared__ float A64s[64][68];
  __shared__ double h[2][4][64];
  int t = threadIdx.x;
  const float* A64 = Apow + (size_t)64*4096;
  #pragma unroll 1
  for (int p=0;p<4;p++){
    int f = p*256+t; int i = f>>4, jq = f&15;
    float4 v = *(const float4*)&A64[f*4];
    A64s[i][jq*4+0]=v.x; A64s[i][jq*4+1]=v.y; A64s[i][jq*4+2]=v.z; A64s[i][jq*4+3]=v.w;
  }
  int b = t>>6, e = t&63;
  h[0][b][e] = 0.0;
  __syncthreads();
  #pragma unroll 1
  for (int c=0;c<32;c++){
    int cur = c&1;
    double acc = (double)P[c*256 + t];
    #pragma unroll
    for (int k=0;k<64;k++) acc += h[cur][b][k]*(double)A64s[k][e];
    h[cur^1][b][e] = acc;
    __syncthreads();
  }
  #pragma unroll 1
  for (int m=0;m<16;m++){
    int o = t + 256*m; int bb = o>>10, d = o&1023;
    const float* wrow = &Wimp[(size_t)d*64];
    double acc = 0.0;
    #pragma unroll
    for (int e4=0;e4<16;e4++){
      float4 w = *(const float4*)&wrow[e4*4];
      acc += h[0][bb][e4*4+0]*(double)w.x;
      acc += h[0][bb][e4*4+1]*(double)w.y;
      acc += h[0][bb][e4*4+2]*(double)w.z;
      acc += h[0][bb][e4*4+3]*(double)w.w;
    }
    hproj[o] = (float)acc;
  }
}

// ============ importance logits (f64) ============
__global__ __launch_bounds__(256) void k_implogit(const float* __restrict__ x, const float* __restrict__ hproj,
                                                  float* __restrict__ logits){
  int row = blockIdx.x; int b = row>>11;
  int t = threadIdx.x;
  float4 xv = ((const float4*)x)[(size_t)row*256 + t];
  float4 hv = ((const float4*)hproj)[(size_t)b*256 + t];
  double p = (double)xv.x*(double)hv.x + (double)xv.y*(double)hv.y
           + (double)xv.z*(double)hv.z + (double)xv.w*(double)hv.w;
  #pragma unroll
  for (int off=32; off; off>>=1) p += __shfl_down(p, off);
  __shared__ double ws4[4];
  if ((t&63)==0) ws4[t>>6] = p;
  __syncthreads();
  if (t==0) logits[row] = (float)(ws4[0]+ws4[1]+ws4[2]+ws4[3]);
}

// ============ softmax over S per batch (f64) ============
__global__ __launch_bounds__(1024) void k_softS(const float* __restrict__ logits, float* __restrict__ imp,
                                                float* __restrict__ out1){
  int b = blockIdx.x; int t = threadIdx.x;
  double v0 = (double)logits[b*2048 + t];
  double v1 = (double)logits[b*2048 + 1024 + t];
  double m = fmax(v0,v1);
  #pragma unroll
  for (int off=32; off; off>>=1) m = fmax(m, __shfl_xor(m, off));
  __shared__ double red[16];
  if ((t&63)==0) red[t>>6] = m;
  __syncthreads();
  double M = red[0];
  #pragma unroll 1
  for (int i=1;i<16;i++) M = fmax(M, red[i]);
  double p0 = exp(v0-M), p1 = exp(v1-M);
  double s = p0+p1;
  #pragma unroll
  for (int off=32; off; off>>=1) s += __shfl_xor(s, off);
  __syncthreads();
  if ((t&63)==0) red[t>>6] = s;
  __syncthreads();
  double S = 0.0;
  #pragma unroll 1
  for (int i=0;i<16;i++) S += red[i];
  float i0 = (float)(p0/S), i1 = (float)(p1/S);
  imp[b*2048+t] = i0; imp[b*2048+1024+t] = i1;
  out1[b*2048+t] = i0; out1[b*2048+1024+t] = i1;
}

// ============ neuron_w (f64) ============
__global__ __launch_bounds__(256) void k_nw(const float* __restrict__ imp, const float* __restrict__ tp,
                                            float* __restrict__ nw, float* __restrict__ out2){
  int b = blockIdx.x; int t = threadIdx.x;
  int n = t&63, sg = t>>6;
  double acc = 0.0;
  #pragma unroll 1
  for (int s=sg; s<2048; s+=4)
    acc += (double)imp[b*2048+s]*(double)tp[((size_t)b*2048+s)*64 + n];
  __shared__ double part[4][64];
  part[sg][n] = acc;
  __syncthreads();
  if (t<64){
    double v = part[0][t]+part[1][t]+part[2][t]+part[3][t];
    double tot = v;
    #pragma unroll
    for (int off=32; off; off>>=1) tot += __shfl_xor(tot, off);
    float r = (float)(v/(tot + 1e-8));
    nw[b*64+t] = r; out2[b*64+t] = r;
  }
}

// ============ shared_compress (f64 accumulate) ============
__global__ __launch_bounds__(256) void k_sc(const float* __restrict__ nw, const float* __restrict__ comp,
                                            float* __restrict__ sc){
  __shared__ float w[256];
  int t = threadIdx.x;
  w[t] = nw[t];
  __syncthreads();
  size_t base = (size_t)blockIdx.x*1024 + t*4;
  double a[4][4];
  #pragma unroll
  for (int i=0;i<4;i++){
    #pragma unroll
    for (int j=0;j<4;j++) a[i][j]=0.0;
  }
  #pragma unroll 1
  for (int n=0;n<64;n++){
    float4 cv = *(const float4*)&comp[(size_t)n*131072 + base];
    double cx=cv.x, cy=cv.y, cz=cv.z, cw=cv.w;
    double w0=w[n], w1=w[64+n], w2=w[128+n], w3=w[192+n];
    a[0][0]+=w0*cx; a[0][1]+=w0*cy; a[0][2]+=w0*cz; a[0][3]+=w0*cw;
    a[1][0]+=w1*cx; a[1][1]+=w1*cy; a[1][2]+=w1*cz; a[1][3]+=w1*cw;
    a[2][0]+=w2*cx; a[2][1]+=w2*cy; a[2][2]+=w2*cz; a[2][3]+=w2*cw;
    a[3][0]+=w3*cx; a[3][1]+=w3*cy; a[3][2]+=w3*cz; a[3][3]+=w3*cw;
  }
  #pragma unroll
  for (int i=0;i<4;i++){
    float4 o; o.x=(float)a[i][0]; o.y=(float)a[i][1]; o.z=(float)a[i][2]; o.w=(float)a[i][3];
    *(float4*)&sc[(size_t)i*131072 + base] = o;
  }
}

// ============ Q = x @ sc[b] (f64 chunk accumulate) ============
__global__ __launch_bounds__(256) void k_Q(const float* __restrict__ x, const float* __restrict__ sc,
                                           float* __restrict__ Q){
  int bid = blockIdx.x;
  int b = bid>>5;
  int row0 = b*2048 + (bid&31)*64;
  __shared__ float Xt[64][36];
  __shared__ float Wt[32][132];
  int t = threadIdx.x; int rg = t>>5, c = t&31;
  double accd[8][4];
  #pragma unroll
  for (int i=0;i<8;i++){
    #pragma unroll
    for (int j=0;j<4;j++) accd[i][j]=0.0;
  }
  #pragma unroll 1
  for (int kc=0;kc<32;kc++){
    int d0 = kc*32;
    #pragma unroll
    for (int p=0;p<2;p++){
      int f = p*256+t; int r = f>>3, dq = f&7;
      float4 v = *(const float4*)&x[(size_t)(row0+r)*1024 + d0 + dq*4];
      Xt[r][dq*4+0]=v.x; Xt[r][dq*4+1]=v.y; Xt[r][dq*4+2]=v.z; Xt[r][dq*4+3]=v.w;
    }
    #pragma unroll
    for (int p=0;p<4;p++){
      int f = p*256+t; int dd = f>>5, nq = f&31;
      float4 v = *(const float4*)&sc[(size_t)b*131072 + (size_t)(d0+dd)*128 + nq*4];
      Wt[dd][nq*4+0]=v.x; Wt[dd][nq*4+1]=v.y; Wt[dd][nq*4+2]=v.z; Wt[dd][nq*4+3]=v.w;
    }
    __syncthreads();
    float accf[8][4];
    #pragma unroll
    for (int i=0;i<8;i++){
      #pragma unroll
      for (int j=0;j<4;j++) accf[i][j]=0.f;
    }
    #pragma unroll
    for (int k4=0;k4<8;k4++){
      float4 xv[8];
      #pragma unroll
      for (int i=0;i<8;i++) xv[i] = *(const float4*)&Xt[rg*8+i][k4*4];
      #pragma unroll
      for (int u=0;u<4;u++){
        int kk = k4*4+u;
        float wv[4];
        #pragma unroll
        for (int j=0;j<4;j++) wv[j] = Wt[kk][c+32*j];
        #pragma unroll
        for (int i=0;i<8;i++){
          float xs = (u==0)?xv[i].x:(u==1)?xv[i].y:(u==2)?xv[i].z:xv[i].w;
          #pragma unroll
          for (int j=0;j<4;j++) accf[i][j] += xs*wv[j];
        }
      }
    }
    #pragma unroll
    for (int i=0;i<8;i++){
      #pragma unroll
      for (int j=0;j<4;j++) accd[i][j] += (double)accf[i][j];
    }
    __syncthreads();
  }
  #pragma unroll
  for (int i=0;i<8;i++){
    #pragma unroll
    for (int j=0;j<4;j++)
      Q[(size_t)(row0+rg*8+i)*128 + c + 32*j] = (float)accd[i][j];
  }
}

// ============ K -> bf16 hi/lo split ============
__global__ __launch_bounds__(256) void k_split(const float* __restrict__ K, ushort* __restrict__ khi,
                                               ushort* __restrict__ klo){
  int i = blockIdx.x*256 + threadIdx.x;   // over 1,048,576 float4s
  float4 v = ((const float4*)K)[i];
  union { ushort u[4]; uint2 q; } ph, pl;
  float xs[4] = {v.x, v.y, v.z, v.w};
  #pragma unroll
  for (int e=0;e<4;e++){
    __hip_bfloat16 h = __float2bfloat16(xs[e]);
    float hf = __bfloat162float(h);
    __hip_bfloat16 l = __float2bfloat16(xs[e]-hf);
    ph.u[e] = bf_bits(h); pl.u[e] = bf_bits(l);
  }
  ((uint2*)khi)[i] = ph.q;
  ((uint2*)klo)[i] = pl.q;
}

// ============ scores via MFMA bf16x3, 256-thr blocks, 4 neuron-quarters ============
// 256 thr = 4 waves = 1 wave/SIMD per block -> 3 blocks/CU co-resident at ~136 total regs
// (launch_bounds min-waves=3 caps VGPR at 170; round-10 lesson: never cap below actual need).
__global__ __launch_bounds__(256,3) void k_scores_mfma(const float* __restrict__ Qm,
                                                       const ushort* __restrict__ khi,
                                                       const ushort* __restrict__ klo,
                                                       int* __restrict__ pci){
  __shared__ float smem[4224];          // 16,896 B: Qt[32][132]; reused after frag build as wcs/wci
  float* Qt  = smem;                    // [32][132]
  float* wcs = smem;                    // [4][32][8] floats (aliases Qt, dead by then)
  int*   wci = (int*)(smem + 1024);     // [4][32][8] ints
  const int t = threadIdx.x;
  const int rg = t>>6, c = t&63;        // wave 0..3, lane 0..63
  const int lrow = c&15, lk8 = c>>4;    // fragment row lane, k-group lane
  const int quarter = blockIdx.x & 3;   // neuron-quarter
  const int row0 = (blockIdx.x >> 2) * 32;
  #pragma unroll
  for (int p=0;p<4;p++){
    int f = p*256+t; int r = f>>5, rq = f&31;
    float4 v = *(const float4*)&Qm[(size_t)(row0+r)*128 + rq*4];
    *(float4*)&Qt[r*132 + rq*4] = v;
  }
  __syncthreads();
  // build Q fragments (bf16 hi/lo), 2 row-tiles x 4 k-chunks, all static
  short8v qhi[2][4], qlo[2][4];
  #pragma unroll
  for (int rt=0;rt<2;rt++){
    #pragma unroll
    for (int kc=0;kc<4;kc++){
      union { ushort u[8]; short8v v; } th, tl;
      #pragma unroll
      for (int e=0;e<8;e++){
        float xq = Qt[(rt*16+lrow)*132 + kc*32 + lk8*8 + e];
        __hip_bfloat16 h = __float2bfloat16(xq);
        float hf = __bfloat162float(h);
        __hip_bfloat16 l = __float2bfloat16(xq-hf);
        th.u[e] = bf_bits(h); tl.u[e] = bf_bits(l);
      }
      qhi[rt][kc] = th.v; qlo[rt][kc] = tl.v;
    }
  }
  __syncthreads();   // Qt dead; smem may now be reused as wcs/wci
  // per-thread top-6 for this thread's 8 fixed rows
  float ts8[8][6]; int ti8[8][6]; float thr8[8];
  #pragma unroll
  for (int s=0;s<8;s++){
    thr8[s] = -3.0e38f;
    #pragma unroll
    for (int q=0;q<6;q++){ ts8[s][q] = -3.0e38f; ti8[s][q] = 0x7fffffff; }
  }
  // ---- phase 1: barrier-free MFMA GEMM + in-register selection over this quarter's 16 chunks ----
  const int nt0 = quarter*16;
  #pragma unroll 1
  for (int nt=nt0; nt<nt0+16; nt++){
    const int nb = nt*512;
    #pragma unroll 1
    for (int cq=0;cq<8;cq++){
      const int ct = rg*8 + cq;                 // col-tile 0..31 within chunk (4 waves x 8)
      const int ncol = nb + ct*16 + lrow;       // this lane's K row (B col) = output column
      f32x4 acc0 = {0.f,0.f,0.f,0.f};
      f32x4 acc1 = {0.f,0.f,0.f,0.f};
      #pragma unroll
      for (int kc=0;kc<4;kc++){
        const size_t koff = (size_t)ncol*128 + kc*32 + lk8*8;
        short8v kh = *(const short8v*)&khi[koff];
        short8v kl = *(const short8v*)&klo[koff];
        acc0 = __builtin_amdgcn_mfma_f32_16x16x32_bf16(qhi[0][kc], kh, acc0, 0,0,0);
        acc1 = __builtin_amdgcn_mfma_f32_16x16x32_bf16(qhi[1][kc], kh, acc1, 0,0,0);
        acc0 = __builtin_amdgcn_mfma_f32_16x16x32_bf16(qlo[0][kc], kh, acc0, 0,0,0);
        acc1 = __builtin_amdgcn_mfma_f32_16x16x32_bf16(qlo[1][kc], kh, acc1, 0,0,0);
        acc0 = __builtin_amdgcn_mfma_f32_16x16x32_bf16(qhi[0][kc], kl, acc0, 0,0,0);
        acc1 = __builtin_amdgcn_mfma_f32_16x16x32_bf16(qhi[1][kc], kl, acc1, 0,0,0);
      }
      #pragma unroll
      for (int v=0;v<4;v++){
        float s0 = acc0[v];
        if (s0 > thr8[v]){
          float mn = ts8[v][0]; int mp = 0;
          #pragma unroll
          for (int k=1;k<6;k++){ bool lt = ts8[v][k] < mn; mn = lt ? ts8[v][k] : mn; mp = lt ? k : mp; }
          #pragma unroll
          for (int k=0;k<6;k++) if (k==mp){ ts8[v][k] = s0; ti8[v][k] = ncol; }
          float nm = ts8[v][0];
          #pragma unroll
          for (int k=1;k<6;k++) nm = fminf(nm, ts8[v][k]);
          thr8[v] = nm;
        }
        float s1 = acc1[v];
        if (s1 > thr8[4+v]){
          float mn = ts8[4+v][0]; int mp = 0;
          #pragma unroll
          for (int k=1;k<6;k++){ bool lt = ts8[4+v][k] < mn; mn = lt ? ts8[4+v][k] : mn; mp = lt ? k : mp; }
          #pragma unroll
          for (int k=0;k<6;k++) if (k==mp){ ts8[4+v][k] = s1; ti8[4+v][k] = ncol; }
          float nm = ts8[4+v][0];
          #pragma unroll
          for (int k=1;k<6;k++) nm = fminf(nm, ts8[4+v][k]);
          thr8[4+v] = nm;
        }
      }
    }
  }
  // ---- phase 2a: per-wave top-8 per row via 16-lane-group shuffles ----
  #pragma unroll
  for (int s=0;s<8;s++){
    const int rloc = (s<4) ? (lk8*4+s) : (16 + lk8*4 + (s-4));
    #pragma unroll 1
    for (int k=0;k<8;k++){
      float bs = ts8[s][0]; int bi = ti8[s][0];
      #pragma unroll
      for (int q=1;q<6;q++){
        bool bt = (ts8[s][q] > bs) || (ts8[s][q]==bs && ti8[s][q] < bi);
        bs = bt ? ts8[s][q] : bs; bi = bt ? ti8[s][q] : bi;
      }
      #pragma unroll
      for (int off=1; off<16; off<<=1){
        float os = __shfl_xor(bs, off, 16); int oi = __shfl_xor(bi, off, 16);
        bool bt = (os > bs) || (os==bs && oi < bi);
        bs = bt ? os : bs; bi = bt ? oi : bi;
      }
      #pragma unroll
      for (int q=0;q<6;q++){
        if (ti8[s][q]==bi){ ts8[s][q] = -3.0e38f; ti8[s][q] = 0x7fffffff; }
      }
      if (lrow==0){ wcs[(rg*32 + rloc)*8 + k] = bs; wci[(rg*32 + rloc)*8 + k] = bi; }
    }
  }
  __syncthreads();
  // ---- phase 2b: block top-8 per row (8 lanes/row merge 4 waves x 8 = 32 cands) ----
  const int mrow = t>>3;        // 0..31
  const int ml   = t&7;
  float cs4[4]; int ci4[4];
  #pragma unroll
  for (int j=0;j<4;j++){
    int idx = ml*4+j;           // 0..31
    cs4[j] = wcs[((idx>>3)*32 + mrow)*8 + (idx&7)];
    ci4[j] = wci[((idx>>3)*32 + mrow)*8 + (idx&7)];
  }
  const size_t pbase = ((size_t)quarter*8192 + row0 + mrow)*8;
  #pragma unroll 1
  for (int k=0;k<8;k++){
    float bs = cs4[0]; int bi = ci4[0];
    #pragma unroll
    for (int q=1;q<4;q++){
      bool bt = (cs4[q] > bs) || (cs4[q]==bs && ci4[q] < bi);
      bs = bt ? cs4[q] : bs; bi = bt ? ci4[q] : bi;
    }
    #pragma unroll
    for (int off=1; off<8; off<<=1){
      float os = __shfl_xor(bs, off, 8); int oi = __shfl_xor(bi, off, 8);
      bool bt = (os > bs) || (os==bs && oi < bi);
      bs = bt ? os : bs; bi = bt ? oi : bi;
    }
    #pragma unroll
    for (int q=0;q<4;q++){
      if (ci4[q]==bi){ cs4[q] = -3.0e38f; ci4[q] = 0x7fffffff; }
    }
    if (ml==k) pci[pbase + k] = bi;
  }
}

// ============ merge quarters: exact f64 rescore of 32 candidates/row -> top-8 + weights ============
__global__ __launch_bounds__(256) void k_merge(const float* __restrict__ Qm, const float* __restrict__ Km,
                                               const int* __restrict__ pci,
                                               float* __restrict__ tw, int* __restrict__ tidx,
                                               float* __restrict__ out3, float* __restrict__ out4){
  const int t = threadIdx.x;
  const int rloc = t>>5, ml = t&31;     // 8 rows/block, 32 candidate lanes/row
  const int row = blockIdx.x*8 + rloc;
  const int quarter = ml>>3;
  const int kidx = pci[((size_t)quarter*8192 + row)*8 + (ml&7)];
  const float* kr = Km + (size_t)kidx*128;
  const float* qrow = Qm + (size_t)row*128;
  double sd = 0.0;
  #pragma unroll 1
  for (int d4=0; d4<32; d4++){
    float4 kv = *(const float4*)&kr[d4*4];
    float4 qv = *(const float4*)&qrow[d4*4];
    sd += (double)qv.x*(double)kv.x;
    sd += (double)qv.y*(double)kv.y;
    sd += (double)qv.z*(double)kv.z;
    sd += (double)qv.w*(double)kv.w;
  }
  double cs = sd; int ci = kidx;
  double sel0,sel1,sel2,sel3,sel4,sel5,sel6,sel7;
  int is0,is1,is2,is3,is4,is5,is6,is7;
  #pragma unroll
  for (int k8=0;k8<8;k8++){
    double bs = cs; int bi = ci;
    #pragma unroll
    for (int off=1; off<32; off<<=1){
      double os = __shfl_xor(bs, off, 32); int oi = __shfl_xor(bi, off, 32);
      bool bt = (os > bs) || (os==bs && oi < bi);
      bs = bt ? os : bs; bi = bt ? oi : bi;
    }
    if (ci==bi) cs = -1.0e300;   // winner owner retires (duplicates impossible: quarters disjoint)
    if (k8==0){sel0=bs;is0=bi;} else if (k8==1){sel1=bs;is1=bi;}
    else if (k8==2){sel2=bs;is2=bi;} else if (k8==3){sel3=bs;is3=bi;}
    else if (k8==4){sel4=bs;is4=bi;} else if (k8==5){sel5=bs;is5=bi;}
    else if (k8==6){sel6=bs;is6=bi;} else {sel7=bs;is7=bi;}
  }
  if (ml==0){
    const double sc_inv = 0.08838834764831845;
    double mx = sel0;
    double e0 = exp((sel0-mx)*sc_inv), e1 = exp((sel1-mx)*sc_inv);
    double e2 = exp((sel2-mx)*sc_inv), e3 = exp((sel3-mx)*sc_inv);
    double e4 = exp((sel4-mx)*sc_inv), e5 = exp((sel5-mx)*sc_inv);
    double e6 = exp((sel6-mx)*sc_inv), e7 = exp((sel7-mx)*sc_inv);
    double sum = e0+e1+e2+e3+e4+e5+e6+e7;
    float w0=(float)(e0/sum),w1=(float)(e1/sum),w2=(float)(e2/sum),w3=(float)(e3/sum);
    float w4=(float)(e4/sum),w5=(float)(e5/sum),w6=(float)(e6/sum),w7=(float)(e7/sum);
    size_t o = (size_t)row*8;
    tw[o+0]=w0; tw[o+1]=w1; tw[o+2]=w2; tw[o+3]=w3;
    tw[o+4]=w4; tw[o+5]=w5; tw[o+6]=w6; tw[o+7]=w7;
    tidx[o+0]=is0; tidx[o+1]=is1; tidx[o+2]=is2; tidx[o+3]=is3;
    tidx[o+4]=is4; tidx[o+5]=is5; tidx[o+6]=is6; tidx[o+7]=is7;
    out4[o+0]=w0; out4[o+1]=w1; out4[o+2]=w2; out4[o+3]=w3;
    out4[o+4]=w4; out4[o+5]=w5; out4[o+6]=w6; out4[o+7]=w7;
    out3[o+0]=(float)is0; out3[o+1]=(float)is1;
    out3[o+2]=(float)is2; out3[o+3]=(float)is3;
    out3[o+4]=(float)is4; out3[o+5]=(float)is5;
    out3[o+6]=(float)is6; out3[o+7]=(float)is7;
  }
}

// ============ scores fallback (round-7 f32 path, used if ws too small) ============
__global__ __launch_bounds__(512) void k_scores(const float* __restrict__ Qm, const float* __restrict__ Km,
                                                float* __restrict__ tw, int* __restrict__ tidx,
                                                float* __restrict__ out3, float* __restrict__ out4){
  __shared__ float Qt[32][132];
  __shared__ float Kt[512][20];
  __shared__ int candI[8][4][16];
  const int t = threadIdx.x;
  const int rg = t>>6, c = t&63;
  const int row0 = blockIdx.x*32;
  #pragma unroll
  for (int p=0;p<2;p++){
    int f = p*512+t; int r = f>>5, rq = f&31;
    float4 v = *(const float4*)&Qm[(size_t)(row0+r)*128 + rq*4];
    *(float4*)&Qt[r][rq*4] = v;
  }
  float ts[4][8]; int ti[4][8]; float thr[4];
  #pragma unroll
  for (int i=0;i<4;i++){
    thr[i] = -3.0e38f;
    #pragma unroll
    for (int k=0;k<8;k++){ ts[i][k] = -3.0e38f; ti[i][k] = 0x7fffffff; }
  }
  __syncthreads();
  #pragma unroll 1
  for (int nt=0;nt<64;nt++){
    const int nb = nt*512;
    float acc[4][8];
    #pragma unroll
    for (int i=0;i<4;i++){
      #pragma unroll
      for (int j=0;j<8;j++) acc[i][j]=0.f;
    }
    #pragma unroll 1
    for (int rc=0;rc<8;rc++){
      #pragma unroll
      for (int p=0;p<4;p++){
        int f = p*512+t; int nn = f>>2, rq = f&3;
        float4 v = *(const float4*)&Km[(size_t)(nb+nn)*128 + rc*16 + rq*4];
        *(float4*)&Kt[nn][rq*4] = v;
      }
      __syncthreads();
      #pragma unroll
      for (int r4=0;r4<4;r4++){
        float4 qv[4]; float4 kv[8];
        #pragma unroll
        for (int i=0;i<4;i++) qv[i] = *(const float4*)&Qt[rg*4+i][rc*16+r4*4];
        #pragma unroll
        for (int j=0;j<8;j++) kv[j] = *(const float4*)&Kt[c+64*j][r4*4];
        #pragma unroll
        for (int i=0;i<4;i++){
          #pragma unroll
          for (int j=0;j<8;j++){
            acc[i][j] += qv[i].x*kv[j].x;
            acc[i][j] += qv[i].y*kv[j].y;
            acc[i][j] += qv[i].z*kv[j].z;
            acc[i][j] += qv[i].w*kv[j].w;
          }
        }
      }
      __syncthreads();
    }
    #pragma unroll
    for (int i=0;i<4;i++){
      #pragma unroll
      for (int j=0;j<8;j++){
        float s = acc[i][j];
        if (s > thr[i]){
          int n = nb + c + 64*j;
          float mn = ts[i][0]; int mp = 0;
          #pragma unroll
          for (int k=1;k<8;k++){ bool lt = ts[i][k] < mn; mn = lt ? ts[i][k] : mn; mp = lt ? k : mp; }
          #pragma unroll
          for (int k=0;k<8;k++) if (k==mp){ ts[i][k] = s; ti[i][k] = n; }
          float nm = ts[i][0];
          #pragma unroll
          for (int k=1;k<8;k++) nm = fminf(nm, ts[i][k]);
          thr[i] = nm;
        }
      }
    }
  }
  #pragma unroll
  for (int i=0;i<4;i++){
    #pragma unroll 1
    for (int k=0;k<16;k++){
      float bs = ts[i][0]; int bi = ti[i][0];
      #pragma unroll
      for (int q=1;q<8;q++){
        bool bt = (ts[i][q] > bs) || (ts[i][q]==bs && ti[i][q] < bi);
        bs = bt ? ts[i][q] : bs; bi = bt ? ti[i][q] : bi;
      }
      #pragma unroll
      for (int off=1; off<64; off<<=1){
        float os = __shfl_xor(bs, off); int oi = __shfl_xor(bi, off);
        bool bt = (os > bs) || (os==bs && oi < bi);
        bs = bt ? os : bs; bi = bt ? oi : bi;
      }
      #pragma unroll
      for (int q=0;q<8;q++){
        if (ti[i][q]==bi){ ts[i][q] = -3.0e38f; ti[i][q] = 0x7fffffff; }
      }
      if (c==0) candI[rg][i][k] = bi;
    }
  }
  __syncthreads();
  const int ri = c>>4, rk = c&15;
  const int kidx = candI[rg][ri][rk];
  const float* kr = Km + (size_t)kidx*128;
  const float* qrow = &Qt[rg*4+ri][0];
  double sd = 0.0;
  #pragma unroll 1
  for (int d4=0; d4<32; d4++){
    float4 kv = *(const float4*)&kr[d4*4];
    sd += (double)qrow[d4*4+0]*(double)kv.x;
    sd += (double)qrow[d4*4+1]*(double)kv.y;
    sd += (double)qrow[d4*4+2]*(double)kv.z;
    sd += (double)qrow[d4*4+3]*(double)kv.w;
  }
  double cs = sd; int ci = kidx;
  double sel0,sel1,sel2,sel3,sel4,sel5,sel6,sel7;
  int is0,is1,is2,is3,is4,is5,is6,is7;
  #pragma unroll
  for (int k8=0;k8<8;k8++){
    double bs = cs; int bi = ci;
    #pragma unroll
    for (int off=1; off<16; off<<=1){
      double os = __shfl_xor(bs, off, 16); int oi = __shfl_xor(bi, off, 16);
      bool bt = (os > bs) || (os==bs && oi < bi);
      bs = bt ? os : bs; bi = bt ? oi : bi;
    }
    if (ci==bi) cs = -1.0e300;
    if (k8==0){sel0=bs;is0=bi;} else if (k8==1){sel1=bs;is1=bi;}
    else if (k8==2){sel2=bs;is2=bi;} else if (k8==3){sel3=bs;is3=bi;}
    else if (k8==4){sel4=bs;is4=bi;} else if (k8==5){sel5=bs;is5=bi;}
    else if (k8==6){sel6=bs;is6=bi;} else {sel7=bs;is7=bi;}
  }
  if (rk==0){
    int grow = row0 + rg*4 + ri;
    const double sc_inv = 0.08838834764831845;
    double mx = sel0;
    double e0 = exp((sel0-mx)*sc_inv), e1 = exp((sel1-mx)*sc_inv);
    double e2 = exp((sel2-mx)*sc_inv), e3 = exp((sel3-mx)*sc_inv);
    double e4 = exp((sel4-mx)*sc_inv), e5 = exp((sel5-mx)*sc_inv);
    double e6 = exp((sel6-mx)*sc_inv), e7 = exp((sel7-mx)*sc_inv);
    double sum = e0+e1+e2+e3+e4+e5+e6+e7;
    float w0=(float)(e0/sum),w1=(float)(e1/sum),w2=(float)(e2/sum),w3=(float)(e3/sum);
    float w4=(float)(e4/sum),w5=(float)(e5/sum),w6=(float)(e6/sum),w7=(float)(e7/sum);
    size_t o = (size_t)grow*8;
    tw[o+0]=w0; tw[o+1]=w1; tw[o+2]=w2; tw[o+3]=w3;
    tw[o+4]=w4; tw[o+5]=w5; tw[o+6]=w6; tw[o+7]=w7;
    tidx[o+0]=is0; tidx[o+1]=is1; tidx[o+2]=is2; tidx[o+3]=is3;
    tidx[o+4]=is4; tidx[o+5]=is5; tidx[o+6]=is6; tidx[o+7]=is7;
    out4[o+0]=w0; out4[o+1]=w1; out4[o+2]=w2; out4[o+3]=w3;
    out4[o+4]=w4; out4[o+5]=w5; out4[o+6]=w6; out4[o+7]=w7;
    out3[o+0]=(float)is0; out3[o+1]=(float)is1;
    out3[o+2]=(float)is2; out3[o+3]=(float)is3;
    out3[o+4]=(float)is4; out3[o+5]=(float)is5;
    out3[o+6]=(float)is6; out3[o+7]=(float)is7;
  }
}

// ============ gather + weighted sum -> output (float32) ============
__global__ __launch_bounds__(256) void k_gather(const float* __restrict__ V, const int* __restrict__ tidx,
                                                const float* __restrict__ tw, float* __restrict__ out0){
  int row = blockIdx.x; int t = threadIdx.x;
  __shared__ int li[8]; __shared__ float lw[8];
  if (t<8){
    int idx = tidx[(size_t)row*8+t];
    idx = idx < 0 ? 0 : (idx > (NK_-1) ? (NK_-1) : idx);
    li[t] = idx;
  } else if (t<16){
    float w = tw[(size_t)row*8 + t-8];
    w = fminf(fmaxf(w, 0.f), 1.f);
    lw[t-8] = w;
  }
  __syncthreads();
  float4 a = {0,0,0,0};
  #pragma unroll
  for (int k=0;k<8;k++){
    float4 v = ((const float4*)V)[(size_t)li[k]*256 + t];
    float w = lw[k];
    a.x += w*v.x; a.y += w*v.y; a.z += w*v.z; a.w += w*v.w;
  }
  ((float4*)(out0 + (size_t)row*1024))[t] = a;
}

extern "C" void kernel_launch(void* const* d_in, const int* in_sizes, int n_in,
                              void* d_out, int out_size, void* d_ws, size_t ws_size,
                              hipStream_t stream) {
  const float* x    = (const float*)d_in[0];
  const float* A    = (const float*)d_in[1];
  const float* Bm   = (const float*)d_in[2];
  const float* Wimp = (const float*)d_in[3];
  const float* Wr   = (const float*)d_in[4];
  const float* comp = (const float*)d_in[5];
  const float* Kmat = (const float*)d_in[6];
  const float* V    = (const float*)d_in[7];
  float* out = (float*)d_out;               // OUTPUT IS FLOAT32
  float* ws = (float*)d_ws;

  float* xB    = ws + OFF_XB;
  float* tp    = ws + OFF_TP;
  float* Apow  = ws + OFF_APOW;
  float* P     = ws + OFF_P;
  float* hproj = ws + OFF_HPROJ;
  float* logit = ws + OFF_LOGIT;
  float* imp   = ws + OFF_IMP;
  float* nw    = ws + OFF_NW;
  float* scb   = ws + OFF_SC;
  float* Qb    = ws + OFF_Q;        // aliases xB+tp (both dead by the time k_Q runs)
  int*   pci   = (int*)(ws + OFF_SC);   // reuses scb region (dead after k_Q); [4][8192][8] int
  int*   tidx  = (int*)(ws + OFF_TIDX);
  float* tw    = ws + OFF_TW;
  ushort* khi  = (ushort*)(ws + OFF_KHI);
  ushort* klo  = (ushort*)(ws + OFF_KLO);

  const bool use_mfma = (ws_size >= WS_NEED_MFMA);

  k_init_apow<<<32,256,0,stream>>>(A, Apow);
  if (use_mfma) k_split<<<4096,256,0,stream>>>(Kmat, khi, klo);
  k_matstage<<<1 ,256,0,stream>>>(Apow, 2 ,1 ,1);
  k_matstage<<<2 ,256,0,stream>>>(Apow, 3 ,2 ,1);
  k_matstage<<<4 ,256,0,stream>>>(Apow, 5 ,4 ,1);
  k_matstage<<<8 ,256,0,stream>>>(Apow, 9 ,8 ,1);
  k_matstage<<<16,256,0,stream>>>(Apow, 17,16,1);
  k_matstage<<<32,256,0,stream>>>(Apow, 33,32,1);
  k_xbr<<<128,256,0,stream>>>(x, Bm, Wr, xB, tp);
  k_P<<<32,256,0,stream>>>(xB, Apow, P);
  k_scan<<<1,256,0,stream>>>(Apow, P, Wimp, hproj);
  k_implogit<<<8192,256,0,stream>>>(x, hproj, logit);
  k_softS<<<4,1024,0,stream>>>(logit, imp, out + O_IMP);
  k_nw<<<4,256,0,stream>>>(imp, tp, nw, out + O_NW);
  k_sc<<<128,256,0,stream>>>(nw, comp, scb);
  k_Q<<<128,256,0,stream>>>(x, scb, Qb);
  if (use_mfma){
    k_scores_mfma<<<1024,256,0,stream>>>(Qb, khi, klo, pci);
    k_merge<<<1024,256,0,stream>>>(Qb, Kmat, pci, tw, tidx, out + O_TIDX, out + O_TW);
  } else {
    k_scores<<<256,512,0,stream>>>(Qb, Kmat, tw, tidx, out + O_TIDX, out + O_TW);
  }
  k_gather<<<8192,256,0,stream>>>(V, tidx, tw, out + O_OUT);
}

// Round 13
// 1187.788 us; speedup vs baseline: 1.5638x; 1.5638x over previous
//
#include <hip/hip_runtime.h>
#include <hip/hip_bf16.h>
#include <math.h>

#define B_  4
#define S_  2048
#define D_  1024
#define R_  128
#define NC_ 64
#define NK_ 32768
#define SD_ 64
#define KK_ 8

typedef __attribute__((ext_vector_type(8))) short short8v;  // 8 bf16 (4 VGPRs)
typedef __attribute__((ext_vector_type(4))) float f32x4;

// ---------------- ws layout (float offsets) ----------------
static const size_t OFF_XB    = 0;         // [8192][64]
static const size_t OFF_TP    = 524288;    // [8192][64]
static const size_t OFF_APOW  = 1048576;   // [65][64][64]
static const size_t OFF_P     = 1314816;   // [32][4][64]
static const size_t OFF_HPROJ = 1323008;   // [4][1024]
static const size_t OFF_LOGIT = 1327104;   // [4][2048]
static const size_t OFF_IMP   = 1335296;   // [4][2048]
static const size_t OFF_NW    = 1343488;   // [4][64]
static const size_t OFF_SC    = 1343744;   // [4][1024][128]
static const size_t OFF_Q     = 0;         // [8192][128] aliases XB+TP (stream-ordered safe)
static const size_t OFF_TIDX  = 1868032;   // [8192][8] int
static const size_t OFF_TW    = 1933568;   // [8192][8]  -> 1999104
// MFMA path extras (bf16 split of K), only used when ws_size is large enough:
static const size_t OFF_KHI   = 1999104;   // [32768][128] ushort -> 2,097,152 floats
static const size_t OFF_KLO   = 4096256;   // [32768][128] ushort -> 2,097,152 floats
static const size_t WS_NEED_MFMA = (size_t)6193408 * 4;   // bytes

// -------- output layout (FLOAT32 offsets) --------
static const size_t O_OUT  = 0;
static const size_t O_IMP  = 8388608;
static const size_t O_NW   = 8396800;
static const size_t O_TIDX = 8397056;
static const size_t O_TW   = 8462592;

__device__ __forceinline__ ushort bf_bits(__hip_bfloat16 h){ return *reinterpret_cast<ushort*>(&h); }

// ============ Apow init ============
__global__ __launch_bounds__(256) void k_init_apow(const float* __restrict__ A, float* __restrict__ Apow){
  int t = blockIdx.x*256 + threadIdx.x;
  if (t < 4096){ int i = t>>6, j = t&63; Apow[t] = (i==j) ? 1.f : 0.f; }
  else Apow[t] = A[t-4096];
}

// ============ batched 64x64x64 matmul (f64 accumulate) ============
__global__ __launch_bounds__(256) void k_matstage(float* __restrict__ Apow, int dst0, int lhs, int rhs0){
  __shared__ float L[64][68];
  __shared__ float Rm[64][68];
  const float* Lp = Apow + (size_t)lhs*4096;
  const float* Rp = Apow + (size_t)(rhs0 + blockIdx.x)*4096;
  int t = threadIdx.x;
  #pragma unroll 1
  for (int p=0;p<4;p++){
    int f = p*256+t; int i = f>>4, jq = f&15;
    float4 v = ((const float4*)Lp)[f];
    L[i][jq*4+0]=v.x; L[i][jq*4+1]=v.y; L[i][jq*4+2]=v.z; L[i][jq*4+3]=v.w;
    float4 w = ((const float4*)Rp)[f];
    Rm[i][jq*4+0]=w.x; Rm[i][jq*4+1]=w.y; Rm[i][jq*4+2]=w.z; Rm[i][jq*4+3]=w.w;
  }
  __syncthreads();
  int j = t&63, rg = t>>6;
  double acc[16];
  #pragma unroll
  for (int ii=0;ii<16;ii++) acc[ii]=0.0;
  #pragma unroll 1
  for (int kk=0;kk<64;kk++){
    double rv = (double)Rm[kk][j];
    #pragma unroll
    for (int ii=0;ii<16;ii++) acc[ii] += (double)L[rg*16+ii][kk]*rv;
  }
  float* out = Apow + (size_t)(dst0 + blockIdx.x)*4096;
  #pragma unroll
  for (int ii=0;ii<16;ii++) out[(rg*16+ii)*64 + j] = (float)acc[ii];
}

// ============ xB + router logits GEMM (+ f64 row softmax -> token_pref) ============
__global__ __launch_bounds__(256) void k_xbr(const float* __restrict__ x, const float* __restrict__ Bm,
                                             const float* __restrict__ Wr,
                                             float* __restrict__ xB, float* __restrict__ tp){
  int row0 = blockIdx.x*64;
  __shared__ float Xt[64][36];
  __shared__ float Wt[32][132];
  __shared__ float SB[64][65];
  int t = threadIdx.x;
  int rg = t>>5, c = t&31;
  double accd[8][4];
  #pragma unroll
  for (int i=0;i<8;i++){
    #pragma unroll
    for (int j=0;j<4;j++) accd[i][j]=0.0;
  }
  #pragma unroll 1
  for (int kc=0;kc<32;kc++){
    int d0 = kc*32;
    #pragma unroll
    for (int p=0;p<2;p++){
      int f = p*256+t; int r = f>>3, dq = f&7;
      float4 v = *(const float4*)&x[(size_t)(row0+r)*1024 + d0 + dq*4];
      Xt[r][dq*4+0]=v.x; Xt[r][dq*4+1]=v.y; Xt[r][dq*4+2]=v.z; Xt[r][dq*4+3]=v.w;
    }
    #pragma unroll
    for (int p=0;p<2;p++){
      int f = p*256+t; int dd = f>>4, eq = f&15;
      float4 v = *(const float4*)&Bm[(size_t)(d0+dd)*64 + eq*4];
      Wt[dd][eq*4+0]=v.x; Wt[dd][eq*4+1]=v.y; Wt[dd][eq*4+2]=v.z; Wt[dd][eq*4+3]=v.w;
    }
    #pragma unroll
    for (int p=0;p<2;p++){
      int f = p*256+t; int n = f>>3, dq = f&7;
      float4 v = *(const float4*)&Wr[(size_t)n*1024 + d0 + dq*4];
      Wt[dq*4+0][64+n]=v.x; Wt[dq*4+1][64+n]=v.y; Wt[dq*4+2][64+n]=v.z; Wt[dq*4+3][64+n]=v.w;
    }
    __syncthreads();
    float accf[8][4];
    #pragma unroll
    for (int i=0;i<8;i++){
      #pragma unroll
      for (int j=0;j<4;j++) accf[i][j]=0.f;
    }
    #pragma unroll
    for (int k4=0;k4<8;k4++){
      float4 xv[8];
      #pragma unroll
      for (int i=0;i<8;i++) xv[i] = *(const float4*)&Xt[rg*8+i][k4*4];
      #pragma unroll
      for (int u=0;u<4;u++){
        int kk = k4*4+u;
        float wv[4];
        #pragma unroll
        for (int j=0;j<4;j++) wv[j] = Wt[kk][c+32*j];
        #pragma unroll
        for (int i=0;i<8;i++){
          float xs = (u==0)?xv[i].x:(u==1)?xv[i].y:(u==2)?xv[i].z:xv[i].w;
          #pragma unroll
          for (int j=0;j<4;j++) accf[i][j] += xs*wv[j];
        }
      }
    }
    #pragma unroll
    for (int i=0;i<8;i++){
      #pragma unroll
      for (int j=0;j<4;j++) accd[i][j] += (double)accf[i][j];
    }
    __syncthreads();
  }
  #pragma unroll
  for (int i=0;i<8;i++){
    int row = row0 + rg*8 + i;
    xB[(size_t)row*64 + c]      = (float)accd[i][0];
    xB[(size_t)row*64 + c + 32] = (float)accd[i][1];
    SB[rg*8+i][c]    = (float)accd[i][2];
    SB[rg*8+i][c+32] = (float)accd[i][3];
  }
  __syncthreads();
  if (t < 64){
    double m = -1.0e300;
    #pragma unroll 1
    for (int n=0;n<64;n++) m = fmax(m, (double)SB[t][n]);
    double s = 0.0;
    #pragma unroll 1
    for (int n=0;n<64;n++){ double e = exp((double)SB[t][n]-m); SB[t][n]=(float)e; s += e; }
    int row = row0 + t;
    #pragma unroll 1
    for (int n=0;n<64;n++) tp[(size_t)row*64 + n] = (float)((double)SB[t][n]/s);
  }
}

// ============ chunk partials (f64 accumulate) ============
__global__ __launch_bounds__(256) void k_P(const float* __restrict__ xB, const float* __restrict__ Apow,
                                           float* __restrict__ P){
  int cchunk = blockIdx.x; int t = threadIdx.x;
  int b = t>>6, e = t&63;
  double acc = 0.0;
  #pragma unroll 1
  for (int l=0;l<64;l++){
    const float* xr = &xB[((size_t)b*2048 + cchunk*64 + l)*64];
    const float* Ap = &Apow[(size_t)(63-l)*4096];
    #pragma unroll
    for (int k4=0;k4<16;k4++){
      float4 xv = *(const float4*)&xr[k4*4];
      acc += (double)xv.x*(double)Ap[(k4*4+0)*64+e];
      acc += (double)xv.y*(double)Ap[(k4*4+1)*64+e];
      acc += (double)xv.z*(double)Ap[(k4*4+2)*64+e];
      acc += (double)xv.w*(double)Ap[(k4*4+3)*64+e];
    }
  }
  P[cchunk*256 + t] = (float)acc;
}

// ============ Horner combine (f64) + h_proj ============
__global__ __launch_bounds__(256) void k_scan(const float* __restrict__ Apow, const float* __restrict__ P,
                                              const float* __restrict__ Wimp, float* __restrict__ hproj){
  __shared__ float A64s[64][68];
  __shared__ double h[2][4][64];
  int t = threadIdx.x;
  const float* A64 = Apow + (size_t)64*4096;
  #pragma unroll 1
  for (int p=0;p<4;p++){
    int f = p*256+t; int i = f>>4, jq = f&15;
    float4 v = *(const float4*)&A64[f*4];
    A64s[i][jq*4+0]=v.x; A64s[i][jq*4+1]=v.y; A64s[i][jq*4+2]=v.z; A64s[i][jq*4+3]=v.w;
  }
  int b = t>>6, e = t&63;
  h[0][b][e] = 0.0;
  __syncthreads();
  #pragma unroll 1
  for (int c=0;c<32;c++){
    int cur = c&1;
    double acc = (double)P[c*256 + t];
    #pragma unroll
    for (int k=0;k<64;k++) acc += h[cur][b][k]*(double)A64s[k][e];
    h[cur^1][b][e] = acc;
    __syncthreads();
  }
  #pragma unroll 1
  for (int m=0;m<16;m++){
    int o = t + 256*m; int bb = o>>10, d = o&1023;
    const float* wrow = &Wimp[(size_t)d*64];
    double acc = 0.0;
    #pragma unroll
    for (int e4=0;e4<16;e4++){
      float4 w = *(const float4*)&wrow[e4*4];
      acc += h[0][bb][e4*4+0]*(double)w.x;
      acc += h[0][bb][e4*4+1]*(double)w.y;
      acc += h[0][bb][e4*4+2]*(double)w.z;
      acc += h[0][bb][e4*4+3]*(double)w.w;
    }
    hproj[o] = (float)acc;
  }
}

// ============ importance logits (f64) ============
__global__ __launch_bounds__(256) void k_implogit(const float* __restrict__ x, const float* __restrict__ hproj,
                                                  float* __restrict__ logits){
  int row = blockIdx.x; int b = row>>11;
  int t = threadIdx.x;
  float4 xv = ((const float4*)x)[(size_t)row*256 + t];
  float4 hv = ((const float4*)hproj)[(size_t)b*256 + t];
  double p = (double)xv.x*(double)hv.x + (double)xv.y*(double)hv.y
           + (double)xv.z*(double)hv.z + (double)xv.w*(double)hv.w;
  #pragma unroll
  for (int off=32; off; off>>=1) p += __shfl_down(p, off);
  __shared__ double ws4[4];
  if ((t&63)==0) ws4[t>>6] = p;
  __syncthreads();
  if (t==0) logits[row] = (float)(ws4[0]+ws4[1]+ws4[2]+ws4[3]);
}

// ============ softmax over S per batch (f64) ============
__global__ __launch_bounds__(1024) void k_softS(const float* __restrict__ logits, float* __restrict__ imp,
                                                float* __restrict__ out1){
  int b = blockIdx.x; int t = threadIdx.x;
  double v0 = (double)logits[b*2048 + t];
  double v1 = (double)logits[b*2048 + 1024 + t];
  double m = fmax(v0,v1);
  #pragma unroll
  for (int off=32; off; off>>=1) m = fmax(m, __shfl_xor(m, off));
  __shared__ double red[16];
  if ((t&63)==0) red[t>>6] = m;
  __syncthreads();
  double M = red[0];
  #pragma unroll 1
  for (int i=1;i<16;i++) M = fmax(M, red[i]);
  double p0 = exp(v0-M), p1 = exp(v1-M);
  double s = p0+p1;
  #pragma unroll
  for (int off=32; off; off>>=1) s += __shfl_xor(s, off);
  __syncthreads();
  if ((t&63)==0) red[t>>6] = s;
  __syncthreads();
  double S = 0.0;
  #pragma unroll 1
  for (int i=0;i<16;i++) S += red[i];
  float i0 = (float)(p0/S), i1 = (float)(p1/S);
  imp[b*2048+t] = i0; imp[b*2048+1024+t] = i1;
  out1[b*2048+t] = i0; out1[b*2048+1024+t] = i1;
}

// ============ neuron_w (f64) ============
__global__ __launch_bounds__(256) void k_nw(const float* __restrict__ imp, const float* __restrict__ tp,
                                            float* __restrict__ nw, float* __restrict__ out2){
  int b = blockIdx.x; int t = threadIdx.x;
  int n = t&63, sg = t>>6;
  double acc = 0.0;
  #pragma unroll 1
  for (int s=sg; s<2048; s+=4)
    acc += (double)imp[b*2048+s]*(double)tp[((size_t)b*2048+s)*64 + n];
  __shared__ double part[4][64];
  part[sg][n] = acc;
  __syncthreads();
  if (t<64){
    double v = part[0][t]+part[1][t]+part[2][t]+part[3][t];
    double tot = v;
    #pragma unroll
    for (int off=32; off; off>>=1) tot += __shfl_xor(tot, off);
    float r = (float)(v/(tot + 1e-8));
    nw[b*64+t] = r; out2[b*64+t] = r;
  }
}

// ============ shared_compress (f64 accumulate) ============
__global__ __launch_bounds__(256) void k_sc(const float* __restrict__ nw, const float* __restrict__ comp,
                                            float* __restrict__ sc){
  __shared__ float w[256];
  int t = threadIdx.x;
  w[t] = nw[t];
  __syncthreads();
  size_t base = (size_t)blockIdx.x*1024 + t*4;
  double a[4][4];
  #pragma unroll
  for (int i=0;i<4;i++){
    #pragma unroll
    for (int j=0;j<4;j++) a[i][j]=0.0;
  }
  #pragma unroll 1
  for (int n=0;n<64;n++){
    float4 cv = *(const float4*)&comp[(size_t)n*131072 + base];
    double cx=cv.x, cy=cv.y, cz=cv.z, cw=cv.w;
    double w0=w[n], w1=w[64+n], w2=w[128+n], w3=w[192+n];
    a[0][0]+=w0*cx; a[0][1]+=w0*cy; a[0][2]+=w0*cz; a[0][3]+=w0*cw;
    a[1][0]+=w1*cx; a[1][1]+=w1*cy; a[1][2]+=w1*cz; a[1][3]+=w1*cw;
    a[2][0]+=w2*cx; a[2][1]+=w2*cy; a[2][2]+=w2*cz; a[2][3]+=w2*cw;
    a[3][0]+=w3*cx; a[3][1]+=w3*cy; a[3][2]+=w3*cz; a[3][3]+=w3*cw;
  }
  #pragma unroll
  for (int i=0;i<4;i++){
    float4 o; o.x=(float)a[i][0]; o.y=(float)a[i][1]; o.z=(float)a[i][2]; o.w=(float)a[i][3];
    *(float4*)&sc[(size_t)i*131072 + base] = o;
  }
}

// ============ Q = x @ sc[b] (f64 chunk accumulate) ============
__global__ __launch_bounds__(256) void k_Q(const float* __restrict__ x, const float* __restrict__ sc,
                                           float* __restrict__ Q){
  int bid = blockIdx.x;
  int b = bid>>5;
  int row0 = b*2048 + (bid&31)*64;
  __shared__ float Xt[64][36];
  __shared__ float Wt[32][132];
  int t = threadIdx.x; int rg = t>>5, c = t&31;
  double accd[8][4];
  #pragma unroll
  for (int i=0;i<8;i++){
    #pragma unroll
    for (int j=0;j<4;j++) accd[i][j]=0.0;
  }
  #pragma unroll 1
  for (int kc=0;kc<32;kc++){
    int d0 = kc*32;
    #pragma unroll
    for (int p=0;p<2;p++){
      int f = p*256+t; int r = f>>3, dq = f&7;
      float4 v = *(const float4*)&x[(size_t)(row0+r)*1024 + d0 + dq*4];
      Xt[r][dq*4+0]=v.x; Xt[r][dq*4+1]=v.y; Xt[r][dq*4+2]=v.z; Xt[r][dq*4+3]=v.w;
    }
    #pragma unroll
    for (int p=0;p<4;p++){
      int f = p*256+t; int dd = f>>5, nq = f&31;
      float4 v = *(const float4*)&sc[(size_t)b*131072 + (size_t)(d0+dd)*128 + nq*4];
      Wt[dd][nq*4+0]=v.x; Wt[dd][nq*4+1]=v.y; Wt[dd][nq*4+2]=v.z; Wt[dd][nq*4+3]=v.w;
    }
    __syncthreads();
    float accf[8][4];
    #pragma unroll
    for (int i=0;i<8;i++){
      #pragma unroll
      for (int j=0;j<4;j++) accf[i][j]=0.f;
    }
    #pragma unroll
    for (int k4=0;k4<8;k4++){
      float4 xv[8];
      #pragma unroll
      for (int i=0;i<8;i++) xv[i] = *(const float4*)&Xt[rg*8+i][k4*4];
      #pragma unroll
      for (int u=0;u<4;u++){
        int kk = k4*4+u;
        float wv[4];
        #pragma unroll
        for (int j=0;j<4;j++) wv[j] = Wt[kk][c+32*j];
        #pragma unroll
        for (int i=0;i<8;i++){
          float xs = (u==0)?xv[i].x:(u==1)?xv[i].y:(u==2)?xv[i].z:xv[i].w;
          #pragma unroll
          for (int j=0;j<4;j++) accf[i][j] += xs*wv[j];
        }
      }
    }
    #pragma unroll
    for (int i=0;i<8;i++){
      #pragma unroll
      for (int j=0;j<4;j++) accd[i][j] += (double)accf[i][j];
    }
    __syncthreads();
  }
  #pragma unroll
  for (int i=0;i<8;i++){
    #pragma unroll
    for (int j=0;j<4;j++)
      Q[(size_t)(row0+rg*8+i)*128 + c + 32*j] = (float)accd[i][j];
  }
}

// ============ K -> bf16 hi/lo split ============
__global__ __launch_bounds__(256) void k_split(const float* __restrict__ K, ushort* __restrict__ khi,
                                               ushort* __restrict__ klo){
  int i = blockIdx.x*256 + threadIdx.x;   // over 1,048,576 float4s
  float4 v = ((const float4*)K)[i];
  union { ushort u[4]; uint2 q; } ph, pl;
  float xs[4] = {v.x, v.y, v.z, v.w};
  #pragma unroll
  for (int e=0;e<4;e++){
    __hip_bfloat16 h = __float2bfloat16(xs[e]);
    float hf = __bfloat162float(h);
    __hip_bfloat16 l = __float2bfloat16(xs[e]-hf);
    ph.u[e] = bf_bits(h); pl.u[e] = bf_bits(l);
  }
  ((uint2*)khi)[i] = ph.q;
  ((uint2*)klo)[i] = pl.q;
}

// helper macro: top-6 insertion for one accumulator pair at column NC
#define SEL8(ACC0, ACC1, NC)                                                              \
  _Pragma("unroll")                                                                       \
  for (int v=0;v<4;v++){                                                                  \
    float s0 = (ACC0)[v];                                                                 \
    if (s0 > thr8[v]){                                                                    \
      float mn = ts8[v][0]; int mp = 0;                                                   \
      _Pragma("unroll")                                                                   \
      for (int k=1;k<6;k++){ bool lt = ts8[v][k] < mn; mn = lt ? ts8[v][k] : mn; mp = lt ? k : mp; } \
      _Pragma("unroll")                                                                   \
      for (int k=0;k<6;k++) if (k==mp){ ts8[v][k] = s0; ti8[v][k] = (NC); }               \
      float nm = ts8[v][0];                                                               \
      _Pragma("unroll")                                                                   \
      for (int k=1;k<6;k++) nm = fminf(nm, ts8[v][k]);                                    \
      thr8[v] = nm;                                                                       \
    }                                                                                     \
    float s1 = (ACC1)[v];                                                                 \
    if (s1 > thr8[4+v]){                                                                  \
      float mn = ts8[4+v][0]; int mp = 0;                                                 \
      _Pragma("unroll")                                                                   \
      for (int k=1;k<6;k++){ bool lt = ts8[4+v][k] < mn; mn = lt ? ts8[4+v][k] : mn; mp = lt ? k : mp; } \
      _Pragma("unroll")                                                                   \
      for (int k=0;k<6;k++) if (k==mp){ ts8[4+v][k] = s1; ti8[4+v][k] = (NC); }           \
      float nm = ts8[4+v][0];                                                             \
      _Pragma("unroll")                                                                   \
      for (int k=1;k<6;k++) nm = fminf(nm, ts8[4+v][k]);                                  \
      thr8[4+v] = nm;                                                                     \
    }                                                                                     \
  }

// ============ scores via MFMA bf16x3, barrier-free + double-buffered K prefetch ============
__global__ __launch_bounds__(512) void k_scores_mfma(const float* __restrict__ Qm,
                                                     const ushort* __restrict__ khi,
                                                     const ushort* __restrict__ klo,
                                                     const float* __restrict__ Km,
                                                     float* __restrict__ tw, int* __restrict__ tidx,
                                                     float* __restrict__ out3, float* __restrict__ out4){
  __shared__ float Qt[32][132];
  __shared__ float wcs[8][32][8];      // per-wave top-8 per row
  __shared__ int   wci[8][32][8];
  const int t = threadIdx.x;
  const int rg = t>>6, c = t&63;       // wave 0..7, lane 0..63
  const int lrow = c&15, lk8 = c>>4;   // fragment row/col lane, k-group lane
  const int row0 = blockIdx.x*32;
  #pragma unroll
  for (int p=0;p<2;p++){
    int f = p*512+t; int r = f>>5, rq = f&31;
    float4 v = *(const float4*)&Qm[(size_t)(row0+r)*128 + rq*4];
    *(float4*)&Qt[r][rq*4] = v;
  }
  __syncthreads();
  // build Q fragments (bf16 hi/lo), 2 row-tiles x 4 k-chunks, all static -> 64 VGPR
  short8v qhi[2][4], qlo[2][4];
  #pragma unroll
  for (int rt=0;rt<2;rt++){
    #pragma unroll
    for (int kc=0;kc<4;kc++){
      union { ushort u[8]; short8v v; } th, tl;
      #pragma unroll
      for (int e=0;e<8;e++){
        float xq = Qt[rt*16+lrow][kc*32 + lk8*8 + e];
        __hip_bfloat16 h = __float2bfloat16(xq);
        float hf = __bfloat162float(h);
        __hip_bfloat16 l = __float2bfloat16(xq-hf);
        th.u[e] = bf_bits(h); tl.u[e] = bf_bits(l);
      }
      qhi[rt][kc] = th.v; qlo[rt][kc] = tl.v;
    }
  }
  // per-thread top-6 for this thread's 8 fixed rows
  float ts8[8][6]; int ti8[8][6]; float thr8[8];
  #pragma unroll
  for (int s=0;s<8;s++){
    thr8[s] = -3.0e38f;
    #pragma unroll
    for (int q=0;q<6;q++){ ts8[s][q] = -3.0e38f; ti8[s][q] = 0x7fffffff; }
  }
  // ---- phase 1: barrier-free MFMA GEMM, linearized it = nt*4+cq, A/B double-buffered loads ----
  short8v ah[4], al[4], bh[4], bl[4];
  int ncolA, ncolB;
  {
    int ncol = (rg*4+0)*16 + lrow; ncolA = ncol;        // it=0: nt=0, cq=0
    #pragma unroll
    for (int kc=0;kc<4;kc++){
      const size_t koff = (size_t)ncol*128 + kc*32 + lk8*8;
      ah[kc] = *(const short8v*)&khi[koff];
      al[kc] = *(const short8v*)&klo[koff];
    }
  }
  #pragma unroll 1
  for (int it=0; it<256; it+=2){
    // prefetch B = it+1
    {
      int nt = (it+1)>>2, cq = (it+1)&3;
      int ncol = nt*512 + (rg*4+cq)*16 + lrow; ncolB = ncol;
      #pragma unroll
      for (int kc=0;kc<4;kc++){
        const size_t koff = (size_t)ncol*128 + kc*32 + lk8*8;
        bh[kc] = *(const short8v*)&khi[koff];
        bl[kc] = *(const short8v*)&klo[koff];
      }
    }
    // compute + select A
    {
      f32x4 acc0 = {0.f,0.f,0.f,0.f};
      f32x4 acc1 = {0.f,0.f,0.f,0.f};
      #pragma unroll
      for (int kc=0;kc<4;kc++){
        acc0 = __builtin_amdgcn_mfma_f32_16x16x32_bf16(qhi[0][kc], ah[kc], acc0, 0,0,0);
        acc1 = __builtin_amdgcn_mfma_f32_16x16x32_bf16(qhi[1][kc], ah[kc], acc1, 0,0,0);
        acc0 = __builtin_amdgcn_mfma_f32_16x16x32_bf16(qlo[0][kc], ah[kc], acc0, 0,0,0);
        acc1 = __builtin_amdgcn_mfma_f32_16x16x32_bf16(qlo[1][kc], ah[kc], acc1, 0,0,0);
        acc0 = __builtin_amdgcn_mfma_f32_16x16x32_bf16(qhi[0][kc], al[kc], acc0, 0,0,0);
        acc1 = __builtin_amdgcn_mfma_f32_16x16x32_bf16(qhi[1][kc], al[kc], acc1, 0,0,0);
      }
      SEL8(acc0, acc1, ncolA)
    }
    // prefetch A = it+2
    if (it+2 < 256){
      int nt = (it+2)>>2, cq = (it+2)&3;
      int ncol = nt*512 + (rg*4+cq)*16 + lrow; ncolA = ncol;
      #pragma unroll
      for (int kc=0;kc<4;kc++){
        const size_t koff = (size_t)ncol*128 + kc*32 + lk8*8;
        ah[kc] = *(const short8v*)&khi[koff];
        al[kc] = *(const short8v*)&klo[koff];
      }
    }
    // compute + select B
    {
      f32x4 acc0 = {0.f,0.f,0.f,0.f};
      f32x4 acc1 = {0.f,0.f,0.f,0.f};
      #pragma unroll
      for (int kc=0;kc<4;kc++){
        acc0 = __builtin_amdgcn_mfma_f32_16x16x32_bf16(qhi[0][kc], bh[kc], acc0, 0,0,0);
        acc1 = __builtin_amdgcn_mfma_f32_16x16x32_bf16(qhi[1][kc], bh[kc], acc1, 0,0,0);
        acc0 = __builtin_amdgcn_mfma_f32_16x16x32_bf16(qlo[0][kc], bh[kc], acc0, 0,0,0);
        acc1 = __builtin_amdgcn_mfma_f32_16x16x32_bf16(qlo[1][kc], bh[kc], acc1, 0,0,0);
        acc0 = __builtin_amdgcn_mfma_f32_16x16x32_bf16(qhi[0][kc], bl[kc], acc0, 0,0,0);
        acc1 = __builtin_amdgcn_mfma_f32_16x16x32_bf16(qhi[1][kc], bl[kc], acc1, 0,0,0);
      }
      SEL8(acc0, acc1, ncolB)
    }
  }
  // ---- phase 2a: per-wave top-8 per row via 16-lane-group shuffles ----
  #pragma unroll
  for (int s=0;s<8;s++){
    const int rloc = (s<4) ? (lk8*4+s) : (16 + lk8*4 + (s-4));
    #pragma unroll 1
    for (int k=0;k<8;k++){
      float bs = ts8[s][0]; int bi = ti8[s][0];
      #pragma unroll
      for (int q=1;q<6;q++){
        bool bt = (ts8[s][q] > bs) || (ts8[s][q]==bs && ti8[s][q] < bi);
        bs = bt ? ts8[s][q] : bs; bi = bt ? ti8[s][q] : bi;
      }
      #pragma unroll
      for (int off=1; off<16; off<<=1){
        float os = __shfl_xor(bs, off, 16); int oi = __shfl_xor(bi, off, 16);
        bool bt = (os > bs) || (os==bs && oi < bi);
        bs = bt ? os : bs; bi = bt ? oi : bi;
      }
      #pragma unroll
      for (int q=0;q<6;q++){
        if (ti8[s][q]==bi){ ts8[s][q] = -3.0e38f; ti8[s][q] = 0x7fffffff; }
      }
      if (lrow==0){ wcs[rg][rloc][k] = bs; wci[rg][rloc][k] = bi; }
    }
  }
  __syncthreads();
  // ---- phase 2b: block top-16 per row (row = t>>4, 16-lane group merges 64 candidates) ----
  const int mrow = t>>4;        // 0..31
  const int ml   = t&15;
  float cs4[4]; int ci4[4];
  #pragma unroll
  for (int j=0;j<4;j++){
    int idx = ml*4+j;
    cs4[j] = wcs[idx>>3][mrow][idx&7];
    ci4[j] = wci[idx>>3][mrow][idx&7];
  }
  int myidx = 0;
  #pragma unroll 1
  for (int k=0;k<16;k++){
    float bs = cs4[0]; int bi = ci4[0];
    #pragma unroll
    for (int q=1;q<4;q++){
      bool bt = (cs4[q] > bs) || (cs4[q]==bs && ci4[q] < bi);
      bs = bt ? cs4[q] : bs; bi = bt ? ci4[q] : bi;
    }
    #pragma unroll
    for (int off=1; off<16; off<<=1){
      float os = __shfl_xor(bs, off, 16); int oi = __shfl_xor(bi, off, 16);
      bool bt = (os > bs) || (os==bs && oi < bi);
      bs = bt ? os : bs; bi = bt ? oi : bi;
    }
    #pragma unroll
    for (int q=0;q<4;q++){
      if (ci4[q]==bi){ cs4[q] = -3.0e38f; ci4[q] = 0x7fffffff; }
    }
    if (ml==k) myidx = bi;
  }
  // ---- phase 3: exact f64 rescore of 16 candidates/row; top-8 by (score desc, idx asc) ----
  const float* kr = Km + (size_t)myidx*128;
  const float* qrow = &Qt[mrow][0];
  double sd = 0.0;
  #pragma unroll 1
  for (int d4=0; d4<32; d4++){
    float4 kv = *(const float4*)&kr[d4*4];
    sd += (double)qrow[d4*4+0]*(double)kv.x;
    sd += (double)qrow[d4*4+1]*(double)kv.y;
    sd += (double)qrow[d4*4+2]*(double)kv.z;
    sd += (double)qrow[d4*4+3]*(double)kv.w;
  }
  double cs = sd; int ci = myidx;
  double sel0,sel1,sel2,sel3,sel4,sel5,sel6,sel7;
  int is0,is1,is2,is3,is4,is5,is6,is7;
  #pragma unroll
  for (int k8=0;k8<8;k8++){
    double bs = cs; int bi = ci;
    #pragma unroll
    for (int off=1; off<16; off<<=1){
      double os = __shfl_xor(bs, off, 16); int oi = __shfl_xor(bi, off, 16);
      bool bt = (os > bs) || (os==bs && oi < bi);
      bs = bt ? os : bs; bi = bt ? oi : bi;
    }
    if (ci==bi) cs = -1.0e300;
    if (k8==0){sel0=bs;is0=bi;} else if (k8==1){sel1=bs;is1=bi;}
    else if (k8==2){sel2=bs;is2=bi;} else if (k8==3){sel3=bs;is3=bi;}
    else if (k8==4){sel4=bs;is4=bi;} else if (k8==5){sel5=bs;is5=bi;}
    else if (k8==6){sel6=bs;is6=bi;} else {sel7=bs;is7=bi;}
  }
  if (ml==0){
    int grow = row0 + mrow;
    const double sc_inv = 0.08838834764831845;
    double mx = sel0;
    double e0 = exp((sel0-mx)*sc_inv), e1 = exp((sel1-mx)*sc_inv);
    double e2 = exp((sel2-mx)*sc_inv), e3 = exp((sel3-mx)*sc_inv);
    double e4 = exp((sel4-mx)*sc_inv), e5 = exp((sel5-mx)*sc_inv);
    double e6 = exp((sel6-mx)*sc_inv), e7 = exp((sel7-mx)*sc_inv);
    double sum = e0+e1+e2+e3+e4+e5+e6+e7;
    float w0=(float)(e0/sum),w1=(float)(e1/sum),w2=(float)(e2/sum),w3=(float)(e3/sum);
    float w4=(float)(e4/sum),w5=(float)(e5/sum),w6=(float)(e6/sum),w7=(float)(e7/sum);
    size_t o = (size_t)grow*8;
    tw[o+0]=w0; tw[o+1]=w1; tw[o+2]=w2; tw[o+3]=w3;
    tw[o+4]=w4; tw[o+5]=w5; tw[o+6]=w6; tw[o+7]=w7;
    tidx[o+0]=is0; tidx[o+1]=is1; tidx[o+2]=is2; tidx[o+3]=is3;
    tidx[o+4]=is4; tidx[o+5]=is5; tidx[o+6]=is6; tidx[o+7]=is7;
    out4[o+0]=w0; out4[o+1]=w1; out4[o+2]=w2; out4[o+3]=w3;
    out4[o+4]=w4; out4[o+5]=w5; out4[o+6]=w6; out4[o+7]=w7;
    out3[o+0]=(float)is0; out3[o+1]=(float)is1;
    out3[o+2]=(float)is2; out3[o+3]=(float)is3;
    out3[o+4]=(float)is4; out3[o+5]=(float)is5;
    out3[o+6]=(float)is6; out3[o+7]=(float)is7;
  }
}

// ============ scores fallback (round-7 f32 path, used if ws too small) ============
__global__ __launch_bounds__(512) void k_scores(const float* __restrict__ Qm, const float* __restrict__ Km,
                                                float* __restrict__ tw, int* __restrict__ tidx,
                                                float* __restrict__ out3, float* __restrict__ out4){
  __shared__ float Qt[32][132];
  __shared__ float Kt[512][20];
  __shared__ int candI[8][4][16];
  const int t = threadIdx.x;
  const int rg = t>>6, c = t&63;
  const int row0 = blockIdx.x*32;
  #pragma unroll
  for (int p=0;p<2;p++){
    int f = p*512+t; int r = f>>5, rq = f&31;
    float4 v = *(const float4*)&Qm[(size_t)(row0+r)*128 + rq*4];
    *(float4*)&Qt[r][rq*4] = v;
  }
  float ts[4][8]; int ti[4][8]; float thr[4];
  #pragma unroll
  for (int i=0;i<4;i++){
    thr[i] = -3.0e38f;
    #pragma unroll
    for (int k=0;k<8;k++){ ts[i][k] = -3.0e38f; ti[i][k] = 0x7fffffff; }
  }
  __syncthreads();
  #pragma unroll 1
  for (int nt=0;nt<64;nt++){
    const int nb = nt*512;
    float acc[4][8];
    #pragma unroll
    for (int i=0;i<4;i++){
      #pragma unroll
      for (int j=0;j<8;j++) acc[i][j]=0.f;
    }
    #pragma unroll 1
    for (int rc=0;rc<8;rc++){
      #pragma unroll
      for (int p=0;p<4;p++){
        int f = p*512+t; int nn = f>>2, rq = f&3;
        float4 v = *(const float4*)&Km[(size_t)(nb+nn)*128 + rc*16 + rq*4];
        *(float4*)&Kt[nn][rq*4] = v;
      }
      __syncthreads();
      #pragma unroll
      for (int r4=0;r4<4;r4++){
        float4 qv[4]; float4 kv[8];
        #pragma unroll
        for (int i=0;i<4;i++) qv[i] = *(const float4*)&Qt[rg*4+i][rc*16+r4*4];
        #pragma unroll
        for (int j=0;j<8;j++) kv[j] = *(const float4*)&Kt[c+64*j][r4*4];
        #pragma unroll
        for (int i=0;i<4;i++){
          #pragma unroll
          for (int j=0;j<8;j++){
            acc[i][j] += qv[i].x*kv[j].x;
            acc[i][j] += qv[i].y*kv[j].y;
            acc[i][j] += qv[i].z*kv[j].z;
            acc[i][j] += qv[i].w*kv[j].w;
          }
        }
      }
      __syncthreads();
    }
    #pragma unroll
    for (int i=0;i<4;i++){
      #pragma unroll
      for (int j=0;j<8;j++){
        float s = acc[i][j];
        if (s > thr[i]){
          int n = nb + c + 64*j;
          float mn = ts[i][0]; int mp = 0;
          #pragma unroll
          for (int k=1;k<8;k++){ bool lt = ts[i][k] < mn; mn = lt ? ts[i][k] : mn; mp = lt ? k : mp; }
          #pragma unroll
          for (int k=0;k<8;k++) if (k==mp){ ts[i][k] = s; ti[i][k] = n; }
          float nm = ts[i][0];
          #pragma unroll
          for (int k=1;k<8;k++) nm = fminf(nm, ts[i][k]);
          thr[i] = nm;
        }
      }
    }
  }
  #pragma unroll
  for (int i=0;i<4;i++){
    #pragma unroll 1
    for (int k=0;k<16;k++){
      float bs = ts[i][0]; int bi = ti[i][0];
      #pragma unroll
      for (int q=1;q<8;q++){
        bool bt = (ts[i][q] > bs) || (ts[i][q]==bs && ti[i][q] < bi);
        bs = bt ? ts[i][q] : bs; bi = bt ? ti[i][q] : bi;
      }
      #pragma unroll
      for (int off=1; off<64; off<<=1){
        float os = __shfl_xor(bs, off); int oi = __shfl_xor(bi, off);
        bool bt = (os > bs) || (os==bs && oi < bi);
        bs = bt ? os : bs; bi = bt ? oi : bi;
      }
      #pragma unroll
      for (int q=0;q<8;q++){
        if (ti[i][q]==bi){ ts[i][q] = -3.0e38f; ti[i][q] = 0x7fffffff; }
      }
      if (c==0) candI[rg][i][k] = bi;
    }
  }
  __syncthreads();
  const int ri = c>>4, rk = c&15;
  const int kidx = candI[rg][ri][rk];
  const float* kr = Km + (size_t)kidx*128;
  const float* qrow = &Qt[rg*4+ri][0];
  double sd = 0.0;
  #pragma unroll 1
  for (int d4=0; d4<32; d4++){
    float4 kv = *(const float4*)&kr[d4*4];
    sd += (double)qrow[d4*4+0]*(double)kv.x;
    sd += (double)qrow[d4*4+1]*(double)kv.y;
    sd += (double)qrow[d4*4+2]*(double)kv.z;
    sd += (double)qrow[d4*4+3]*(double)kv.w;
  }
  double cs = sd; int ci = kidx;
  double sel0,sel1,sel2,sel3,sel4,sel5,sel6,sel7;
  int is0,is1,is2,is3,is4,is5,is6,is7;
  #pragma unroll
  for (int k8=0;k8<8;k8++){
    double bs = cs; int bi = ci;
    #pragma unroll
    for (int off=1; off<16; off<<=1){
      double os = __shfl_xor(bs, off, 16); int oi = __shfl_xor(bi, off, 16);
      bool bt = (os > bs) || (os==bs && oi < bi);
      bs = bt ? os : bs; bi = bt ? oi : bi;
    }
    if (ci==bi) cs = -1.0e300;
    if (k8==0){sel0=bs;is0=bi;} else if (k8==1){sel1=bs;is1=bi;}
    else if (k8==2){sel2=bs;is2=bi;} else if (k8==3){sel3=bs;is3=bi;}
    else if (k8==4){sel4=bs;is4=bi;} else if (k8==5){sel5=bs;is5=bi;}
    else if (k8==6){sel6=bs;is6=bi;} else {sel7=bs;is7=bi;}
  }
  if (rk==0){
    int grow = row0 + rg*4 + ri;
    const double sc_inv = 0.08838834764831845;
    double mx = sel0;
    double e0 = exp((sel0-mx)*sc_inv), e1 = exp((sel1-mx)*sc_inv);
    double e2 = exp((sel2-mx)*sc_inv), e3 = exp((sel3-mx)*sc_inv);
    double e4 = exp((sel4-mx)*sc_inv), e5 = exp((sel5-mx)*sc_inv);
    double e6 = exp((sel6-mx)*sc_inv), e7 = exp((sel7-mx)*sc_inv);
    double sum = e0+e1+e2+e3+e4+e5+e6+e7;
    float w0=(float)(e0/sum),w1=(float)(e1/sum),w2=(float)(e2/sum),w3=(float)(e3/sum);
    float w4=(float)(e4/sum),w5=(float)(e5/sum),w6=(float)(e6/sum),w7=(float)(e7/sum);
    size_t o = (size_t)grow*8;
    tw[o+0]=w0; tw[o+1]=w1; tw[o+2]=w2; tw[o+3]=w3;
    tw[o+4]=w4; tw[o+5]=w5; tw[o+6]=w6; tw[o+7]=w7;
    tidx[o+0]=is0; tidx[o+1]=is1; tidx[o+2]=is2; tidx[o+3]=is3;
    tidx[o+4]=is4; tidx[o+5]=is5; tidx[o+6]=is6; tidx[o+7]=is7;
    out4[o+0]=w0; out4[o+1]=w1; out4[o+2]=w2; out4[o+3]=w3;
    out4[o+4]=w4; out4[o+5]=w5; out4[o+6]=w6; out4[o+7]=w7;
    out3[o+0]=(float)is0; out3[o+1]=(float)is1;
    out3[o+2]=(float)is2; out3[o+3]=(float)is3;
    out3[o+4]=(float)is4; out3[o+5]=(float)is5;
    out3[o+6]=(float)is6; out3[o+7]=(float)is7;
  }
}

// ============ gather + weighted sum -> output (float32) ============
__global__ __launch_bounds__(256) void k_gather(const float* __restrict__ V, const int* __restrict__ tidx,
                                                const float* __restrict__ tw, float* __restrict__ out0){
  int row = blockIdx.x; int t = threadIdx.x;
  __shared__ int li[8]; __shared__ float lw[8];
  if (t<8){
    int idx = tidx[(size_t)row*8+t];
    idx = idx < 0 ? 0 : (idx > (NK_-1) ? (NK_-1) : idx);
    li[t] = idx;
  } else if (t<16){
    float w = tw[(size_t)row*8 + t-8];
    w = fminf(fmaxf(w, 0.f), 1.f);
    lw[t-8] = w;
  }
  __syncthreads();
  float4 a = {0,0,0,0};
  #pragma unroll
  for (int k=0;k<8;k++){
    float4 v = ((const float4*)V)[(size_t)li[k]*256 + t];
    float w = lw[k];
    a.x += w*v.x; a.y += w*v.y; a.z += w*v.z; a.w += w*v.w;
  }
  ((float4*)(out0 + (size_t)row*1024))[t] = a;
}

extern "C" void kernel_launch(void* const* d_in, const int* in_sizes, int n_in,
                              void* d_out, int out_size, void* d_ws, size_t ws_size,
                              hipStream_t stream) {
  const float* x    = (const float*)d_in[0];
  const float* A    = (const float*)d_in[1];
  const float* Bm   = (const float*)d_in[2];
  const float* Wimp = (const float*)d_in[3];
  const float* Wr   = (const float*)d_in[4];
  const float* comp = (const float*)d_in[5];
  const float* Kmat = (const float*)d_in[6];
  const float* V    = (const float*)d_in[7];
  float* out = (float*)d_out;               // OUTPUT IS FLOAT32
  float* ws = (float*)d_ws;

  float* xB    = ws + OFF_XB;
  float* tp    = ws + OFF_TP;
  float* Apow  = ws + OFF_APOW;
  float* P     = ws + OFF_P;
  float* hproj = ws + OFF_HPROJ;
  float* logit = ws + OFF_LOGIT;
  float* imp   = ws + OFF_IMP;
  float* nw    = ws + OFF_NW;
  float* scb   = ws + OFF_SC;
  float* Qb    = ws + OFF_Q;        // aliases xB+tp (both dead by the time k_Q runs)
  int*   tidx  = (int*)(ws + OFF_TIDX);
  float* tw    = ws + OFF_TW;
  ushort* khi  = (ushort*)(ws + OFF_KHI);
  ushort* klo  = (ushort*)(ws + OFF_KLO);

  const bool use_mfma = (ws_size >= WS_NEED_MFMA);

  k_init_apow<<<32,256,0,stream>>>(A, Apow);
  if (use_mfma) k_split<<<4096,256,0,stream>>>(Kmat, khi, klo);
  k_matstage<<<1 ,256,0,stream>>>(Apow, 2 ,1 ,1);
  k_matstage<<<2 ,256,0,stream>>>(Apow, 3 ,2 ,1);
  k_matstage<<<4 ,256,0,stream>>>(Apow, 5 ,4 ,1);
  k_matstage<<<8 ,256,0,stream>>>(Apow, 9 ,8 ,1);
  k_matstage<<<16,256,0,stream>>>(Apow, 17,16,1);
  k_matstage<<<32,256,0,stream>>>(Apow, 33,32,1);
  k_xbr<<<128,256,0,stream>>>(x, Bm, Wr, xB, tp);
  k_P<<<32,256,0,stream>>>(xB, Apow, P);
  k_scan<<<1,256,0,stream>>>(Apow, P, Wimp, hproj);
  k_implogit<<<8192,256,0,stream>>>(x, hproj, logit);
  k_softS<<<4,1024,0,stream>>>(logit, imp, out + O_IMP);
  k_nw<<<4,256,0,stream>>>(imp, tp, nw, out + O_NW);
  k_sc<<<128,256,0,stream>>>(nw, comp, scb);
  k_Q<<<128,256,0,stream>>>(x, scb, Qb);
  if (use_mfma)
    k_scores_mfma<<<256,512,0,stream>>>(Qb, khi, klo, Kmat, tw, tidx, out + O_TIDX, out + O_TW);
  else
    k_scores<<<256,512,0,stream>>>(Qb, Kmat, tw, tidx, out + O_TIDX, out + O_TW);
  k_gather<<<8192,256,0,stream>>>(V, tidx, tw, out + O_OUT);
}

// Round 14
// 1085.931 us; speedup vs baseline: 1.7105x; 1.0938x over previous
//
#include <hip/hip_runtime.h>
#include <hip/hip_bf16.h>
#include <math.h>

#define B_  4
#define S_  2048
#define D_  1024
#define R_  128
#define NC_ 64
#define NK_ 32768
#define SD_ 64
#define KK_ 8

typedef __attribute__((ext_vector_type(8))) short short8v;  // 8 bf16 (4 VGPRs)
typedef __attribute__((ext_vector_type(4))) float f32x4;

// ---------------- ws layout (float offsets) ----------------
static const size_t OFF_XB    = 0;         // [8192][64]
static const size_t OFF_TP    = 524288;    // [8192][64]
static const size_t OFF_APOW  = 1048576;   // [65][64][64]
static const size_t OFF_P     = 1314816;   // [32][4][64]
static const size_t OFF_HPROJ = 1323008;   // [4][1024]
static const size_t OFF_LOGIT = 1327104;   // [4][2048]
static const size_t OFF_IMP   = 1335296;   // [4][2048]
static const size_t OFF_NW    = 1343488;   // [4][64]
static const size_t OFF_SC    = 1343744;   // [4][1024][128]
static const size_t OFF_Q     = 0;         // [8192][128] aliases XB+TP (stream-ordered safe)
static const size_t OFF_TIDX  = 1868032;   // [8192][8] int
static const size_t OFF_TW    = 1933568;   // [8192][8]  -> 1999104
// MFMA path extras (bf16 split of K), only used when ws_size is large enough:
static const size_t OFF_KHI   = 1999104;   // [32768][128] ushort -> 2,097,152 floats
static const size_t OFF_KLO   = 4096256;   // [32768][128] ushort -> 2,097,152 floats
static const size_t WS_NEED_MFMA = (size_t)6193408 * 4;   // bytes

// -------- output layout (FLOAT32 offsets) --------
static const size_t O_OUT  = 0;
static const size_t O_IMP  = 8388608;
static const size_t O_NW   = 8396800;
static const size_t O_TIDX = 8397056;
static const size_t O_TW   = 8462592;

__device__ __forceinline__ ushort bf_bits(__hip_bfloat16 h){ return *reinterpret_cast<ushort*>(&h); }

// ============ Apow init ============
__global__ __launch_bounds__(256) void k_init_apow(const float* __restrict__ A, float* __restrict__ Apow){
  int t = blockIdx.x*256 + threadIdx.x;
  if (t < 4096){ int i = t>>6, j = t&63; Apow[t] = (i==j) ? 1.f : 0.f; }
  else Apow[t] = A[t-4096];
}

// ============ batched 64x64x64 matmul (f64 accumulate) ============
__global__ __launch_bounds__(256) void k_matstage(float* __restrict__ Apow, int dst0, int lhs, int rhs0){
  __shared__ float L[64][68];
  __shared__ float Rm[64][68];
  const float* Lp = Apow + (size_t)lhs*4096;
  const float* Rp = Apow + (size_t)(rhs0 + blockIdx.x)*4096;
  int t = threadIdx.x;
  #pragma unroll 1
  for (int p=0;p<4;p++){
    int f = p*256+t; int i = f>>4, jq = f&15;
    float4 v = ((const float4*)Lp)[f];
    L[i][jq*4+0]=v.x; L[i][jq*4+1]=v.y; L[i][jq*4+2]=v.z; L[i][jq*4+3]=v.w;
    float4 w = ((const float4*)Rp)[f];
    Rm[i][jq*4+0]=w.x; Rm[i][jq*4+1]=w.y; Rm[i][jq*4+2]=w.z; Rm[i][jq*4+3]=w.w;
  }
  __syncthreads();
  int j = t&63, rg = t>>6;
  double acc[16];
  #pragma unroll
  for (int ii=0;ii<16;ii++) acc[ii]=0.0;
  #pragma unroll 1
  for (int kk=0;kk<64;kk++){
    double rv = (double)Rm[kk][j];
    #pragma unroll
    for (int ii=0;ii<16;ii++) acc[ii] += (double)L[rg*16+ii][kk]*rv;
  }
  float* out = Apow + (size_t)(dst0 + blockIdx.x)*4096;
  #pragma unroll
  for (int ii=0;ii<16;ii++) out[(rg*16+ii)*64 + j] = (float)acc[ii];
}

// ============ xB + router logits GEMM, 32-row tiles (256 blocks: full CU coverage) ============
__global__ __launch_bounds__(256) void k_xbr(const float* __restrict__ x, const float* __restrict__ Bm,
                                             const float* __restrict__ Wr,
                                             float* __restrict__ xB, float* __restrict__ tp){
  int row0 = blockIdx.x*32;
  __shared__ float Xt[32][36];
  __shared__ float Wt[32][132];
  __shared__ float SB[32][65];
  int t = threadIdx.x;
  int rg = t>>5, c = t&31;
  double accd[4][4];
  #pragma unroll
  for (int i=0;i<4;i++){
    #pragma unroll
    for (int j=0;j<4;j++) accd[i][j]=0.0;
  }
  #pragma unroll 1
  for (int kc=0;kc<32;kc++){
    int d0 = kc*32;
    {
      int f = t; int r = f>>3, dq = f&7;
      float4 v = *(const float4*)&x[(size_t)(row0+r)*1024 + d0 + dq*4];
      Xt[r][dq*4+0]=v.x; Xt[r][dq*4+1]=v.y; Xt[r][dq*4+2]=v.z; Xt[r][dq*4+3]=v.w;
    }
    #pragma unroll
    for (int p=0;p<2;p++){
      int f = p*256+t; int dd = f>>4, eq = f&15;
      float4 v = *(const float4*)&Bm[(size_t)(d0+dd)*64 + eq*4];
      Wt[dd][eq*4+0]=v.x; Wt[dd][eq*4+1]=v.y; Wt[dd][eq*4+2]=v.z; Wt[dd][eq*4+3]=v.w;
    }
    #pragma unroll
    for (int p=0;p<2;p++){
      int f = p*256+t; int n = f>>3, dq = f&7;
      float4 v = *(const float4*)&Wr[(size_t)n*1024 + d0 + dq*4];
      Wt[dq*4+0][64+n]=v.x; Wt[dq*4+1][64+n]=v.y; Wt[dq*4+2][64+n]=v.z; Wt[dq*4+3][64+n]=v.w;
    }
    __syncthreads();
    float accf[4][4];
    #pragma unroll
    for (int i=0;i<4;i++){
      #pragma unroll
      for (int j=0;j<4;j++) accf[i][j]=0.f;
    }
    #pragma unroll
    for (int k4=0;k4<8;k4++){
      float4 xv[4];
      #pragma unroll
      for (int i=0;i<4;i++) xv[i] = *(const float4*)&Xt[rg*4+i][k4*4];
      #pragma unroll
      for (int u=0;u<4;u++){
        int kk = k4*4+u;
        float wv[4];
        #pragma unroll
        for (int j=0;j<4;j++) wv[j] = Wt[kk][c+32*j];
        #pragma unroll
        for (int i=0;i<4;i++){
          float xs = (u==0)?xv[i].x:(u==1)?xv[i].y:(u==2)?xv[i].z:xv[i].w;
          #pragma unroll
          for (int j=0;j<4;j++) accf[i][j] += xs*wv[j];
        }
      }
    }
    #pragma unroll
    for (int i=0;i<4;i++){
      #pragma unroll
      for (int j=0;j<4;j++) accd[i][j] += (double)accf[i][j];
    }
    __syncthreads();
  }
  #pragma unroll
  for (int i=0;i<4;i++){
    int row = row0 + rg*4 + i;
    xB[(size_t)row*64 + c]      = (float)accd[i][0];
    xB[(size_t)row*64 + c + 32] = (float)accd[i][1];
    SB[rg*4+i][c]    = (float)accd[i][2];
    SB[rg*4+i][c+32] = (float)accd[i][3];
  }
  __syncthreads();
  if (t < 32){
    double m = -1.0e300;
    #pragma unroll 1
    for (int n=0;n<64;n++) m = fmax(m, (double)SB[t][n]);
    double s = 0.0;
    #pragma unroll 1
    for (int n=0;n<64;n++){ double e = exp((double)SB[t][n]-m); SB[t][n]=(float)e; s += e; }
    int row = row0 + t;
    #pragma unroll 1
    for (int n=0;n<64;n++) tp[(size_t)row*64 + n] = (float)((double)SB[t][n]/s);
  }
}

// ============ chunk partials (f64 accumulate) ============
__global__ __launch_bounds__(256) void k_P(const float* __restrict__ xB, const float* __restrict__ Apow,
                                           float* __restrict__ P){
  int cchunk = blockIdx.x; int t = threadIdx.x;
  int b = t>>6, e = t&63;
  double acc = 0.0;
  #pragma unroll 1
  for (int l=0;l<64;l++){
    const float* xr = &xB[((size_t)b*2048 + cchunk*64 + l)*64];
    const float* Ap = &Apow[(size_t)(63-l)*4096];
    #pragma unroll
    for (int k4=0;k4<16;k4++){
      float4 xv = *(const float4*)&xr[k4*4];
      acc += (double)xv.x*(double)Ap[(k4*4+0)*64+e];
      acc += (double)xv.y*(double)Ap[(k4*4+1)*64+e];
      acc += (double)xv.z*(double)Ap[(k4*4+2)*64+e];
      acc += (double)xv.w*(double)Ap[(k4*4+3)*64+e];
    }
  }
  P[cchunk*256 + t] = (float)acc;
}

// ============ Horner combine (f64) + h_proj ============
__global__ __launch_bounds__(256) void k_scan(const float* __restrict__ Apow, const float* __restrict__ P,
                                              const float* __restrict__ Wimp, float* __restrict__ hproj){
  __shared__ float A64s[64][68];
  __shared__ double h[2][4][64];
  int t = threadIdx.x;
  const float* A64 = Apow + (size_t)64*4096;
  #pragma unroll 1
  for (int p=0;p<4;p++){
    int f = p*256+t; int i = f>>4, jq = f&15;
    float4 v = *(const float4*)&A64[f*4];
    A64s[i][jq*4+0]=v.x; A64s[i][jq*4+1]=v.y; A64s[i][jq*4+2]=v.z; A64s[i][jq*4+3]=v.w;
  }
  int b = t>>6, e = t&63;
  h[0][b][e] = 0.0;
  __syncthreads();
  #pragma unroll 1
  for (int c=0;c<32;c++){
    int cur = c&1;
    double acc = (double)P[c*256 + t];
    #pragma unroll
    for (int k=0;k<64;k++) acc += h[cur][b][k]*(double)A64s[k][e];
    h[cur^1][b][e] = acc;
    __syncthreads();
  }
  #pragma unroll 1
  for (int m=0;m<16;m++){
    int o = t + 256*m; int bb = o>>10, d = o&1023;
    const float* wrow = &Wimp[(size_t)d*64];
    double acc = 0.0;
    #pragma unroll
    for (int e4=0;e4<16;e4++){
      float4 w = *(const float4*)&wrow[e4*4];
      acc += h[0][bb][e4*4+0]*(double)w.x;
      acc += h[0][bb][e4*4+1]*(double)w.y;
      acc += h[0][bb][e4*4+2]*(double)w.z;
      acc += h[0][bb][e4*4+3]*(double)w.w;
    }
    hproj[o] = (float)acc;
  }
}

// ============ importance logits (f64) ============
__global__ __launch_bounds__(256) void k_implogit(const float* __restrict__ x, const float* __restrict__ hproj,
                                                  float* __restrict__ logits){
  int row = blockIdx.x; int b = row>>11;
  int t = threadIdx.x;
  float4 xv = ((const float4*)x)[(size_t)row*256 + t];
  float4 hv = ((const float4*)hproj)[(size_t)b*256 + t];
  double p = (double)xv.x*(double)hv.x + (double)xv.y*(double)hv.y
           + (double)xv.z*(double)hv.z + (double)xv.w*(double)hv.w;
  #pragma unroll
  for (int off=32; off; off>>=1) p += __shfl_down(p, off);
  __shared__ double ws4[4];
  if ((t&63)==0) ws4[t>>6] = p;
  __syncthreads();
  if (t==0) logits[row] = (float)(ws4[0]+ws4[1]+ws4[2]+ws4[3]);
}

// ============ softmax over S per batch (f64) ============
__global__ __launch_bounds__(1024) void k_softS(const float* __restrict__ logits, float* __restrict__ imp,
                                                float* __restrict__ out1){
  int b = blockIdx.x; int t = threadIdx.x;
  double v0 = (double)logits[b*2048 + t];
  double v1 = (double)logits[b*2048 + 1024 + t];
  double m = fmax(v0,v1);
  #pragma unroll
  for (int off=32; off; off>>=1) m = fmax(m, __shfl_xor(m, off));
  __shared__ double red[16];
  if ((t&63)==0) red[t>>6] = m;
  __syncthreads();
  double M = red[0];
  #pragma unroll 1
  for (int i=1;i<16;i++) M = fmax(M, red[i]);
  double p0 = exp(v0-M), p1 = exp(v1-M);
  double s = p0+p1;
  #pragma unroll
  for (int off=32; off; off>>=1) s += __shfl_xor(s, off);
  __syncthreads();
  if ((t&63)==0) red[t>>6] = s;
  __syncthreads();
  double S = 0.0;
  #pragma unroll 1
  for (int i=0;i<16;i++) S += red[i];
  float i0 = (float)(p0/S), i1 = (float)(p1/S);
  imp[b*2048+t] = i0; imp[b*2048+1024+t] = i1;
  out1[b*2048+t] = i0; out1[b*2048+1024+t] = i1;
}

// ============ neuron_w (f64) ============
__global__ __launch_bounds__(256) void k_nw(const float* __restrict__ imp, const float* __restrict__ tp,
                                            float* __restrict__ nw, float* __restrict__ out2){
  int b = blockIdx.x; int t = threadIdx.x;
  int n = t&63, sg = t>>6;
  double acc = 0.0;
  #pragma unroll 1
  for (int s=sg; s<2048; s+=4)
    acc += (double)imp[b*2048+s]*(double)tp[((size_t)b*2048+s)*64 + n];
  __shared__ double part[4][64];
  part[sg][n] = acc;
  __syncthreads();
  if (t<64){
    double v = part[0][t]+part[1][t]+part[2][t]+part[3][t];
    double tot = v;
    #pragma unroll
    for (int off=32; off; off>>=1) tot += __shfl_xor(tot, off);
    float r = (float)(v/(tot + 1e-8));
    nw[b*64+t] = r; out2[b*64+t] = r;
  }
}

// ============ shared_compress (f64 accumulate) ============
__global__ __launch_bounds__(256) void k_sc(const float* __restrict__ nw, const float* __restrict__ comp,
                                            float* __restrict__ sc){
  __shared__ float w[256];
  int t = threadIdx.x;
  w[t] = nw[t];
  __syncthreads();
  size_t base = (size_t)blockIdx.x*1024 + t*4;
  double a[4][4];
  #pragma unroll
  for (int i=0;i<4;i++){
    #pragma unroll
    for (int j=0;j<4;j++) a[i][j]=0.0;
  }
  #pragma unroll 1
  for (int n=0;n<64;n++){
    float4 cv = *(const float4*)&comp[(size_t)n*131072 + base];
    double cx=cv.x, cy=cv.y, cz=cv.z, cw=cv.w;
    double w0=w[n], w1=w[64+n], w2=w[128+n], w3=w[192+n];
    a[0][0]+=w0*cx; a[0][1]+=w0*cy; a[0][2]+=w0*cz; a[0][3]+=w0*cw;
    a[1][0]+=w1*cx; a[1][1]+=w1*cy; a[1][2]+=w1*cz; a[1][3]+=w1*cw;
    a[2][0]+=w2*cx; a[2][1]+=w2*cy; a[2][2]+=w2*cz; a[2][3]+=w2*cw;
    a[3][0]+=w3*cx; a[3][1]+=w3*cy; a[3][2]+=w3*cz; a[3][3]+=w3*cw;
  }
  #pragma unroll
  for (int i=0;i<4;i++){
    float4 o; o.x=(float)a[i][0]; o.y=(float)a[i][1]; o.z=(float)a[i][2]; o.w=(float)a[i][3];
    *(float4*)&sc[(size_t)i*131072 + base] = o;
  }
}

// ============ Q = x @ sc[b], 32-row tiles (256 blocks: full CU coverage) ============
__global__ __launch_bounds__(256) void k_Q(const float* __restrict__ x, const float* __restrict__ sc,
                                           float* __restrict__ Q){
  int bid = blockIdx.x;
  int b = bid>>6;
  int row0 = b*2048 + (bid&63)*32;
  __shared__ float Xt[32][36];
  __shared__ float Wt[32][132];
  int t = threadIdx.x; int rg = t>>5, c = t&31;
  double accd[4][4];
  #pragma unroll
  for (int i=0;i<4;i++){
    #pragma unroll
    for (int j=0;j<4;j++) accd[i][j]=0.0;
  }
  #pragma unroll 1
  for (int kc=0;kc<32;kc++){
    int d0 = kc*32;
    {
      int f = t; int r = f>>3, dq = f&7;
      float4 v = *(const float4*)&x[(size_t)(row0+r)*1024 + d0 + dq*4];
      Xt[r][dq*4+0]=v.x; Xt[r][dq*4+1]=v.y; Xt[r][dq*4+2]=v.z; Xt[r][dq*4+3]=v.w;
    }
    #pragma unroll
    for (int p=0;p<4;p++){
      int f = p*256+t; int dd = f>>5, nq = f&31;
      float4 v = *(const float4*)&sc[(size_t)b*131072 + (size_t)(d0+dd)*128 + nq*4];
      Wt[dd][nq*4+0]=v.x; Wt[dd][nq*4+1]=v.y; Wt[dd][nq*4+2]=v.z; Wt[dd][nq*4+3]=v.w;
    }
    __syncthreads();
    float accf[4][4];
    #pragma unroll
    for (int i=0;i<4;i++){
      #pragma unroll
      for (int j=0;j<4;j++) accf[i][j]=0.f;
    }
    #pragma unroll
    for (int k4=0;k4<8;k4++){
      float4 xv[4];
      #pragma unroll
      for (int i=0;i<4;i++) xv[i] = *(const float4*)&Xt[rg*4+i][k4*4];
      #pragma unroll
      for (int u=0;u<4;u++){
        int kk = k4*4+u;
        float wv[4];
        #pragma unroll
        for (int j=0;j<4;j++) wv[j] = Wt[kk][c+32*j];
        #pragma unroll
        for (int i=0;i<4;i++){
          float xs = (u==0)?xv[i].x:(u==1)?xv[i].y:(u==2)?xv[i].z:xv[i].w;
          #pragma unroll
          for (int j=0;j<4;j++) accf[i][j] += xs*wv[j];
        }
      }
    }
    #pragma unroll
    for (int i=0;i<4;i++){
      #pragma unroll
      for (int j=0;j<4;j++) accd[i][j] += (double)accf[i][j];
    }
    __syncthreads();
  }
  #pragma unroll
  for (int i=0;i<4;i++){
    #pragma unroll
    for (int j=0;j<4;j++)
      Q[(size_t)(row0+rg*4+i)*128 + c + 32*j] = (float)accd[i][j];
  }
}

// ============ K -> bf16 hi/lo split ============
__global__ __launch_bounds__(256) void k_split(const float* __restrict__ K, ushort* __restrict__ khi,
                                               ushort* __restrict__ klo){
  int i = blockIdx.x*256 + threadIdx.x;   // over 1,048,576 float4s
  float4 v = ((const float4*)K)[i];
  union { ushort u[4]; uint2 q; } ph, pl;
  float xs[4] = {v.x, v.y, v.z, v.w};
  #pragma unroll
  for (int e=0;e<4;e++){
    __hip_bfloat16 h = __float2bfloat16(xs[e]);
    float hf = __bfloat162float(h);
    __hip_bfloat16 l = __float2bfloat16(xs[e]-hf);
    ph.u[e] = bf_bits(h); pl.u[e] = bf_bits(l);
  }
  ((uint2*)khi)[i] = ph.q;
  ((uint2*)klo)[i] = pl.q;
}

// helper macro: top-6 insertion for one accumulator pair at column NC
#define SEL8(ACC0, ACC1, NC)                                                              \
  _Pragma("unroll")                                                                       \
  for (int v=0;v<4;v++){                                                                  \
    float s0 = (ACC0)[v];                                                                 \
    if (s0 > thr8[v]){                                                                    \
      float mn = ts8[v][0]; int mp = 0;                                                   \
      _Pragma("unroll")                                                                   \
      for (int k=1;k<6;k++){ bool lt = ts8[v][k] < mn; mn = lt ? ts8[v][k] : mn; mp = lt ? k : mp; } \
      _Pragma("unroll")                                                                   \
      for (int k=0;k<6;k++) if (k==mp){ ts8[v][k] = s0; ti8[v][k] = (NC); }               \
      float nm = ts8[v][0];                                                               \
      _Pragma("unroll")                                                                   \
      for (int k=1;k<6;k++) nm = fminf(nm, ts8[v][k]);                                    \
      thr8[v] = nm;                                                                       \
    }                                                                                     \
    float s1 = (ACC1)[v];                                                                 \
    if (s1 > thr8[4+v]){                                                                  \
      float mn = ts8[4+v][0]; int mp = 0;                                                 \
      _Pragma("unroll")                                                                   \
      for (int k=1;k<6;k++){ bool lt = ts8[4+v][k] < mn; mn = lt ? ts8[4+v][k] : mn; mp = lt ? k : mp; } \
      _Pragma("unroll")                                                                   \
      for (int k=0;k<6;k++) if (k==mp){ ts8[4+v][k] = s1; ti8[4+v][k] = (NC); }           \
      float nm = ts8[4+v][0];                                                             \
      _Pragma("unroll")                                                                   \
      for (int k=1;k<6;k++) nm = fminf(nm, ts8[4+v][k]);                                  \
      thr8[4+v] = nm;                                                                     \
    }                                                                                     \
  }

// ============ scores via MFMA bf16x3, barrier-free + double-buffered K prefetch ============
__global__ __launch_bounds__(512) void k_scores_mfma(const float* __restrict__ Qm,
                                                     const ushort* __restrict__ khi,
                                                     const ushort* __restrict__ klo,
                                                     const float* __restrict__ Km,
                                                     float* __restrict__ tw, int* __restrict__ tidx,
                                                     float* __restrict__ out3, float* __restrict__ out4){
  __shared__ float Qt[32][132];
  __shared__ float wcs[8][32][8];      // per-wave top-8 per row
  __shared__ int   wci[8][32][8];
  const int t = threadIdx.x;
  const int rg = t>>6, c = t&63;       // wave 0..7, lane 0..63
  const int lrow = c&15, lk8 = c>>4;   // fragment row/col lane, k-group lane
  const int row0 = blockIdx.x*32;
  #pragma unroll
  for (int p=0;p<2;p++){
    int f = p*512+t; int r = f>>5, rq = f&31;
    float4 v = *(const float4*)&Qm[(size_t)(row0+r)*128 + rq*4];
    *(float4*)&Qt[r][rq*4] = v;
  }
  __syncthreads();
  // build Q fragments (bf16 hi/lo), 2 row-tiles x 4 k-chunks, all static -> 64 VGPR
  short8v qhi[2][4], qlo[2][4];
  #pragma unroll
  for (int rt=0;rt<2;rt++){
    #pragma unroll
    for (int kc=0;kc<4;kc++){
      union { ushort u[8]; short8v v; } th, tl;
      #pragma unroll
      for (int e=0;e<8;e++){
        float xq = Qt[rt*16+lrow][kc*32 + lk8*8 + e];
        __hip_bfloat16 h = __float2bfloat16(xq);
        float hf = __bfloat162float(h);
        __hip_bfloat16 l = __float2bfloat16(xq-hf);
        th.u[e] = bf_bits(h); tl.u[e] = bf_bits(l);
      }
      qhi[rt][kc] = th.v; qlo[rt][kc] = tl.v;
    }
  }
  // per-thread top-6 for this thread's 8 fixed rows
  float ts8[8][6]; int ti8[8][6]; float thr8[8];
  #pragma unroll
  for (int s=0;s<8;s++){
    thr8[s] = -3.0e38f;
    #pragma unroll
    for (int q=0;q<6;q++){ ts8[s][q] = -3.0e38f; ti8[s][q] = 0x7fffffff; }
  }
  // ---- phase 1: barrier-free MFMA GEMM, linearized it = nt*4+cq, A/B double-buffered loads ----
  short8v ah[4], al[4], bh[4], bl[4];
  int ncolA, ncolB;
  {
    int ncol = (rg*4+0)*16 + lrow; ncolA = ncol;        // it=0: nt=0, cq=0
    #pragma unroll
    for (int kc=0;kc<4;kc++){
      const size_t koff = (size_t)ncol*128 + kc*32 + lk8*8;
      ah[kc] = *(const short8v*)&khi[koff];
      al[kc] = *(const short8v*)&klo[koff];
    }
  }
  #pragma unroll 1
  for (int it=0; it<256; it+=2){
    // prefetch B = it+1
    {
      int nt = (it+1)>>2, cq = (it+1)&3;
      int ncol = nt*512 + (rg*4+cq)*16 + lrow; ncolB = ncol;
      #pragma unroll
      for (int kc=0;kc<4;kc++){
        const size_t koff = (size_t)ncol*128 + kc*32 + lk8*8;
        bh[kc] = *(const short8v*)&khi[koff];
        bl[kc] = *(const short8v*)&klo[koff];
      }
    }
    // compute + select A
    {
      f32x4 acc0 = {0.f,0.f,0.f,0.f};
      f32x4 acc1 = {0.f,0.f,0.f,0.f};
      #pragma unroll
      for (int kc=0;kc<4;kc++){
        acc0 = __builtin_amdgcn_mfma_f32_16x16x32_bf16(qhi[0][kc], ah[kc], acc0, 0,0,0);
        acc1 = __builtin_amdgcn_mfma_f32_16x16x32_bf16(qhi[1][kc], ah[kc], acc1, 0,0,0);
        acc0 = __builtin_amdgcn_mfma_f32_16x16x32_bf16(qlo[0][kc], ah[kc], acc0, 0,0,0);
        acc1 = __builtin_amdgcn_mfma_f32_16x16x32_bf16(qlo[1][kc], ah[kc], acc1, 0,0,0);
        acc0 = __builtin_amdgcn_mfma_f32_16x16x32_bf16(qhi[0][kc], al[kc], acc0, 0,0,0);
        acc1 = __builtin_amdgcn_mfma_f32_16x16x32_bf16(qhi[1][kc], al[kc], acc1, 0,0,0);
      }
      SEL8(acc0, acc1, ncolA)
    }
    // prefetch A = it+2
    if (it+2 < 256){
      int nt = (it+2)>>2, cq = (it+2)&3;
      int ncol = nt*512 + (rg*4+cq)*16 + lrow; ncolA = ncol;
      #pragma unroll
      for (int kc=0;kc<4;kc++){
        const size_t koff = (size_t)ncol*128 + kc*32 + lk8*8;
        ah[kc] = *(const short8v*)&khi[koff];
        al[kc] = *(const short8v*)&klo[koff];
      }
    }
    // compute + select B
    {
      f32x4 acc0 = {0.f,0.f,0.f,0.f};
      f32x4 acc1 = {0.f,0.f,0.f,0.f};
      #pragma unroll
      for (int kc=0;kc<4;kc++){
        acc0 = __builtin_amdgcn_mfma_f32_16x16x32_bf16(qhi[0][kc], bh[kc], acc0, 0,0,0);
        acc1 = __builtin_amdgcn_mfma_f32_16x16x32_bf16(qhi[1][kc], bh[kc], acc1, 0,0,0);
        acc0 = __builtin_amdgcn_mfma_f32_16x16x32_bf16(qlo[0][kc], bh[kc], acc0, 0,0,0);
        acc1 = __builtin_amdgcn_mfma_f32_16x16x32_bf16(qlo[1][kc], bh[kc], acc1, 0,0,0);
        acc0 = __builtin_amdgcn_mfma_f32_16x16x32_bf16(qhi[0][kc], bl[kc], acc0, 0,0,0);
        acc1 = __builtin_amdgcn_mfma_f32_16x16x32_bf16(qhi[1][kc], bl[kc], acc1, 0,0,0);
      }
      SEL8(acc0, acc1, ncolB)
    }
  }
  // ---- phase 2a: per-wave top-8 per row via 16-lane-group shuffles ----
  #pragma unroll
  for (int s=0;s<8;s++){
    const int rloc = (s<4) ? (lk8*4+s) : (16 + lk8*4 + (s-4));
    #pragma unroll 1
    for (int k=0;k<8;k++){
      float bs = ts8[s][0]; int bi = ti8[s][0];
      #pragma unroll
      for (int q=1;q<6;q++){
        bool bt = (ts8[s][q] > bs) || (ts8[s][q]==bs && ti8[s][q] < bi);
        bs = bt ? ts8[s][q] : bs; bi = bt ? ti8[s][q] : bi;
      }
      #pragma unroll
      for (int off=1; off<16; off<<=1){
        float os = __shfl_xor(bs, off, 16); int oi = __shfl_xor(bi, off, 16);
        bool bt = (os > bs) || (os==bs && oi < bi);
        bs = bt ? os : bs; bi = bt ? oi : bi;
      }
      #pragma unroll
      for (int q=0;q<6;q++){
        if (ti8[s][q]==bi){ ts8[s][q] = -3.0e38f; ti8[s][q] = 0x7fffffff; }
      }
      if (lrow==0){ wcs[rg][rloc][k] = bs; wci[rg][rloc][k] = bi; }
    }
  }
  __syncthreads();
  // ---- phase 2b: block top-16 per row (row = t>>4, 16-lane group merges 64 candidates) ----
  const int mrow = t>>4;        // 0..31
  const int ml   = t&15;
  float cs4[4]; int ci4[4];
  #pragma unroll
  for (int j=0;j<4;j++){
    int idx = ml*4+j;
    cs4[j] = wcs[idx>>3][mrow][idx&7];
    ci4[j] = wci[idx>>3][mrow][idx&7];
  }
  int myidx = 0;
  #pragma unroll 1
  for (int k=0;k<16;k++){
    float bs = cs4[0]; int bi = ci4[0];
    #pragma unroll
    for (int q=1;q<4;q++){
      bool bt = (cs4[q] > bs) || (cs4[q]==bs && ci4[q] < bi);
      bs = bt ? cs4[q] : bs; bi = bt ? ci4[q] : bi;
    }
    #pragma unroll
    for (int off=1; off<16; off<<=1){
      float os = __shfl_xor(bs, off, 16); int oi = __shfl_xor(bi, off, 16);
      bool bt = (os > bs) || (os==bs && oi < bi);
      bs = bt ? os : bs; bi = bt ? oi : bi;
    }
    #pragma unroll
    for (int q=0;q<4;q++){
      if (ci4[q]==bi){ cs4[q] = -3.0e38f; ci4[q] = 0x7fffffff; }
    }
    if (ml==k) myidx = bi;
  }
  // ---- phase 3: exact f64 rescore of 16 candidates/row; top-8 by (score desc, idx asc) ----
  const float* kr = Km + (size_t)myidx*128;
  const float* qrow = &Qt[mrow][0];
  double sd = 0.0;
  #pragma unroll 1
  for (int d4=0; d4<32; d4++){
    float4 kv = *(const float4*)&kr[d4*4];
    sd += (double)qrow[d4*4+0]*(double)kv.x;
    sd += (double)qrow[d4*4+1]*(double)kv.y;
    sd += (double)qrow[d4*4+2]*(double)kv.z;
    sd += (double)qrow[d4*4+3]*(double)kv.w;
  }
  double cs = sd; int ci = myidx;
  double sel0,sel1,sel2,sel3,sel4,sel5,sel6,sel7;
  int is0,is1,is2,is3,is4,is5,is6,is7;
  #pragma unroll
  for (int k8=0;k8<8;k8++){
    double bs = cs; int bi = ci;
    #pragma unroll
    for (int off=1; off<16; off<<=1){
      double os = __shfl_xor(bs, off, 16); int oi = __shfl_xor(bi, off, 16);
      bool bt = (os > bs) || (os==bs && oi < bi);
      bs = bt ? os : bs; bi = bt ? oi : bi;
    }
    if (ci==bi) cs = -1.0e300;
    if (k8==0){sel0=bs;is0=bi;} else if (k8==1){sel1=bs;is1=bi;}
    else if (k8==2){sel2=bs;is2=bi;} else if (k8==3){sel3=bs;is3=bi;}
    else if (k8==4){sel4=bs;is4=bi;} else if (k8==5){sel5=bs;is5=bi;}
    else if (k8==6){sel6=bs;is6=bi;} else {sel7=bs;is7=bi;}
  }
  if (ml==0){
    int grow = row0 + mrow;
    const double sc_inv = 0.08838834764831845;
    double mx = sel0;
    double e0 = exp((sel0-mx)*sc_inv), e1 = exp((sel1-mx)*sc_inv);
    double e2 = exp((sel2-mx)*sc_inv), e3 = exp((sel3-mx)*sc_inv);
    double e4 = exp((sel4-mx)*sc_inv), e5 = exp((sel5-mx)*sc_inv);
    double e6 = exp((sel6-mx)*sc_inv), e7 = exp((sel7-mx)*sc_inv);
    double sum = e0+e1+e2+e3+e4+e5+e6+e7;
    float w0=(float)(e0/sum),w1=(float)(e1/sum),w2=(float)(e2/sum),w3=(float)(e3/sum);
    float w4=(float)(e4/sum),w5=(float)(e5/sum),w6=(float)(e6/sum),w7=(float)(e7/sum);
    size_t o = (size_t)grow*8;
    tw[o+0]=w0; tw[o+1]=w1; tw[o+2]=w2; tw[o+3]=w3;
    tw[o+4]=w4; tw[o+5]=w5; tw[o+6]=w6; tw[o+7]=w7;
    tidx[o+0]=is0; tidx[o+1]=is1; tidx[o+2]=is2; tidx[o+3]=is3;
    tidx[o+4]=is4; tidx[o+5]=is5; tidx[o+6]=is6; tidx[o+7]=is7;
    out4[o+0]=w0; out4[o+1]=w1; out4[o+2]=w2; out4[o+3]=w3;
    out4[o+4]=w4; out4[o+5]=w5; out4[o+6]=w6; out4[o+7]=w7;
    out3[o+0]=(float)is0; out3[o+1]=(float)is1;
    out3[o+2]=(float)is2; out3[o+3]=(float)is3;
    out3[o+4]=(float)is4; out3[o+5]=(float)is5;
    out3[o+6]=(float)is6; out3[o+7]=(float)is7;
  }
}

// ============ scores fallback (round-7 f32 path, used if ws too small) ============
__global__ __launch_bounds__(512) void k_scores(const float* __restrict__ Qm, const float* __restrict__ Km,
                                                float* __restrict__ tw, int* __restrict__ tidx,
                                                float* __restrict__ out3, float* __restrict__ out4){
  __shared__ float Qt[32][132];
  __shared__ float Kt[512][20];
  __shared__ int candI[8][4][16];
  const int t = threadIdx.x;
  const int rg = t>>6, c = t&63;
  const int row0 = blockIdx.x*32;
  #pragma unroll
  for (int p=0;p<2;p++){
    int f = p*512+t; int r = f>>5, rq = f&31;
    float4 v = *(const float4*)&Qm[(size_t)(row0+r)*128 + rq*4];
    *(float4*)&Qt[r][rq*4] = v;
  }
  float ts[4][8]; int ti[4][8]; float thr[4];
  #pragma unroll
  for (int i=0;i<4;i++){
    thr[i] = -3.0e38f;
    #pragma unroll
    for (int k=0;k<8;k++){ ts[i][k] = -3.0e38f; ti[i][k] = 0x7fffffff; }
  }
  __syncthreads();
  #pragma unroll 1
  for (int nt=0;nt<64;nt++){
    const int nb = nt*512;
    float acc[4][8];
    #pragma unroll
    for (int i=0;i<4;i++){
      #pragma unroll
      for (int j=0;j<8;j++) acc[i][j]=0.f;
    }
    #pragma unroll 1
    for (int rc=0;rc<8;rc++){
      #pragma unroll
      for (int p=0;p<4;p++){
        int f = p*512+t; int nn = f>>2, rq = f&3;
        float4 v = *(const float4*)&Km[(size_t)(nb+nn)*128 + rc*16 + rq*4];
        *(float4*)&Kt[nn][rq*4] = v;
      }
      __syncthreads();
      #pragma unroll
      for (int r4=0;r4<4;r4++){
        float4 qv[4]; float4 kv[8];
        #pragma unroll
        for (int i=0;i<4;i++) qv[i] = *(const float4*)&Qt[rg*4+i][rc*16+r4*4];
        #pragma unroll
        for (int j=0;j<8;j++) kv[j] = *(const float4*)&Kt[c+64*j][r4*4];
        #pragma unroll
        for (int i=0;i<4;i++){
          #pragma unroll
          for (int j=0;j<8;j++){
            acc[i][j] += qv[i].x*kv[j].x;
            acc[i][j] += qv[i].y*kv[j].y;
            acc[i][j] += qv[i].z*kv[j].z;
            acc[i][j] += qv[i].w*kv[j].w;
          }
        }
      }
      __syncthreads();
    }
    #pragma unroll
    for (int i=0;i<4;i++){
      #pragma unroll
      for (int j=0;j<8;j++){
        float s = acc[i][j];
        if (s > thr[i]){
          int n = nb + c + 64*j;
          float mn = ts[i][0]; int mp = 0;
          #pragma unroll
          for (int k=1;k<8;k++){ bool lt = ts[i][k] < mn; mn = lt ? ts[i][k] : mn; mp = lt ? k : mp; }
          #pragma unroll
          for (int k=0;k<8;k++) if (k==mp){ ts[i][k] = s; ti[i][k] = n; }
          float nm = ts[i][0];
          #pragma unroll
          for (int k=1;k<8;k++) nm = fminf(nm, ts[i][k]);
          thr[i] = nm;
        }
      }
    }
  }
  #pragma unroll
  for (int i=0;i<4;i++){
    #pragma unroll 1
    for (int k=0;k<16;k++){
      float bs = ts[i][0]; int bi = ti[i][0];
      #pragma unroll
      for (int q=1;q<8;q++){
        bool bt = (ts[i][q] > bs) || (ts[i][q]==bs && ti[i][q] < bi);
        bs = bt ? ts[i][q] : bs; bi = bt ? ti[i][q] : bi;
      }
      #pragma unroll
      for (int off=1; off<64; off<<=1){
        float os = __shfl_xor(bs, off); int oi = __shfl_xor(bi, off);
        bool bt = (os > bs) || (os==bs && oi < bi);
        bs = bt ? os : bs; bi = bt ? oi : bi;
      }
      #pragma unroll
      for (int q=0;q<8;q++){
        if (ti[i][q]==bi){ ts[i][q] = -3.0e38f; ti[i][q] = 0x7fffffff; }
      }
      if (c==0) candI[rg][i][k] = bi;
    }
  }
  __syncthreads();
  const int ri = c>>4, rk = c&15;
  const int kidx = candI[rg][ri][rk];
  const float* kr = Km + (size_t)kidx*128;
  const float* qrow = &Qt[rg*4+ri][0];
  double sd = 0.0;
  #pragma unroll 1
  for (int d4=0; d4<32; d4++){
    float4 kv = *(const float4*)&kr[d4*4];
    sd += (double)qrow[d4*4+0]*(double)kv.x;
    sd += (double)qrow[d4*4+1]*(double)kv.y;
    sd += (double)qrow[d4*4+2]*(double)kv.z;
    sd += (double)qrow[d4*4+3]*(double)kv.w;
  }
  double cs = sd; int ci = kidx;
  double sel0,sel1,sel2,sel3,sel4,sel5,sel6,sel7;
  int is0,is1,is2,is3,is4,is5,is6,is7;
  #pragma unroll
  for (int k8=0;k8<8;k8++){
    double bs = cs; int bi = ci;
    #pragma unroll
    for (int off=1; off<16; off<<=1){
      double os = __shfl_xor(bs, off, 16); int oi = __shfl_xor(bi, off, 16);
      bool bt = (os > bs) || (os==bs && oi < bi);
      bs = bt ? os : bs; bi = bt ? oi : bi;
    }
    if (ci==bi) cs = -1.0e300;
    if (k8==0){sel0=bs;is0=bi;} else if (k8==1){sel1=bs;is1=bi;}
    else if (k8==2){sel2=bs;is2=bi;} else if (k8==3){sel3=bs;is3=bi;}
    else if (k8==4){sel4=bs;is4=bi;} else if (k8==5){sel5=bs;is5=bi;}
    else if (k8==6){sel6=bs;is6=bi;} else {sel7=bs;is7=bi;}
  }
  if (rk==0){
    int grow = row0 + rg*4 + ri;
    const double sc_inv = 0.08838834764831845;
    double mx = sel0;
    double e0 = exp((sel0-mx)*sc_inv), e1 = exp((sel1-mx)*sc_inv);
    double e2 = exp((sel2-mx)*sc_inv), e3 = exp((sel3-mx)*sc_inv);
    double e4 = exp((sel4-mx)*sc_inv), e5 = exp((sel5-mx)*sc_inv);
    double e6 = exp((sel6-mx)*sc_inv), e7 = exp((sel7-mx)*sc_inv);
    double sum = e0+e1+e2+e3+e4+e5+e6+e7;
    float w0=(float)(e0/sum),w1=(float)(e1/sum),w2=(float)(e2/sum),w3=(float)(e3/sum);
    float w4=(float)(e4/sum),w5=(float)(e5/sum),w6=(float)(e6/sum),w7=(float)(e7/sum);
    size_t o = (size_t)grow*8;
    tw[o+0]=w0; tw[o+1]=w1; tw[o+2]=w2; tw[o+3]=w3;
    tw[o+4]=w4; tw[o+5]=w5; tw[o+6]=w6; tw[o+7]=w7;
    tidx[o+0]=is0; tidx[o+1]=is1; tidx[o+2]=is2; tidx[o+3]=is3;
    tidx[o+4]=is4; tidx[o+5]=is5; tidx[o+6]=is6; tidx[o+7]=is7;
    out4[o+0]=w0; out4[o+1]=w1; out4[o+2]=w2; out4[o+3]=w3;
    out4[o+4]=w4; out4[o+5]=w5; out4[o+6]=w6; out4[o+7]=w7;
    out3[o+0]=(float)is0; out3[o+1]=(float)is1;
    out3[o+2]=(float)is2; out3[o+3]=(float)is3;
    out3[o+4]=(float)is4; out3[o+5]=(float)is5;
    out3[o+6]=(float)is6; out3[o+7]=(float)is7;
  }
}

// ============ gather + weighted sum -> output (float32) ============
__global__ __launch_bounds__(256) void k_gather(const float* __restrict__ V, const int* __restrict__ tidx,
                                                const float* __restrict__ tw, float* __restrict__ out0){
  int row = blockIdx.x; int t = threadIdx.x;
  __shared__ int li[8]; __shared__ float lw[8];
  if (t<8){
    int idx = tidx[(size_t)row*8+t];
    idx = idx < 0 ? 0 : (idx > (NK_-1) ? (NK_-1) : idx);
    li[t] = idx;
  } else if (t<16){
    float w = tw[(size_t)row*8 + t-8];
    w = fminf(fmaxf(w, 0.f), 1.f);
    lw[t-8] = w;
  }
  __syncthreads();
  float4 a = {0,0,0,0};
  #pragma unroll
  for (int k=0;k<8;k++){
    float4 v = ((const float4*)V)[(size_t)li[k]*256 + t];
    float w = lw[k];
    a.x += w*v.x; a.y += w*v.y; a.z += w*v.z; a.w += w*v.w;
  }
  ((float4*)(out0 + (size_t)row*1024))[t] = a;
}

extern "C" void kernel_launch(void* const* d_in, const int* in_sizes, int n_in,
                              void* d_out, int out_size, void* d_ws, size_t ws_size,
                              hipStream_t stream) {
  const float* x    = (const float*)d_in[0];
  const float* A    = (const float*)d_in[1];
  const float* Bm   = (const float*)d_in[2];
  const float* Wimp = (const float*)d_in[3];
  const float* Wr   = (const float*)d_in[4];
  const float* comp = (const float*)d_in[5];
  const float* Kmat = (const float*)d_in[6];
  const float* V    = (const float*)d_in[7];
  float* out = (float*)d_out;               // OUTPUT IS FLOAT32
  float* ws = (float*)d_ws;

  float* xB    = ws + OFF_XB;
  float* tp    = ws + OFF_TP;
  float* Apow  = ws + OFF_APOW;
  float* P     = ws + OFF_P;
  float* hproj = ws + OFF_HPROJ;
  float* logit = ws + OFF_LOGIT;
  float* imp   = ws + OFF_IMP;
  float* nw    = ws + OFF_NW;
  float* scb   = ws + OFF_SC;
  float* Qb    = ws + OFF_Q;        // aliases xB+tp (both dead by the time k_Q runs)
  int*   tidx  = (int*)(ws + OFF_TIDX);
  float* tw    = ws + OFF_TW;
  ushort* khi  = (ushort*)(ws + OFF_KHI);
  ushort* klo  = (ushort*)(ws + OFF_KLO);

  const bool use_mfma = (ws_size >= WS_NEED_MFMA);

  k_init_apow<<<32,256,0,stream>>>(A, Apow);
  if (use_mfma) k_split<<<4096,256,0,stream>>>(Kmat, khi, klo);
  k_matstage<<<1 ,256,0,stream>>>(Apow, 2 ,1 ,1);
  k_matstage<<<2 ,256,0,stream>>>(Apow, 3 ,2 ,1);
  k_matstage<<<4 ,256,0,stream>>>(Apow, 5 ,4 ,1);
  k_matstage<<<8 ,256,0,stream>>>(Apow, 9 ,8 ,1);
  k_matstage<<<16,256,0,stream>>>(Apow, 17,16,1);
  k_matstage<<<32,256,0,stream>>>(Apow, 33,32,1);
  k_xbr<<<256,256,0,stream>>>(x, Bm, Wr, xB, tp);
  k_P<<<32,256,0,stream>>>(xB, Apow, P);
  k_scan<<<1,256,0,stream>>>(Apow, P, Wimp, hproj);
  k_implogit<<<8192,256,0,stream>>>(x, hproj, logit);
  k_softS<<<4,1024,0,stream>>>(logit, imp, out + O_IMP);
  k_nw<<<4,256,0,stream>>>(imp, tp, nw, out + O_NW);
  k_sc<<<128,256,0,stream>>>(nw, comp, scb);
  k_Q<<<256,256,0,stream>>>(x, scb, Qb);
  if (use_mfma)
    k_scores_mfma<<<256,512,0,stream>>>(Qb, khi, klo, Kmat, tw, tidx, out + O_TIDX, out + O_TW);
  else
    k_scores<<<256,512,0,stream>>>(Qb, Kmat, tw, tidx, out + O_TIDX, out + O_TW);
  k_gather<<<8192,256,0,stream>>>(V, tidx, tw, out + O_OUT);
}

// Round 15
// 1048.834 us; speedup vs baseline: 1.7710x; 1.0354x over previous
//
#include <hip/hip_runtime.h>
#include <hip/hip_bf16.h>
#include <math.h>

#define B_  4
#define S_  2048
#define D_  1024
#define R_  128
#define NC_ 64
#define NK_ 32768
#define SD_ 64
#define KK_ 8

typedef __attribute__((ext_vector_type(8))) short short8v;  // 8 bf16 (4 VGPRs)
typedef __attribute__((ext_vector_type(4))) float f32x4;

// ---------------- ws layout (float offsets) ----------------
static const size_t OFF_XB    = 0;         // [8192][64]
static const size_t OFF_TP    = 524288;    // [8192][64]
static const size_t OFF_APOW  = 1048576;   // [65][64][64]
static const size_t OFF_P     = 1314816;   // [32][4][64]
static const size_t OFF_HPROJ = 1323008;   // [4][1024]
static const size_t OFF_LOGIT = 1327104;   // [4][2048]
static const size_t OFF_IMP   = 1335296;   // [4][2048]
static const size_t OFF_NW    = 1343488;   // [4][64]
static const size_t OFF_SC    = 1343744;   // [4][1024][128]
static const size_t OFF_Q     = 0;         // [8192][128] aliases XB+TP (stream-ordered safe)
static const size_t OFF_TIDX  = 1868032;   // [8192][8] int
static const size_t OFF_TW    = 1933568;   // [8192][8]  -> 1999104
// MFMA path extras (bf16 split of K), only used when ws_size is large enough:
static const size_t OFF_KHI   = 1999104;   // [32768][128] ushort -> 2,097,152 floats
static const size_t OFF_KLO   = 4096256;   // [32768][128] ushort -> 2,097,152 floats
static const size_t WS_NEED_MFMA = (size_t)6193408 * 4;   // bytes

// -------- output layout (FLOAT32 offsets) --------
static const size_t O_OUT  = 0;
static const size_t O_IMP  = 8388608;
static const size_t O_NW   = 8396800;
static const size_t O_TIDX = 8397056;
static const size_t O_TW   = 8462592;

__device__ __forceinline__ ushort bf_bits(__hip_bfloat16 h){ return *reinterpret_cast<ushort*>(&h); }

// ============ Apow init ============
__global__ __launch_bounds__(256) void k_init_apow(const float* __restrict__ A, float* __restrict__ Apow){
  int t = blockIdx.x*256 + threadIdx.x;
  if (t < 4096){ int i = t>>6, j = t&63; Apow[t] = (i==j) ? 1.f : 0.f; }
  else Apow[t] = A[t-4096];
}

// ============ batched 64x64x64 matmul (f64 accumulate) ============
__global__ __launch_bounds__(256) void k_matstage(float* __restrict__ Apow, int dst0, int lhs, int rhs0){
  __shared__ float L[64][68];
  __shared__ float Rm[64][68];
  const float* Lp = Apow + (size_t)lhs*4096;
  const float* Rp = Apow + (size_t)(rhs0 + blockIdx.x)*4096;
  int t = threadIdx.x;
  #pragma unroll 1
  for (int p=0;p<4;p++){
    int f = p*256+t; int i = f>>4, jq = f&15;
    float4 v = ((const float4*)Lp)[f];
    L[i][jq*4+0]=v.x; L[i][jq*4+1]=v.y; L[i][jq*4+2]=v.z; L[i][jq*4+3]=v.w;
    float4 w = ((const float4*)Rp)[f];
    Rm[i][jq*4+0]=w.x; Rm[i][jq*4+1]=w.y; Rm[i][jq*4+2]=w.z; Rm[i][jq*4+3]=w.w;
  }
  __syncthreads();
  int j = t&63, rg = t>>6;
  double acc[16];
  #pragma unroll
  for (int ii=0;ii<16;ii++) acc[ii]=0.0;
  #pragma unroll 1
  for (int kk=0;kk<64;kk++){
    double rv = (double)Rm[kk][j];
    #pragma unroll
    for (int ii=0;ii<16;ii++) acc[ii] += (double)L[rg*16+ii][kk]*rv;
  }
  float* out = Apow + (size_t)(dst0 + blockIdx.x)*4096;
  #pragma unroll
  for (int ii=0;ii<16;ii++) out[(rg*16+ii)*64 + j] = (float)acc[ii];
}

// ============ xB + router logits GEMM, 32-row tiles (256 blocks: full CU coverage) ============
__global__ __launch_bounds__(256) void k_xbr(const float* __restrict__ x, const float* __restrict__ Bm,
                                             const float* __restrict__ Wr,
                                             float* __restrict__ xB, float* __restrict__ tp){
  int row0 = blockIdx.x*32;
  __shared__ float Xt[32][36];
  __shared__ float Wt[32][132];
  __shared__ float SB[32][65];
  int t = threadIdx.x;
  int rg = t>>5, c = t&31;
  double accd[4][4];
  #pragma unroll
  for (int i=0;i<4;i++){
    #pragma unroll
    for (int j=0;j<4;j++) accd[i][j]=0.0;
  }
  #pragma unroll 1
  for (int kc=0;kc<32;kc++){
    int d0 = kc*32;
    {
      int f = t; int r = f>>3, dq = f&7;
      float4 v = *(const float4*)&x[(size_t)(row0+r)*1024 + d0 + dq*4];
      Xt[r][dq*4+0]=v.x; Xt[r][dq*4+1]=v.y; Xt[r][dq*4+2]=v.z; Xt[r][dq*4+3]=v.w;
    }
    #pragma unroll
    for (int p=0;p<2;p++){
      int f = p*256+t; int dd = f>>4, eq = f&15;
      float4 v = *(const float4*)&Bm[(size_t)(d0+dd)*64 + eq*4];
      Wt[dd][eq*4+0]=v.x; Wt[dd][eq*4+1]=v.y; Wt[dd][eq*4+2]=v.z; Wt[dd][eq*4+3]=v.w;
    }
    #pragma unroll
    for (int p=0;p<2;p++){
      int f = p*256+t; int n = f>>3, dq = f&7;
      float4 v = *(const float4*)&Wr[(size_t)n*1024 + d0 + dq*4];
      Wt[dq*4+0][64+n]=v.x; Wt[dq*4+1][64+n]=v.y; Wt[dq*4+2][64+n]=v.z; Wt[dq*4+3][64+n]=v.w;
    }
    __syncthreads();
    float accf[4][4];
    #pragma unroll
    for (int i=0;i<4;i++){
      #pragma unroll
      for (int j=0;j<4;j++) accf[i][j]=0.f;
    }
    #pragma unroll
    for (int k4=0;k4<8;k4++){
      float4 xv[4];
      #pragma unroll
      for (int i=0;i<4;i++) xv[i] = *(const float4*)&Xt[rg*4+i][k4*4];
      #pragma unroll
      for (int u=0;u<4;u++){
        int kk = k4*4+u;
        float wv[4];
        #pragma unroll
        for (int j=0;j<4;j++) wv[j] = Wt[kk][c+32*j];
        #pragma unroll
        for (int i=0;i<4;i++){
          float xs = (u==0)?xv[i].x:(u==1)?xv[i].y:(u==2)?xv[i].z:xv[i].w;
          #pragma unroll
          for (int j=0;j<4;j++) accf[i][j] += xs*wv[j];
        }
      }
    }
    #pragma unroll
    for (int i=0;i<4;i++){
      #pragma unroll
      for (int j=0;j<4;j++) accd[i][j] += (double)accf[i][j];
    }
    __syncthreads();
  }
  #pragma unroll
  for (int i=0;i<4;i++){
    int row = row0 + rg*4 + i;
    xB[(size_t)row*64 + c]      = (float)accd[i][0];
    xB[(size_t)row*64 + c + 32] = (float)accd[i][1];
    SB[rg*4+i][c]    = (float)accd[i][2];
    SB[rg*4+i][c+32] = (float)accd[i][3];
  }
  __syncthreads();
  if (t < 32){
    double m = -1.0e300;
    #pragma unroll 1
    for (int n=0;n<64;n++) m = fmax(m, (double)SB[t][n]);
    double s = 0.0;
    #pragma unroll 1
    for (int n=0;n<64;n++){ double e = exp((double)SB[t][n]-m); SB[t][n]=(float)e; s += e; }
    int row = row0 + t;
    #pragma unroll 1
    for (int n=0;n<64;n++) tp[(size_t)row*64 + n] = (float)((double)SB[t][n]/s);
  }
}

// ============ chunk partials (f64 accumulate) ============
__global__ __launch_bounds__(256) void k_P(const float* __restrict__ xB, const float* __restrict__ Apow,
                                           float* __restrict__ P){
  int cchunk = blockIdx.x; int t = threadIdx.x;
  int b = t>>6, e = t&63;
  double acc = 0.0;
  #pragma unroll 1
  for (int l=0;l<64;l++){
    const float* xr = &xB[((size_t)b*2048 + cchunk*64 + l)*64];
    const float* Ap = &Apow[(size_t)(63-l)*4096];
    #pragma unroll
    for (int k4=0;k4<16;k4++){
      float4 xv = *(const float4*)&xr[k4*4];
      acc += (double)xv.x*(double)Ap[(k4*4+0)*64+e];
      acc += (double)xv.y*(double)Ap[(k4*4+1)*64+e];
      acc += (double)xv.z*(double)Ap[(k4*4+2)*64+e];
      acc += (double)xv.w*(double)Ap[(k4*4+3)*64+e];
    }
  }
  P[cchunk*256 + t] = (float)acc;
}

// ============ Horner combine (f64) + h_proj ============
__global__ __launch_bounds__(256) void k_scan(const float* __restrict__ Apow, const float* __restrict__ P,
                                              const float* __restrict__ Wimp, float* __restrict__ hproj){
  __shared__ float A64s[64][68];
  __shared__ double h[2][4][64];
  int t = threadIdx.x;
  const float* A64 = Apow + (size_t)64*4096;
  #pragma unroll 1
  for (int p=0;p<4;p++){
    int f = p*256+t; int i = f>>4, jq = f&15;
    float4 v = *(const float4*)&A64[f*4];
    A64s[i][jq*4+0]=v.x; A64s[i][jq*4+1]=v.y; A64s[i][jq*4+2]=v.z; A64s[i][jq*4+3]=v.w;
  }
  int b = t>>6, e = t&63;
  h[0][b][e] = 0.0;
  __syncthreads();
  #pragma unroll 1
  for (int c=0;c<32;c++){
    int cur = c&1;
    double acc = (double)P[c*256 + t];
    #pragma unroll
    for (int k=0;k<64;k++) acc += h[cur][b][k]*(double)A64s[k][e];
    h[cur^1][b][e] = acc;
    __syncthreads();
  }
  #pragma unroll 1
  for (int m=0;m<16;m++){
    int o = t + 256*m; int bb = o>>10, d = o&1023;
    const float* wrow = &Wimp[(size_t)d*64];
    double acc = 0.0;
    #pragma unroll
    for (int e4=0;e4<16;e4++){
      float4 w = *(const float4*)&wrow[e4*4];
      acc += h[0][bb][e4*4+0]*(double)w.x;
      acc += h[0][bb][e4*4+1]*(double)w.y;
      acc += h[0][bb][e4*4+2]*(double)w.z;
      acc += h[0][bb][e4*4+3]*(double)w.w;
    }
    hproj[o] = (float)acc;
  }
}

// ============ importance logits (f64) ============
__global__ __launch_bounds__(256) void k_implogit(const float* __restrict__ x, const float* __restrict__ hproj,
                                                  float* __restrict__ logits){
  int row = blockIdx.x; int b = row>>11;
  int t = threadIdx.x;
  float4 xv = ((const float4*)x)[(size_t)row*256 + t];
  float4 hv = ((const float4*)hproj)[(size_t)b*256 + t];
  double p = (double)xv.x*(double)hv.x + (double)xv.y*(double)hv.y
           + (double)xv.z*(double)hv.z + (double)xv.w*(double)hv.w;
  #pragma unroll
  for (int off=32; off; off>>=1) p += __shfl_down(p, off);
  __shared__ double ws4[4];
  if ((t&63)==0) ws4[t>>6] = p;
  __syncthreads();
  if (t==0) logits[row] = (float)(ws4[0]+ws4[1]+ws4[2]+ws4[3]);
}

// ============ softmax over S per batch (f64) ============
__global__ __launch_bounds__(1024) void k_softS(const float* __restrict__ logits, float* __restrict__ imp,
                                                float* __restrict__ out1){
  int b = blockIdx.x; int t = threadIdx.x;
  double v0 = (double)logits[b*2048 + t];
  double v1 = (double)logits[b*2048 + 1024 + t];
  double m = fmax(v0,v1);
  #pragma unroll
  for (int off=32; off; off>>=1) m = fmax(m, __shfl_xor(m, off));
  __shared__ double red[16];
  if ((t&63)==0) red[t>>6] = m;
  __syncthreads();
  double M = red[0];
  #pragma unroll 1
  for (int i=1;i<16;i++) M = fmax(M, red[i]);
  double p0 = exp(v0-M), p1 = exp(v1-M);
  double s = p0+p1;
  #pragma unroll
  for (int off=32; off; off>>=1) s += __shfl_xor(s, off);
  __syncthreads();
  if ((t&63)==0) red[t>>6] = s;
  __syncthreads();
  double S = 0.0;
  #pragma unroll 1
  for (int i=0;i<16;i++) S += red[i];
  float i0 = (float)(p0/S), i1 = (float)(p1/S);
  imp[b*2048+t] = i0; imp[b*2048+1024+t] = i1;
  out1[b*2048+t] = i0; out1[b*2048+1024+t] = i1;
}

// ============ neuron_w (f64) ============
__global__ __launch_bounds__(256) void k_nw(const float* __restrict__ imp, const float* __restrict__ tp,
                                            float* __restrict__ nw, float* __restrict__ out2){
  int b = blockIdx.x; int t = threadIdx.x;
  int n = t&63, sg = t>>6;
  double acc = 0.0;
  #pragma unroll 1
  for (int s=sg; s<2048; s+=4)
    acc += (double)imp[b*2048+s]*(double)tp[((size_t)b*2048+s)*64 + n];
  __shared__ double part[4][64];
  part[sg][n] = acc;
  __syncthreads();
  if (t<64){
    double v = part[0][t]+part[1][t]+part[2][t]+part[3][t];
    double tot = v;
    #pragma unroll
    for (int off=32; off; off>>=1) tot += __shfl_xor(tot, off);
    float r = (float)(v/(tot + 1e-8));
    nw[b*64+t] = r; out2[b*64+t] = r;
  }
}

// ============ shared_compress (f64 accumulate) ============
__global__ __launch_bounds__(256) void k_sc(const float* __restrict__ nw, const float* __restrict__ comp,
                                            float* __restrict__ sc){
  __shared__ float w[256];
  int t = threadIdx.x;
  w[t] = nw[t];
  __syncthreads();
  size_t base = (size_t)blockIdx.x*1024 + t*4;
  double a[4][4];
  #pragma unroll
  for (int i=0;i<4;i++){
    #pragma unroll
    for (int j=0;j<4;j++) a[i][j]=0.0;
  }
  #pragma unroll 1
  for (int n=0;n<64;n++){
    float4 cv = *(const float4*)&comp[(size_t)n*131072 + base];
    double cx=cv.x, cy=cv.y, cz=cv.z, cw=cv.w;
    double w0=w[n], w1=w[64+n], w2=w[128+n], w3=w[192+n];
    a[0][0]+=w0*cx; a[0][1]+=w0*cy; a[0][2]+=w0*cz; a[0][3]+=w0*cw;
    a[1][0]+=w1*cx; a[1][1]+=w1*cy; a[1][2]+=w1*cz; a[1][3]+=w1*cw;
    a[2][0]+=w2*cx; a[2][1]+=w2*cy; a[2][2]+=w2*cz; a[2][3]+=w2*cw;
    a[3][0]+=w3*cx; a[3][1]+=w3*cy; a[3][2]+=w3*cz; a[3][3]+=w3*cw;
  }
  #pragma unroll
  for (int i=0;i<4;i++){
    float4 o; o.x=(float)a[i][0]; o.y=(float)a[i][1]; o.z=(float)a[i][2]; o.w=(float)a[i][3];
    *(float4*)&sc[(size_t)i*131072 + base] = o;
  }
}

// ============ Q = x @ sc[b], 32-row tiles (256 blocks: full CU coverage) ============
__global__ __launch_bounds__(256) void k_Q(const float* __restrict__ x, const float* __restrict__ sc,
                                           float* __restrict__ Q){
  int bid = blockIdx.x;
  int b = bid>>6;
  int row0 = b*2048 + (bid&63)*32;
  __shared__ float Xt[32][36];
  __shared__ float Wt[32][132];
  int t = threadIdx.x; int rg = t>>5, c = t&31;
  double accd[4][4];
  #pragma unroll
  for (int i=0;i<4;i++){
    #pragma unroll
    for (int j=0;j<4;j++) accd[i][j]=0.0;
  }
  #pragma unroll 1
  for (int kc=0;kc<32;kc++){
    int d0 = kc*32;
    {
      int f = t; int r = f>>3, dq = f&7;
      float4 v = *(const float4*)&x[(size_t)(row0+r)*1024 + d0 + dq*4];
      Xt[r][dq*4+0]=v.x; Xt[r][dq*4+1]=v.y; Xt[r][dq*4+2]=v.z; Xt[r][dq*4+3]=v.w;
    }
    #pragma unroll
    for (int p=0;p<4;p++){
      int f = p*256+t; int dd = f>>5, nq = f&31;
      float4 v = *(const float4*)&sc[(size_t)b*131072 + (size_t)(d0+dd)*128 + nq*4];
      Wt[dd][nq*4+0]=v.x; Wt[dd][nq*4+1]=v.y; Wt[dd][nq*4+2]=v.z; Wt[dd][nq*4+3]=v.w;
    }
    __syncthreads();
    float accf[4][4];
    #pragma unroll
    for (int i=0;i<4;i++){
      #pragma unroll
      for (int j=0;j<4;j++) accf[i][j]=0.f;
    }
    #pragma unroll
    for (int k4=0;k4<8;k4++){
      float4 xv[4];
      #pragma unroll
      for (int i=0;i<4;i++) xv[i] = *(const float4*)&Xt[rg*4+i][k4*4];
      #pragma unroll
      for (int u=0;u<4;u++){
        int kk = k4*4+u;
        float wv[4];
        #pragma unroll
        for (int j=0;j<4;j++) wv[j] = Wt[kk][c+32*j];
        #pragma unroll
        for (int i=0;i<4;i++){
          float xs = (u==0)?xv[i].x:(u==1)?xv[i].y:(u==2)?xv[i].z:xv[i].w;
          #pragma unroll
          for (int j=0;j<4;j++) accf[i][j] += xs*wv[j];
        }
      }
    }
    #pragma unroll
    for (int i=0;i<4;i++){
      #pragma unroll
      for (int j=0;j<4;j++) accd[i][j] += (double)accf[i][j];
    }
    __syncthreads();
  }
  #pragma unroll
  for (int i=0;i<4;i++){
    #pragma unroll
    for (int j=0;j<4;j++)
      Q[(size_t)(row0+rg*4+i)*128 + c + 32*j] = (float)accd[i][j];
  }
}

// ============ K -> bf16 hi/lo split ============
__global__ __launch_bounds__(256) void k_split(const float* __restrict__ K, ushort* __restrict__ khi,
                                               ushort* __restrict__ klo){
  int i = blockIdx.x*256 + threadIdx.x;   // over 1,048,576 float4s
  float4 v = ((const float4*)K)[i];
  union { ushort u[4]; uint2 q; } ph, pl;
  float xs[4] = {v.x, v.y, v.z, v.w};
  #pragma unroll
  for (int e=0;e<4;e++){
    __hip_bfloat16 h = __float2bfloat16(xs[e]);
    float hf = __bfloat162float(h);
    __hip_bfloat16 l = __float2bfloat16(xs[e]-hf);
    ph.u[e] = bf_bits(h); pl.u[e] = bf_bits(l);
  }
  ((uint2*)khi)[i] = ph.q;
  ((uint2*)klo)[i] = pl.q;
}

// load K fragment set for iteration IT into (BH,BL); NCB = base neuron index for this thread's acc
#define LOADK(BH, BL, NCB, IT) {                                          \
  int nt_ = (IT)>>2, cq_ = (IT)&3;                                        \
  int base_ = nt_*512 + (rg*4+cq_)*16;                                    \
  NCB = base_ + lk8*4;                                                    \
  const size_t ko_ = (size_t)(base_ + lrow)*128 + lk8*8;                  \
  BH[0] = *(const short8v*)&khi[ko_];      BL[0] = *(const short8v*)&klo[ko_];      \
  BH[1] = *(const short8v*)&khi[ko_+32];   BL[1] = *(const short8v*)&klo[ko_+32];   \
  BH[2] = *(const short8v*)&khi[ko_+64];   BL[2] = *(const short8v*)&klo[ko_+64];   \
  BH[3] = *(const short8v*)&khi[ko_+96];   BL[3] = *(const short8v*)&klo[ko_+96];   \
}

// compute + select: swapped operands -> acc row = neuron, col = q-row (thread owns 2 q-rows)
#define COMPSEL(BH, BL, NCB) {                                            \
  f32x4 a0 = {0.f,0.f,0.f,0.f};                                           \
  f32x4 a1 = {0.f,0.f,0.f,0.f};                                           \
  _Pragma("unroll")                                                       \
  for (int kc=0;kc<4;kc++){                                               \
    a0 = __builtin_amdgcn_mfma_f32_16x16x32_bf16(BH[kc], qhi[0][kc], a0, 0,0,0); \
    a1 = __builtin_amdgcn_mfma_f32_16x16x32_bf16(BH[kc], qhi[1][kc], a1, 0,0,0); \
    a0 = __builtin_amdgcn_mfma_f32_16x16x32_bf16(BL[kc], qhi[0][kc], a0, 0,0,0); \
    a1 = __builtin_amdgcn_mfma_f32_16x16x32_bf16(BL[kc], qhi[1][kc], a1, 0,0,0); \
    a0 = __builtin_amdgcn_mfma_f32_16x16x32_bf16(BH[kc], qlo[0][kc], a0, 0,0,0); \
    a1 = __builtin_amdgcn_mfma_f32_16x16x32_bf16(BH[kc], qlo[1][kc], a1, 0,0,0); \
  }                                                                       \
  _Pragma("unroll")                                                       \
  for (int v=0;v<4;v++){                                                  \
    float s0 = a0[v];                                                     \
    if (s0 > thr0){                                                       \
      float mn = ts0[0]; int mp = 0;                                      \
      _Pragma("unroll")                                                   \
      for (int k=1;k<6;k++){ bool lt = ts0[k] < mn; mn = lt ? ts0[k] : mn; mp = lt ? k : mp; } \
      _Pragma("unroll")                                                   \
      for (int k=0;k<6;k++) if (k==mp){ ts0[k] = s0; ti0[k] = NCB + v; }  \
      float nm = ts0[0];                                                  \
      _Pragma("unroll")                                                   \
      for (int k=1;k<6;k++) nm = fminf(nm, ts0[k]);                       \
      thr0 = nm;                                                          \
    }                                                                     \
    float s1 = a1[v];                                                     \
    if (s1 > thr1){                                                       \
      float mn = ts1[0]; int mp = 0;                                      \
      _Pragma("unroll")                                                   \
      for (int k=1;k<6;k++){ bool lt = ts1[k] < mn; mn = lt ? ts1[k] : mn; mp = lt ? k : mp; } \
      _Pragma("unroll")                                                   \
      for (int k=0;k<6;k++) if (k==mp){ ts1[k] = s1; ti1[k] = NCB + v; }  \
      float nm = ts1[0];                                                  \
      _Pragma("unroll")                                                   \
      for (int k=1;k<6;k++) nm = fminf(nm, ts1[k]);                       \
      thr1 = nm;                                                          \
    }                                                                     \
  }                                                                       \
}

// ============ scores via MFMA bf16x3 (swapped operands), 4-deep K prefetch ============
__global__ __launch_bounds__(512) void k_scores_mfma(const float* __restrict__ Qm,
                                                     const ushort* __restrict__ khi,
                                                     const ushort* __restrict__ klo,
                                                     const float* __restrict__ Km,
                                                     float* __restrict__ tw, int* __restrict__ tidx,
                                                     float* __restrict__ out3, float* __restrict__ out4){
  __shared__ float Qt[32][132];
  __shared__ float wcs[8][32][8];      // per-wave top-8 per row
  __shared__ int   wci[8][32][8];
  const int t = threadIdx.x;
  const int rg = t>>6, c = t&63;       // wave 0..7, lane 0..63
  const int lrow = c&15, lk8 = c>>4;   // fragment row/col lane, k-group lane
  const int row0 = blockIdx.x*32;
  #pragma unroll
  for (int p=0;p<2;p++){
    int f = p*512+t; int r = f>>5, rq = f&31;
    float4 v = *(const float4*)&Qm[(size_t)(row0+r)*128 + rq*4];
    *(float4*)&Qt[r][rq*4] = v;
  }
  __syncthreads();
  // build Q fragments (bf16 hi/lo); B-operand layout: col=lane&15 = q-row (same build as A)
  short8v qhi[2][4], qlo[2][4];
  #pragma unroll
  for (int rt=0;rt<2;rt++){
    #pragma unroll
    for (int kc=0;kc<4;kc++){
      union { ushort u[8]; short8v v; } th, tl;
      #pragma unroll
      for (int e=0;e<8;e++){
        float xq = Qt[rt*16+lrow][kc*32 + lk8*8 + e];
        __hip_bfloat16 h = __float2bfloat16(xq);
        float hf = __bfloat162float(h);
        __hip_bfloat16 l = __float2bfloat16(xq-hf);
        th.u[e] = bf_bits(h); tl.u[e] = bf_bits(l);
      }
      qhi[rt][kc] = th.v; qlo[rt][kc] = tl.v;
    }
  }
  // per-thread top-6 for this thread's TWO q-rows: lrow (bank0), lrow+16 (bank1)
  float ts0[6], ts1[6]; int ti0[6], ti1[6]; float thr0, thr1;
  thr0 = thr1 = -3.0e38f;
  #pragma unroll
  for (int q=0;q<6;q++){ ts0[q]=-3.0e38f; ti0[q]=0x7fffffff; ts1[q]=-3.0e38f; ti1[q]=0x7fffffff; }
  // ---- phase 1: barrier-free MFMA, 4 rotating K buffers (3-deep prefetch) ----
  short8v h0[4],l0[4],h1[4],l1[4],h2[4],l2[4],h3[4],l3[4];
  int n0,n1,n2,n3;
  LOADK(h0,l0,n0,0)
  LOADK(h1,l1,n1,1)
  LOADK(h2,l2,n2,2)
  #pragma unroll 1
  for (int it=0; it<256; it+=4){
    if (it+3 < 256) LOADK(h3,l3,n3,it+3)
    COMPSEL(h0,l0,n0)
    if (it+4 < 256) LOADK(h0,l0,n0,it+4)
    COMPSEL(h1,l1,n1)
    if (it+5 < 256) LOADK(h1,l1,n1,it+5)
    COMPSEL(h2,l2,n2)
    if (it+6 < 256) LOADK(h2,l2,n2,it+6)
    COMPSEL(h3,l3,n3)
  }
  // ---- phase 2a: per-row wave top-8; row r merged across 4 lanes {r&15 + 16*lk8} ----
  {
    const int rloc = lrow;          // bank 0
    #pragma unroll 1
    for (int k=0;k<8;k++){
      float bs = ts0[0]; int bi = ti0[0];
      #pragma unroll
      for (int q=1;q<6;q++){
        bool bt = (ts0[q] > bs) || (ts0[q]==bs && ti0[q] < bi);
        bs = bt ? ts0[q] : bs; bi = bt ? ti0[q] : bi;
      }
      #pragma unroll
      for (int off=16; off<64; off<<=1){
        float os = __shfl_xor(bs, off); int oi = __shfl_xor(bi, off);
        bool bt = (os > bs) || (os==bs && oi < bi);
        bs = bt ? os : bs; bi = bt ? oi : bi;
      }
      #pragma unroll
      for (int q=0;q<6;q++){
        if (ti0[q]==bi){ ts0[q] = -3.0e38f; ti0[q] = 0x7fffffff; }
      }
      if (lk8==0){ wcs[rg][rloc][k] = bs; wci[rg][rloc][k] = bi; }
    }
  }
  {
    const int rloc = 16 + lrow;     // bank 1
    #pragma unroll 1
    for (int k=0;k<8;k++){
      float bs = ts1[0]; int bi = ti1[0];
      #pragma unroll
      for (int q=1;q<6;q++){
        bool bt = (ts1[q] > bs) || (ts1[q]==bs && ti1[q] < bi);
        bs = bt ? ts1[q] : bs; bi = bt ? ti1[q] : bi;
      }
      #pragma unroll
      for (int off=16; off<64; off<<=1){
        float os = __shfl_xor(bs, off); int oi = __shfl_xor(bi, off);
        bool bt = (os > bs) || (os==bs && oi < bi);
        bs = bt ? os : bs; bi = bt ? oi : bi;
      }
      #pragma unroll
      for (int q=0;q<6;q++){
        if (ti1[q]==bi){ ts1[q] = -3.0e38f; ti1[q] = 0x7fffffff; }
      }
      if (lk8==0){ wcs[rg][rloc][k] = bs; wci[rg][rloc][k] = bi; }
    }
  }
  __syncthreads();
  // ---- phase 2b: block top-16 per row (row = t>>4, 16-lane group merges 64 candidates) ----
  const int mrow = t>>4;        // 0..31
  const int ml   = t&15;
  float cs4[4]; int ci4[4];
  #pragma unroll
  for (int j=0;j<4;j++){
    int idx = ml*4+j;
    cs4[j] = wcs[idx>>3][mrow][idx&7];
    ci4[j] = wci[idx>>3][mrow][idx&7];
  }
  int myidx = 0;
  #pragma unroll 1
  for (int k=0;k<16;k++){
    float bs = cs4[0]; int bi = ci4[0];
    #pragma unroll
    for (int q=1;q<4;q++){
      bool bt = (cs4[q] > bs) || (cs4[q]==bs && ci4[q] < bi);
      bs = bt ? cs4[q] : bs; bi = bt ? ci4[q] : bi;
    }
    #pragma unroll
    for (int off=1; off<16; off<<=1){
      float os = __shfl_xor(bs, off, 16); int oi = __shfl_xor(bi, off, 16);
      bool bt = (os > bs) || (os==bs && oi < bi);
      bs = bt ? os : bs; bi = bt ? oi : bi;
    }
    #pragma unroll
    for (int q=0;q<4;q++){
      if (ci4[q]==bi){ cs4[q] = -3.0e38f; ci4[q] = 0x7fffffff; }
    }
    if (ml==k) myidx = bi;
  }
  // ---- phase 3: exact f64 rescore of 16 candidates/row; top-8 by (score desc, idx asc) ----
  const float* kr = Km + (size_t)myidx*128;
  const float* qrow = &Qt[mrow][0];
  double sd = 0.0;
  #pragma unroll 1
  for (int d4=0; d4<32; d4++){
    float4 kv = *(const float4*)&kr[d4*4];
    sd += (double)qrow[d4*4+0]*(double)kv.x;
    sd += (double)qrow[d4*4+1]*(double)kv.y;
    sd += (double)qrow[d4*4+2]*(double)kv.z;
    sd += (double)qrow[d4*4+3]*(double)kv.w;
  }
  double cs = sd; int ci = myidx;
  double sel0,sel1,sel2,sel3,sel4,sel5,sel6,sel7;
  int is0,is1,is2,is3,is4,is5,is6,is7;
  #pragma unroll
  for (int k8=0;k8<8;k8++){
    double bs = cs; int bi = ci;
    #pragma unroll
    for (int off=1; off<16; off<<=1){
      double os = __shfl_xor(bs, off, 16); int oi = __shfl_xor(bi, off, 16);
      bool bt = (os > bs) || (os==bs && oi < bi);
      bs = bt ? os : bs; bi = bt ? oi : bi;
    }
    if (ci==bi) cs = -1.0e300;
    if (k8==0){sel0=bs;is0=bi;} else if (k8==1){sel1=bs;is1=bi;}
    else if (k8==2){sel2=bs;is2=bi;} else if (k8==3){sel3=bs;is3=bi;}
    else if (k8==4){sel4=bs;is4=bi;} else if (k8==5){sel5=bs;is5=bi;}
    else if (k8==6){sel6=bs;is6=bi;} else {sel7=bs;is7=bi;}
  }
  if (ml==0){
    int grow = row0 + mrow;
    const double sc_inv = 0.08838834764831845;
    double mx = sel0;
    double e0 = exp((sel0-mx)*sc_inv), e1 = exp((sel1-mx)*sc_inv);
    double e2 = exp((sel2-mx)*sc_inv), e3 = exp((sel3-mx)*sc_inv);
    double e4 = exp((sel4-mx)*sc_inv), e5 = exp((sel5-mx)*sc_inv);
    double e6 = exp((sel6-mx)*sc_inv), e7 = exp((sel7-mx)*sc_inv);
    double sum = e0+e1+e2+e3+e4+e5+e6+e7;
    float w0=(float)(e0/sum),w1=(float)(e1/sum),w2=(float)(e2/sum),w3=(float)(e3/sum);
    float w4=(float)(e4/sum),w5=(float)(e5/sum),w6=(float)(e6/sum),w7=(float)(e7/sum);
    size_t o = (size_t)grow*8;
    tw[o+0]=w0; tw[o+1]=w1; tw[o+2]=w2; tw[o+3]=w3;
    tw[o+4]=w4; tw[o+5]=w5; tw[o+6]=w6; tw[o+7]=w7;
    tidx[o+0]=is0; tidx[o+1]=is1; tidx[o+2]=is2; tidx[o+3]=is3;
    tidx[o+4]=is4; tidx[o+5]=is5; tidx[o+6]=is6; tidx[o+7]=is7;
    out4[o+0]=w0; out4[o+1]=w1; out4[o+2]=w2; out4[o+3]=w3;
    out4[o+4]=w4; out4[o+5]=w5; out4[o+6]=w6; out4[o+7]=w7;
    out3[o+0]=(float)is0; out3[o+1]=(float)is1;
    out3[o+2]=(float)is2; out3[o+3]=(float)is3;
    out3[o+4]=(float)is4; out3[o+5]=(float)is5;
    out3[o+6]=(float)is6; out3[o+7]=(float)is7;
  }
}

// ============ scores fallback (round-7 f32 path, used if ws too small) ============
__global__ __launch_bounds__(512) void k_scores(const float* __restrict__ Qm, const float* __restrict__ Km,
                                                float* __restrict__ tw, int* __restrict__ tidx,
                                                float* __restrict__ out3, float* __restrict__ out4){
  __shared__ float Qt[32][132];
  __shared__ float Kt[512][20];
  __shared__ int candI[8][4][16];
  const int t = threadIdx.x;
  const int rg = t>>6, c = t&63;
  const int row0 = blockIdx.x*32;
  #pragma unroll
  for (int p=0;p<2;p++){
    int f = p*512+t; int r = f>>5, rq = f&31;
    float4 v = *(const float4*)&Qm[(size_t)(row0+r)*128 + rq*4];
    *(float4*)&Qt[r][rq*4] = v;
  }
  float ts[4][8]; int ti[4][8]; float thr[4];
  #pragma unroll
  for (int i=0;i<4;i++){
    thr[i] = -3.0e38f;
    #pragma unroll
    for (int k=0;k<8;k++){ ts[i][k] = -3.0e38f; ti[i][k] = 0x7fffffff; }
  }
  __syncthreads();
  #pragma unroll 1
  for (int nt=0;nt<64;nt++){
    const int nb = nt*512;
    float acc[4][8];
    #pragma unroll
    for (int i=0;i<4;i++){
      #pragma unroll
      for (int j=0;j<8;j++) acc[i][j]=0.f;
    }
    #pragma unroll 1
    for (int rc=0;rc<8;rc++){
      #pragma unroll
      for (int p=0;p<4;p++){
        int f = p*512+t; int nn = f>>2, rq = f&3;
        float4 v = *(const float4*)&Km[(size_t)(nb+nn)*128 + rc*16 + rq*4];
        *(float4*)&Kt[nn][rq*4] = v;
      }
      __syncthreads();
      #pragma unroll
      for (int r4=0;r4<4;r4++){
        float4 qv[4]; float4 kv[8];
        #pragma unroll
        for (int i=0;i<4;i++) qv[i] = *(const float4*)&Qt[rg*4+i][rc*16+r4*4];
        #pragma unroll
        for (int j=0;j<8;j++) kv[j] = *(const float4*)&Kt[c+64*j][r4*4];
        #pragma unroll
        for (int i=0;i<4;i++){
          #pragma unroll
          for (int j=0;j<8;j++){
            acc[i][j] += qv[i].x*kv[j].x;
            acc[i][j] += qv[i].y*kv[j].y;
            acc[i][j] += qv[i].z*kv[j].z;
            acc[i][j] += qv[i].w*kv[j].w;
          }
        }
      }
      __syncthreads();
    }
    #pragma unroll
    for (int i=0;i<4;i++){
      #pragma unroll
      for (int j=0;j<8;j++){
        float s = acc[i][j];
        if (s > thr[i]){
          int n = nb + c + 64*j;
          float mn = ts[i][0]; int mp = 0;
          #pragma unroll
          for (int k=1;k<8;k++){ bool lt = ts[i][k] < mn; mn = lt ? ts[i][k] : mn; mp = lt ? k : mp; }
          #pragma unroll
          for (int k=0;k<8;k++) if (k==mp){ ts[i][k] = s; ti[i][k] = n; }
          float nm = ts[i][0];
          #pragma unroll
          for (int k=1;k<8;k++) nm = fminf(nm, ts[i][k]);
          thr[i] = nm;
        }
      }
    }
  }
  #pragma unroll
  for (int i=0;i<4;i++){
    #pragma unroll 1
    for (int k=0;k<16;k++){
      float bs = ts[i][0]; int bi = ti[i][0];
      #pragma unroll
      for (int q=1;q<8;q++){
        bool bt = (ts[i][q] > bs) || (ts[i][q]==bs && ti[i][q] < bi);
        bs = bt ? ts[i][q] : bs; bi = bt ? ti[i][q] : bi;
      }
      #pragma unroll
      for (int off=1; off<64; off<<=1){
        float os = __shfl_xor(bs, off); int oi = __shfl_xor(bi, off);
        bool bt = (os > bs) || (os==bs && oi < bi);
        bs = bt ? os : bs; bi = bt ? oi : bi;
      }
      #pragma unroll
      for (int q=0;q<8;q++){
        if (ti[i][q]==bi){ ts[i][q] = -3.0e38f; ti[i][q] = 0x7fffffff; }
      }
      if (c==0) candI[rg][i][k] = bi;
    }
  }
  __syncthreads();
  const int ri = c>>4, rk = c&15;
  const int kidx = candI[rg][ri][rk];
  const float* kr = Km + (size_t)kidx*128;
  const float* qrow = &Qt[rg*4+ri][0];
  double sd = 0.0;
  #pragma unroll 1
  for (int d4=0; d4<32; d4++){
    float4 kv = *(const float4*)&kr[d4*4];
    sd += (double)qrow[d4*4+0]*(double)kv.x;
    sd += (double)qrow[d4*4+1]*(double)kv.y;
    sd += (double)qrow[d4*4+2]*(double)kv.z;
    sd += (double)qrow[d4*4+3]*(double)kv.w;
  }
  double cs = sd; int ci = kidx;
  double sel0,sel1,sel2,sel3,sel4,sel5,sel6,sel7;
  int is0,is1,is2,is3,is4,is5,is6,is7;
  #pragma unroll
  for (int k8=0;k8<8;k8++){
    double bs = cs; int bi = ci;
    #pragma unroll
    for (int off=1; off<16; off<<=1){
      double os = __shfl_xor(bs, off, 16); int oi = __shfl_xor(bi, off, 16);
      bool bt = (os > bs) || (os==bs && oi < bi);
      bs = bt ? os : bs; bi = bt ? oi : bi;
    }
    if (ci==bi) cs = -1.0e300;
    if (k8==0){sel0=bs;is0=bi;} else if (k8==1){sel1=bs;is1=bi;}
    else if (k8==2){sel2=bs;is2=bi;} else if (k8==3){sel3=bs;is3=bi;}
    else if (k8==4){sel4=bs;is4=bi;} else if (k8==5){sel5=bs;is5=bi;}
    else if (k8==6){sel6=bs;is6=bi;} else {sel7=bs;is7=bi;}
  }
  if (rk==0){
    int grow = row0 + rg*4 + ri;
    const double sc_inv = 0.08838834764831845;
    double mx = sel0;
    double e0 = exp((sel0-mx)*sc_inv), e1 = exp((sel1-mx)*sc_inv);
    double e2 = exp((sel2-mx)*sc_inv), e3 = exp((sel3-mx)*sc_inv);
    double e4 = exp((sel4-mx)*sc_inv), e5 = exp((sel5-mx)*sc_inv);
    double e6 = exp((sel6-mx)*sc_inv), e7 = exp((sel7-mx)*sc_inv);
    double sum = e0+e1+e2+e3+e4+e5+e6+e7;
    float w0=(float)(e0/sum),w1=(float)(e1/sum),w2=(float)(e2/sum),w3=(float)(e3/sum);
    float w4=(float)(e4/sum),w5=(float)(e5/sum),w6=(float)(e6/sum),w7=(float)(e7/sum);
    size_t o = (size_t)grow*8;
    tw[o+0]=w0; tw[o+1]=w1; tw[o+2]=w2; tw[o+3]=w3;
    tw[o+4]=w4; tw[o+5]=w5; tw[o+6]=w6; tw[o+7]=w7;
    tidx[o+0]=is0; tidx[o+1]=is1; tidx[o+2]=is2; tidx[o+3]=is3;
    tidx[o+4]=is4; tidx[o+5]=is5; tidx[o+6]=is6; tidx[o+7]=is7;
    out4[o+0]=w0; out4[o+1]=w1; out4[o+2]=w2; out4[o+3]=w3;
    out4[o+4]=w4; out4[o+5]=w5; out4[o+6]=w6; out4[o+7]=w7;
    out3[o+0]=(float)is0; out3[o+1]=(float)is1;
    out3[o+2]=(float)is2; out3[o+3]=(float)is3;
    out3[o+4]=(float)is4; out3[o+5]=(float)is5;
    out3[o+6]=(float)is6; out3[o+7]=(float)is7;
  }
}

// ============ gather + weighted sum -> output (float32) ============
__global__ __launch_bounds__(256) void k_gather(const float* __restrict__ V, const int* __restrict__ tidx,
                                                const float* __restrict__ tw, float* __restrict__ out0){
  int row = blockIdx.x; int t = threadIdx.x;
  __shared__ int li[8]; __shared__ float lw[8];
  if (t<8){
    int idx = tidx[(size_t)row*8+t];
    idx = idx < 0 ? 0 : (idx > (NK_-1) ? (NK_-1) : idx);
    li[t] = idx;
  } else if (t<16){
    float w = tw[(size_t)row*8 + t-8];
    w = fminf(fmaxf(w, 0.f), 1.f);
    lw[t-8] = w;
  }
  __syncthreads();
  float4 a = {0,0,0,0};
  #pragma unroll
  for (int k=0;k<8;k++){
    float4 v = ((const float4*)V)[(size_t)li[k]*256 + t];
    float w = lw[k];
    a.x += w*v.x; a.y += w*v.y; a.z += w*v.z; a.w += w*v.w;
  }
  ((float4*)(out0 + (size_t)row*1024))[t] = a;
}

extern "C" void kernel_launch(void* const* d_in, const int* in_sizes, int n_in,
                              void* d_out, int out_size, void* d_ws, size_t ws_size,
                              hipStream_t stream) {
  const float* x    = (const float*)d_in[0];
  const float* A    = (const float*)d_in[1];
  const float* Bm   = (const float*)d_in[2];
  const float* Wimp = (const float*)d_in[3];
  const float* Wr   = (const float*)d_in[4];
  const float* comp = (const float*)d_in[5];
  const float* Kmat = (const float*)d_in[6];
  const float* V    = (const float*)d_in[7];
  float* out = (float*)d_out;               // OUTPUT IS FLOAT32
  float* ws = (float*)d_ws;

  float* xB    = ws + OFF_XB;
  float* tp    = ws + OFF_TP;
  float* Apow  = ws + OFF_APOW;
  float* P     = ws + OFF_P;
  float* hproj = ws + OFF_HPROJ;
  float* logit = ws + OFF_LOGIT;
  float* imp   = ws + OFF_IMP;
  float* nw    = ws + OFF_NW;
  float* scb   = ws + OFF_SC;
  float* Qb    = ws + OFF_Q;        // aliases xB+tp (both dead by the time k_Q runs)
  int*   tidx  = (int*)(ws + OFF_TIDX);
  float* tw    = ws + OFF_TW;
  ushort* khi  = (ushort*)(ws + OFF_KHI);
  ushort* klo  = (ushort*)(ws + OFF_KLO);

  const bool use_mfma = (ws_size >= WS_NEED_MFMA);

  k_init_apow<<<32,256,0,stream>>>(A, Apow);
  if (use_mfma) k_split<<<4096,256,0,stream>>>(Kmat, khi, klo);
  k_matstage<<<1 ,256,0,stream>>>(Apow, 2 ,1 ,1);
  k_matstage<<<2 ,256,0,stream>>>(Apow, 3 ,2 ,1);
  k_matstage<<<4 ,256,0,stream>>>(Apow, 5 ,4 ,1);
  k_matstage<<<8 ,256,0,stream>>>(Apow, 9 ,8 ,1);
  k_matstage<<<16,256,0,stream>>>(Apow, 17,16,1);
  k_matstage<<<32,256,0,stream>>>(Apow, 33,32,1);
  k_xbr<<<256,256,0,stream>>>(x, Bm, Wr, xB, tp);
  k_P<<<32,256,0,stream>>>(xB, Apow, P);
  k_scan<<<1,256,0,stream>>>(Apow, P, Wimp, hproj);
  k_implogit<<<8192,256,0,stream>>>(x, hproj, logit);
  k_softS<<<4,1024,0,stream>>>(logit, imp, out + O_IMP);
  k_nw<<<4,256,0,stream>>>(imp, tp, nw, out + O_NW);
  k_sc<<<128,256,0,stream>>>(nw, comp, scb);
  k_Q<<<256,256,0,stream>>>(x, scb, Qb);
  if (use_mfma)
    k_scores_mfma<<<256,512,0,stream>>>(Qb, khi, klo, Kmat, tw, tidx, out + O_TIDX, out + O_TW);
  else
    k_scores<<<256,512,0,stream>>>(Qb, Kmat, tw, tidx, out + O_TIDX, out + O_TW);
  k_gather<<<8192,256,0,stream>>>(V, tidx, tw, out + O_OUT);
}

// Round 16
// 843.206 us; speedup vs baseline: 2.2028x; 1.2439x over previous
//
#include <hip/hip_runtime.h>
#include <hip/hip_bf16.h>
#include <math.h>

#define B_  4
#define S_  2048
#define D_  1024
#define R_  128
#define NC_ 64
#define NK_ 32768
#define SD_ 64
#define KK_ 8

typedef __attribute__((ext_vector_type(8))) short short8v;  // 8 bf16 (4 VGPRs)
typedef __attribute__((ext_vector_type(4))) float f32x4;

// ---------------- ws layout (float offsets) ----------------
static const size_t OFF_XB    = 0;         // [8192][64]
static const size_t OFF_TP    = 524288;    // [8192][64]
static const size_t OFF_APOW  = 1048576;   // [65][64][64]
static const size_t OFF_P     = 1314816;   // [32][4][64]
static const size_t OFF_HPROJ = 1323008;   // [4][1024]
static const size_t OFF_LOGIT = 1327104;   // [4][2048]
static const size_t OFF_IMP   = 1335296;   // [4][2048]
static const size_t OFF_NW    = 1343488;   // [4][64]
static const size_t OFF_SC    = 1343744;   // [4][1024][128]
static const size_t OFF_Q     = 0;         // [8192][128] aliases XB+TP (stream-ordered safe)
static const size_t OFF_TIDX  = 1868032;   // [8192][8] int
static const size_t OFF_TW    = 1933568;   // [8192][8]  -> 1999104
// MFMA path extras (bf16 K), only used when ws_size is large enough:
static const size_t OFF_KHI   = 1999104;   // [32768][128] ushort -> 2,097,152 floats
static const size_t OFF_KLO   = 4096256;   // (unused now, kept for ws sizing)
static const size_t WS_NEED_MFMA = (size_t)6193408 * 4;   // bytes

// -------- output layout (FLOAT32 offsets) --------
static const size_t O_OUT  = 0;
static const size_t O_IMP  = 8388608;
static const size_t O_NW   = 8396800;
static const size_t O_TIDX = 8397056;
static const size_t O_TW   = 8462592;

__device__ __forceinline__ ushort bf_bits(__hip_bfloat16 h){ return *reinterpret_cast<ushort*>(&h); }

// ============ Apow init ============
__global__ __launch_bounds__(256) void k_init_apow(const float* __restrict__ A, float* __restrict__ Apow){
  int t = blockIdx.x*256 + threadIdx.x;
  if (t < 4096){ int i = t>>6, j = t&63; Apow[t] = (i==j) ? 1.f : 0.f; }
  else Apow[t] = A[t-4096];
}

// ============ batched 64x64x64 matmul (f64 accumulate) ============
__global__ __launch_bounds__(256) void k_matstage(float* __restrict__ Apow, int dst0, int lhs, int rhs0){
  __shared__ float L[64][68];
  __shared__ float Rm[64][68];
  const float* Lp = Apow + (size_t)lhs*4096;
  const float* Rp = Apow + (size_t)(rhs0 + blockIdx.x)*4096;
  int t = threadIdx.x;
  #pragma unroll 1
  for (int p=0;p<4;p++){
    int f = p*256+t; int i = f>>4, jq = f&15;
    float4 v = ((const float4*)Lp)[f];
    L[i][jq*4+0]=v.x; L[i][jq*4+1]=v.y; L[i][jq*4+2]=v.z; L[i][jq*4+3]=v.w;
    float4 w = ((const float4*)Rp)[f];
    Rm[i][jq*4+0]=w.x; Rm[i][jq*4+1]=w.y; Rm[i][jq*4+2]=w.z; Rm[i][jq*4+3]=w.w;
  }
  __syncthreads();
  int j = t&63, rg = t>>6;
  double acc[16];
  #pragma unroll
  for (int ii=0;ii<16;ii++) acc[ii]=0.0;
  #pragma unroll 1
  for (int kk=0;kk<64;kk++){
    double rv = (double)Rm[kk][j];
    #pragma unroll
    for (int ii=0;ii<16;ii++) acc[ii] += (double)L[rg*16+ii][kk]*rv;
  }
  float* out = Apow + (size_t)(dst0 + blockIdx.x)*4096;
  #pragma unroll
  for (int ii=0;ii<16;ii++) out[(rg*16+ii)*64 + j] = (float)acc[ii];
}

// ============ xB + router logits GEMM, 32-row tiles (256 blocks: full CU coverage) ============
__global__ __launch_bounds__(256) void k_xbr(const float* __restrict__ x, const float* __restrict__ Bm,
                                             const float* __restrict__ Wr,
                                             float* __restrict__ xB, float* __restrict__ tp){
  int row0 = blockIdx.x*32;
  __shared__ float Xt[32][36];
  __shared__ float Wt[32][132];
  __shared__ float SB[32][65];
  int t = threadIdx.x;
  int rg = t>>5, c = t&31;
  double accd[4][4];
  #pragma unroll
  for (int i=0;i<4;i++){
    #pragma unroll
    for (int j=0;j<4;j++) accd[i][j]=0.0;
  }
  #pragma unroll 1
  for (int kc=0;kc<32;kc++){
    int d0 = kc*32;
    {
      int f = t; int r = f>>3, dq = f&7;
      float4 v = *(const float4*)&x[(size_t)(row0+r)*1024 + d0 + dq*4];
      Xt[r][dq*4+0]=v.x; Xt[r][dq*4+1]=v.y; Xt[r][dq*4+2]=v.z; Xt[r][dq*4+3]=v.w;
    }
    #pragma unroll
    for (int p=0;p<2;p++){
      int f = p*256+t; int dd = f>>4, eq = f&15;
      float4 v = *(const float4*)&Bm[(size_t)(d0+dd)*64 + eq*4];
      Wt[dd][eq*4+0]=v.x; Wt[dd][eq*4+1]=v.y; Wt[dd][eq*4+2]=v.z; Wt[dd][eq*4+3]=v.w;
    }
    #pragma unroll
    for (int p=0;p<2;p++){
      int f = p*256+t; int n = f>>3, dq = f&7;
      float4 v = *(const float4*)&Wr[(size_t)n*1024 + d0 + dq*4];
      Wt[dq*4+0][64+n]=v.x; Wt[dq*4+1][64+n]=v.y; Wt[dq*4+2][64+n]=v.z; Wt[dq*4+3][64+n]=v.w;
    }
    __syncthreads();
    float accf[4][4];
    #pragma unroll
    for (int i=0;i<4;i++){
      #pragma unroll
      for (int j=0;j<4;j++) accf[i][j]=0.f;
    }
    #pragma unroll
    for (int k4=0;k4<8;k4++){
      float4 xv[4];
      #pragma unroll
      for (int i=0;i<4;i++) xv[i] = *(const float4*)&Xt[rg*4+i][k4*4];
      #pragma unroll
      for (int u=0;u<4;u++){
        int kk = k4*4+u;
        float wv[4];
        #pragma unroll
        for (int j=0;j<4;j++) wv[j] = Wt[kk][c+32*j];
        #pragma unroll
        for (int i=0;i<4;i++){
          float xs = (u==0)?xv[i].x:(u==1)?xv[i].y:(u==2)?xv[i].z:xv[i].w;
          #pragma unroll
          for (int j=0;j<4;j++) accf[i][j] += xs*wv[j];
        }
      }
    }
    #pragma unroll
    for (int i=0;i<4;i++){
      #pragma unroll
      for (int j=0;j<4;j++) accd[i][j] += (double)accf[i][j];
    }
    __syncthreads();
  }
  #pragma unroll
  for (int i=0;i<4;i++){
    int row = row0 + rg*4 + i;
    xB[(size_t)row*64 + c]      = (float)accd[i][0];
    xB[(size_t)row*64 + c + 32] = (float)accd[i][1];
    SB[rg*4+i][c]    = (float)accd[i][2];
    SB[rg*4+i][c+32] = (float)accd[i][3];
  }
  __syncthreads();
  if (t < 32){
    double m = -1.0e300;
    #pragma unroll 1
    for (int n=0;n<64;n++) m = fmax(m, (double)SB[t][n]);
    double s = 0.0;
    #pragma unroll 1
    for (int n=0;n<64;n++){ double e = exp((double)SB[t][n]-m); SB[t][n]=(float)e; s += e; }
    int row = row0 + t;
    #pragma unroll 1
    for (int n=0;n<64;n++) tp[(size_t)row*64 + n] = (float)((double)SB[t][n]/s);
  }
}

// ============ chunk partials (f64 accumulate) ============
__global__ __launch_bounds__(256) void k_P(const float* __restrict__ xB, const float* __restrict__ Apow,
                                           float* __restrict__ P){
  int cchunk = blockIdx.x; int t = threadIdx.x;
  int b = t>>6, e = t&63;
  double acc = 0.0;
  #pragma unroll 1
  for (int l=0;l<64;l++){
    const float* xr = &xB[((size_t)b*2048 + cchunk*64 + l)*64];
    const float* Ap = &Apow[(size_t)(63-l)*4096];
    #pragma unroll
    for (int k4=0;k4<16;k4++){
      float4 xv = *(const float4*)&xr[k4*4];
      acc += (double)xv.x*(double)Ap[(k4*4+0)*64+e];
      acc += (double)xv.y*(double)Ap[(k4*4+1)*64+e];
      acc += (double)xv.z*(double)Ap[(k4*4+2)*64+e];
      acc += (double)xv.w*(double)Ap[(k4*4+3)*64+e];
    }
  }
  P[cchunk*256 + t] = (float)acc;
}

// ============ Horner combine (f64) + h_proj ============
__global__ __launch_bounds__(256) void k_scan(const float* __restrict__ Apow, const float* __restrict__ P,
                                              const float* __restrict__ Wimp, float* __restrict__ hproj){
  __shared__ float A64s[64][68];
  __shared__ double h[2][4][64];
  int t = threadIdx.x;
  const float* A64 = Apow + (size_t)64*4096;
  #pragma unroll 1
  for (int p=0;p<4;p++){
    int f = p*256+t; int i = f>>4, jq = f&15;
    float4 v = *(const float4*)&A64[f*4];
    A64s[i][jq*4+0]=v.x; A64s[i][jq*4+1]=v.y; A64s[i][jq*4+2]=v.z; A64s[i][jq*4+3]=v.w;
  }
  int b = t>>6, e = t&63;
  h[0][b][e] = 0.0;
  __syncthreads();
  #pragma unroll 1
  for (int c=0;c<32;c++){
    int cur = c&1;
    double acc = (double)P[c*256 + t];
    #pragma unroll
    for (int k=0;k<64;k++) acc += h[cur][b][k]*(double)A64s[k][e];
    h[cur^1][b][e] = acc;
    __syncthreads();
  }
  #pragma unroll 1
  for (int m=0;m<16;m++){
    int o = t + 256*m; int bb = o>>10, d = o&1023;
    const float* wrow = &Wimp[(size_t)d*64];
    double acc = 0.0;
    #pragma unroll
    for (int e4=0;e4<16;e4++){
      float4 w = *(const float4*)&wrow[e4*4];
      acc += h[0][bb][e4*4+0]*(double)w.x;
      acc += h[0][bb][e4*4+1]*(double)w.y;
      acc += h[0][bb][e4*4+2]*(double)w.z;
      acc += h[0][bb][e4*4+3]*(double)w.w;
    }
    hproj[o] = (float)acc;
  }
}

// ============ importance logits (f64) ============
__global__ __launch_bounds__(256) void k_implogit(const float* __restrict__ x, const float* __restrict__ hproj,
                                                  float* __restrict__ logits){
  int row = blockIdx.x; int b = row>>11;
  int t = threadIdx.x;
  float4 xv = ((const float4*)x)[(size_t)row*256 + t];
  float4 hv = ((const float4*)hproj)[(size_t)b*256 + t];
  double p = (double)xv.x*(double)hv.x + (double)xv.y*(double)hv.y
           + (double)xv.z*(double)hv.z + (double)xv.w*(double)hv.w;
  #pragma unroll
  for (int off=32; off; off>>=1) p += __shfl_down(p, off);
  __shared__ double ws4[4];
  if ((t&63)==0) ws4[t>>6] = p;
  __syncthreads();
  if (t==0) logits[row] = (float)(ws4[0]+ws4[1]+ws4[2]+ws4[3]);
}

// ============ softmax over S per batch (f64) ============
__global__ __launch_bounds__(1024) void k_softS(const float* __restrict__ logits, float* __restrict__ imp,
                                                float* __restrict__ out1){
  int b = blockIdx.x; int t = threadIdx.x;
  double v0 = (double)logits[b*2048 + t];
  double v1 = (double)logits[b*2048 + 1024 + t];
  double m = fmax(v0,v1);
  #pragma unroll
  for (int off=32; off; off>>=1) m = fmax(m, __shfl_xor(m, off));
  __shared__ double red[16];
  if ((t&63)==0) red[t>>6] = m;
  __syncthreads();
  double M = red[0];
  #pragma unroll 1
  for (int i=1;i<16;i++) M = fmax(M, red[i]);
  double p0 = exp(v0-M), p1 = exp(v1-M);
  double s = p0+p1;
  #pragma unroll
  for (int off=32; off; off>>=1) s += __shfl_xor(s, off);
  __syncthreads();
  if ((t&63)==0) red[t>>6] = s;
  __syncthreads();
  double S = 0.0;
  #pragma unroll 1
  for (int i=0;i<16;i++) S += red[i];
  float i0 = (float)(p0/S), i1 = (float)(p1/S);
  imp[b*2048+t] = i0; imp[b*2048+1024+t] = i1;
  out1[b*2048+t] = i0; out1[b*2048+1024+t] = i1;
}

// ============ neuron_w (f64) ============
__global__ __launch_bounds__(256) void k_nw(const float* __restrict__ imp, const float* __restrict__ tp,
                                            float* __restrict__ nw, float* __restrict__ out2){
  int b = blockIdx.x; int t = threadIdx.x;
  int n = t&63, sg = t>>6;
  double acc = 0.0;
  #pragma unroll 1
  for (int s=sg; s<2048; s+=4)
    acc += (double)imp[b*2048+s]*(double)tp[((size_t)b*2048+s)*64 + n];
  __shared__ double part[4][64];
  part[sg][n] = acc;
  __syncthreads();
  if (t<64){
    double v = part[0][t]+part[1][t]+part[2][t]+part[3][t];
    double tot = v;
    #pragma unroll
    for (int off=32; off; off>>=1) tot += __shfl_xor(tot, off);
    float r = (float)(v/(tot + 1e-8));
    nw[b*64+t] = r; out2[b*64+t] = r;
  }
}

// ============ shared_compress (f64 accumulate) ============
__global__ __launch_bounds__(256) void k_sc(const float* __restrict__ nw, const float* __restrict__ comp,
                                            float* __restrict__ sc){
  __shared__ float w[256];
  int t = threadIdx.x;
  w[t] = nw[t];
  __syncthreads();
  size_t base = (size_t)blockIdx.x*1024 + t*4;
  double a[4][4];
  #pragma unroll
  for (int i=0;i<4;i++){
    #pragma unroll
    for (int j=0;j<4;j++) a[i][j]=0.0;
  }
  #pragma unroll 1
  for (int n=0;n<64;n++){
    float4 cv = *(const float4*)&comp[(size_t)n*131072 + base];
    double cx=cv.x, cy=cv.y, cz=cv.z, cw=cv.w;
    double w0=w[n], w1=w[64+n], w2=w[128+n], w3=w[192+n];
    a[0][0]+=w0*cx; a[0][1]+=w0*cy; a[0][2]+=w0*cz; a[0][3]+=w0*cw;
    a[1][0]+=w1*cx; a[1][1]+=w1*cy; a[1][2]+=w1*cz; a[1][3]+=w1*cw;
    a[2][0]+=w2*cx; a[2][1]+=w2*cy; a[2][2]+=w2*cz; a[2][3]+=w2*cw;
    a[3][0]+=w3*cx; a[3][1]+=w3*cy; a[3][2]+=w3*cz; a[3][3]+=w3*cw;
  }
  #pragma unroll
  for (int i=0;i<4;i++){
    float4 o; o.x=(float)a[i][0]; o.y=(float)a[i][1]; o.z=(float)a[i][2]; o.w=(float)a[i][3];
    *(float4*)&sc[(size_t)i*131072 + base] = o;
  }
}

// ============ Q = x @ sc[b], 32-row tiles (256 blocks: full CU coverage) ============
__global__ __launch_bounds__(256) void k_Q(const float* __restrict__ x, const float* __restrict__ sc,
                                           float* __restrict__ Q){
  int bid = blockIdx.x;
  int b = bid>>6;
  int row0 = b*2048 + (bid&63)*32;
  __shared__ float Xt[32][36];
  __shared__ float Wt[32][132];
  int t = threadIdx.x; int rg = t>>5, c = t&31;
  double accd[4][4];
  #pragma unroll
  for (int i=0;i<4;i++){
    #pragma unroll
    for (int j=0;j<4;j++) accd[i][j]=0.0;
  }
  #pragma unroll 1
  for (int kc=0;kc<32;kc++){
    int d0 = kc*32;
    {
      int f = t; int r = f>>3, dq = f&7;
      float4 v = *(const float4*)&x[(size_t)(row0+r)*1024 + d0 + dq*4];
      Xt[r][dq*4+0]=v.x; Xt[r][dq*4+1]=v.y; Xt[r][dq*4+2]=v.z; Xt[r][dq*4+3]=v.w;
    }
    #pragma unroll
    for (int p=0;p<4;p++){
      int f = p*256+t; int dd = f>>5, nq = f&31;
      float4 v = *(const float4*)&sc[(size_t)b*131072 + (size_t)(d0+dd)*128 + nq*4];
      Wt[dd][nq*4+0]=v.x; Wt[dd][nq*4+1]=v.y; Wt[dd][nq*4+2]=v.z; Wt[dd][nq*4+3]=v.w;
    }
    __syncthreads();
    float accf[4][4];
    #pragma unroll
    for (int i=0;i<4;i++){
      #pragma unroll
      for (int j=0;j<4;j++) accf[i][j]=0.f;
    }
    #pragma unroll
    for (int k4=0;k4<8;k4++){
      float4 xv[4];
      #pragma unroll
      for (int i=0;i<4;i++) xv[i] = *(const float4*)&Xt[rg*4+i][k4*4];
      #pragma unroll
      for (int u=0;u<4;u++){
        int kk = k4*4+u;
        float wv[4];
        #pragma unroll
        for (int j=0;j<4;j++) wv[j] = Wt[kk][c+32*j];
        #pragma unroll
        for (int i=0;i<4;i++){
          float xs = (u==0)?xv[i].x:(u==1)?xv[i].y:(u==2)?xv[i].z:xv[i].w;
          #pragma unroll
          for (int j=0;j<4;j++) accf[i][j] += xs*wv[j];
        }
      }
    }
    #pragma unroll
    for (int i=0;i<4;i++){
      #pragma unroll
      for (int j=0;j<4;j++) accd[i][j] += (double)accf[i][j];
    }
    __syncthreads();
  }
  #pragma unroll
  for (int i=0;i<4;i++){
    #pragma unroll
    for (int j=0;j<4;j++)
      Q[(size_t)(row0+rg*4+i)*128 + c + 32*j] = (float)accd[i][j];
  }
}

// ============ K -> bf16 (hi only) ============
__global__ __launch_bounds__(256) void k_split(const float* __restrict__ K, ushort* __restrict__ khi){
  int i = blockIdx.x*256 + threadIdx.x;   // over 1,048,576 float4s
  float4 v = ((const float4*)K)[i];
  union { ushort u[4]; uint2 q; } ph;
  float xs[4] = {v.x, v.y, v.z, v.w};
  #pragma unroll
  for (int e=0;e<4;e++){
    __hip_bfloat16 h = __float2bfloat16(xs[e]);
    ph.u[e] = bf_bits(h);
  }
  ((uint2*)khi)[i] = ph.q;
}

// load K fragment set (khi only) for iteration IT into BH; NCB = base neuron index
#define LOADK1(BH, NCB, IT) {                                             \
  int nt_ = (IT)>>2, cq_ = (IT)&3;                                        \
  int base_ = nt_*512 + (rg*4+cq_)*16;                                    \
  NCB = base_ + lk8*4;                                                    \
  const size_t ko_ = (size_t)(base_ + lrow)*128 + lk8*8;                  \
  BH[0] = *(const short8v*)&khi[ko_];                                     \
  BH[1] = *(const short8v*)&khi[ko_+32];                                  \
  BH[2] = *(const short8v*)&khi[ko_+64];                                  \
  BH[3] = *(const short8v*)&khi[ko_+96];                                  \
}

// compute + select (bf16-only filter): acc row = neuron, col = q-row; thread owns 2 q-rows
#define COMPSEL1(BH, NCB) {                                               \
  f32x4 a0 = {0.f,0.f,0.f,0.f};                                           \
  f32x4 a1 = {0.f,0.f,0.f,0.f};                                           \
  _Pragma("unroll")                                                       \
  for (int kc=0;kc<4;kc++){                                               \
    a0 = __builtin_amdgcn_mfma_f32_16x16x32_bf16(BH[kc], qhi[0][kc], a0, 0,0,0); \
    a1 = __builtin_amdgcn_mfma_f32_16x16x32_bf16(BH[kc], qhi[1][kc], a1, 0,0,0); \
  }                                                                       \
  _Pragma("unroll")                                                       \
  for (int v=0;v<4;v++){                                                  \
    float s0 = a0[v];                                                     \
    if (s0 > thr0){                                                       \
      float mn = ts0[0]; int mp = 0;                                      \
      _Pragma("unroll")                                                   \
      for (int k=1;k<6;k++){ bool lt = ts0[k] < mn; mn = lt ? ts0[k] : mn; mp = lt ? k : mp; } \
      _Pragma("unroll")                                                   \
      for (int k=0;k<6;k++) if (k==mp){ ts0[k] = s0; ti0[k] = NCB + v; }  \
      float nm = ts0[0];                                                  \
      _Pragma("unroll")                                                   \
      for (int k=1;k<6;k++) nm = fminf(nm, ts0[k]);                       \
      thr0 = nm;                                                          \
    }                                                                     \
    float s1 = a1[v];                                                     \
    if (s1 > thr1){                                                       \
      float mn = ts1[0]; int mp = 0;                                      \
      _Pragma("unroll")                                                   \
      for (int k=1;k<6;k++){ bool lt = ts1[k] < mn; mn = lt ? ts1[k] : mn; mp = lt ? k : mp; } \
      _Pragma("unroll")                                                   \
      for (int k=0;k<6;k++) if (k==mp){ ts1[k] = s1; ti1[k] = NCB + v; }  \
      float nm = ts1[0];                                                  \
      _Pragma("unroll")                                                   \
      for (int k=1;k<6;k++) nm = fminf(nm, ts1[k]);                       \
      thr1 = nm;                                                          \
    }                                                                     \
  }                                                                       \
}

// ============ scores: bf16-only MFMA filter (swapped operands), 7-deep K prefetch ============
__global__ __launch_bounds__(512) void k_scores_mfma(const float* __restrict__ Qm,
                                                     const ushort* __restrict__ khi,
                                                     const float* __restrict__ Km,
                                                     float* __restrict__ tw, int* __restrict__ tidx,
                                                     float* __restrict__ out3, float* __restrict__ out4){
  __shared__ float Qt[32][132];
  __shared__ float wcs[8][32][8];      // per-wave top-8 per row
  __shared__ int   wci[8][32][8];
  const int t = threadIdx.x;
  const int rg = t>>6, c = t&63;       // wave 0..7, lane 0..63
  const int lrow = c&15, lk8 = c>>4;   // fragment row/col lane, k-group lane
  const int row0 = blockIdx.x*32;
  #pragma unroll
  for (int p=0;p<2;p++){
    int f = p*512+t; int r = f>>5, rq = f&31;
    float4 v = *(const float4*)&Qm[(size_t)(row0+r)*128 + rq*4];
    *(float4*)&Qt[r][rq*4] = v;
  }
  __syncthreads();
  // build Q fragments (bf16 hi only); B-operand: col=lane&15 = q-row
  short8v qhi[2][4];
  #pragma unroll
  for (int rt=0;rt<2;rt++){
    #pragma unroll
    for (int kc=0;kc<4;kc++){
      union { ushort u[8]; short8v v; } th;
      #pragma unroll
      for (int e=0;e<8;e++){
        float xq = Qt[rt*16+lrow][kc*32 + lk8*8 + e];
        __hip_bfloat16 h = __float2bfloat16(xq);
        th.u[e] = bf_bits(h);
      }
      qhi[rt][kc] = th.v;
    }
  }
  // per-thread top-6 for this thread's TWO q-rows: lrow (bank0), lrow+16 (bank1)
  float ts0[6], ts1[6]; int ti0[6], ti1[6]; float thr0, thr1;
  thr0 = thr1 = -3.0e38f;
  #pragma unroll
  for (int q=0;q<6;q++){ ts0[q]=-3.0e38f; ti0[q]=0x7fffffff; ts1[q]=-3.0e38f; ti1[q]=0x7fffffff; }
  // ---- phase 1: barrier-free MFMA, 8 rotating K buffers (7-deep prefetch) ----
  short8v h0[4],h1[4],h2[4],h3[4],h4[4],h5[4],h6[4],h7[4];
  int n0,n1,n2,n3,n4,n5,n6,n7;
  LOADK1(h0,n0,0)
  LOADK1(h1,n1,1)
  LOADK1(h2,n2,2)
  LOADK1(h3,n3,3)
  LOADK1(h4,n4,4)
  LOADK1(h5,n5,5)
  LOADK1(h6,n6,6)
  #pragma unroll 1
  for (int it=0; it<256; it+=8){
    if (it+7  < 256) LOADK1(h7,n7,it+7)
    COMPSEL1(h0,n0)
    if (it+8  < 256) LOADK1(h0,n0,it+8)
    COMPSEL1(h1,n1)
    if (it+9  < 256) LOADK1(h1,n1,it+9)
    COMPSEL1(h2,n2)
    if (it+10 < 256) LOADK1(h2,n2,it+10)
    COMPSEL1(h3,n3)
    if (it+11 < 256) LOADK1(h3,n3,it+11)
    COMPSEL1(h4,n4)
    if (it+12 < 256) LOADK1(h4,n4,it+12)
    COMPSEL1(h5,n5)
    if (it+13 < 256) LOADK1(h5,n5,it+13)
    COMPSEL1(h6,n6)
    if (it+14 < 256) LOADK1(h6,n6,it+14)
    COMPSEL1(h7,n7)
  }
  // ---- phase 2a: per-row wave top-8; row r merged across 4 lanes {r&15 + 16*lk8} ----
  {
    const int rloc = lrow;          // bank 0
    #pragma unroll 1
    for (int k=0;k<8;k++){
      float bs = ts0[0]; int bi = ti0[0];
      #pragma unroll
      for (int q=1;q<6;q++){
        bool bt = (ts0[q] > bs) || (ts0[q]==bs && ti0[q] < bi);
        bs = bt ? ts0[q] : bs; bi = bt ? ti0[q] : bi;
      }
      #pragma unroll
      for (int off=16; off<64; off<<=1){
        float os = __shfl_xor(bs, off); int oi = __shfl_xor(bi, off);
        bool bt = (os > bs) || (os==bs && oi < bi);
        bs = bt ? os : bs; bi = bt ? oi : bi;
      }
      #pragma unroll
      for (int q=0;q<6;q++){
        if (ti0[q]==bi){ ts0[q] = -3.0e38f; ti0[q] = 0x7fffffff; }
      }
      if (lk8==0){ wcs[rg][rloc][k] = bs; wci[rg][rloc][k] = bi; }
    }
  }
  {
    const int rloc = 16 + lrow;     // bank 1
    #pragma unroll 1
    for (int k=0;k<8;k++){
      float bs = ts1[0]; int bi = ti1[0];
      #pragma unroll
      for (int q=1;q<6;q++){
        bool bt = (ts1[q] > bs) || (ts1[q]==bs && ti1[q] < bi);
        bs = bt ? ts1[q] : bs; bi = bt ? ti1[q] : bi;
      }
      #pragma unroll
      for (int off=16; off<64; off<<=1){
        float os = __shfl_xor(bs, off); int oi = __shfl_xor(bi, off);
        bool bt = (os > bs) || (os==bs && oi < bi);
        bs = bt ? os : bs; bi = bt ? oi : bi;
      }
      #pragma unroll
      for (int q=0;q<6;q++){
        if (ti1[q]==bi){ ts1[q] = -3.0e38f; ti1[q] = 0x7fffffff; }
      }
      if (lk8==0){ wcs[rg][rloc][k] = bs; wci[rg][rloc][k] = bi; }
    }
  }
  __syncthreads();
  // ---- phase 2b: block top-16 per row (row = t>>4, 16-lane group merges 64 candidates) ----
  const int mrow = t>>4;        // 0..31
  const int ml   = t&15;
  float cs4[4]; int ci4[4];
  #pragma unroll
  for (int j=0;j<4;j++){
    int idx = ml*4+j;
    cs4[j] = wcs[idx>>3][mrow][idx&7];
    ci4[j] = wci[idx>>3][mrow][idx&7];
  }
  int myidx = 0;
  #pragma unroll 1
  for (int k=0;k<16;k++){
    float bs = cs4[0]; int bi = ci4[0];
    #pragma unroll
    for (int q=1;q<4;q++){
      bool bt = (cs4[q] > bs) || (cs4[q]==bs && ci4[q] < bi);
      bs = bt ? cs4[q] : bs; bi = bt ? ci4[q] : bi;
    }
    #pragma unroll
    for (int off=1; off<16; off<<=1){
      float os = __shfl_xor(bs, off, 16); int oi = __shfl_xor(bi, off, 16);
      bool bt = (os > bs) || (os==bs && oi < bi);
      bs = bt ? os : bs; bi = bt ? oi : bi;
    }
    #pragma unroll
    for (int q=0;q<4;q++){
      if (ci4[q]==bi){ cs4[q] = -3.0e38f; ci4[q] = 0x7fffffff; }
    }
    if (ml==k) myidx = bi;
  }
  // ---- phase 3: exact f64 rescore of 16 candidates/row; top-8 by (score desc, idx asc) ----
  const float* kr = Km + (size_t)myidx*128;
  const float* qrow = &Qt[mrow][0];
  double sd = 0.0;
  #pragma unroll 1
  for (int d4=0; d4<32; d4++){
    float4 kv = *(const float4*)&kr[d4*4];
    sd += (double)qrow[d4*4+0]*(double)kv.x;
    sd += (double)qrow[d4*4+1]*(double)kv.y;
    sd += (double)qrow[d4*4+2]*(double)kv.z;
    sd += (double)qrow[d4*4+3]*(double)kv.w;
  }
  double cs = sd; int ci = myidx;
  double sel0,sel1,sel2,sel3,sel4,sel5,sel6,sel7;
  int is0,is1,is2,is3,is4,is5,is6,is7;
  #pragma unroll
  for (int k8=0;k8<8;k8++){
    double bs = cs; int bi = ci;
    #pragma unroll
    for (int off=1; off<16; off<<=1){
      double os = __shfl_xor(bs, off, 16); int oi = __shfl_xor(bi, off, 16);
      bool bt = (os > bs) || (os==bs && oi < bi);
      bs = bt ? os : bs; bi = bt ? oi : bi;
    }
    if (ci==bi) cs = -1.0e300;
    if (k8==0){sel0=bs;is0=bi;} else if (k8==1){sel1=bs;is1=bi;}
    else if (k8==2){sel2=bs;is2=bi;} else if (k8==3){sel3=bs;is3=bi;}
    else if (k8==4){sel4=bs;is4=bi;} else if (k8==5){sel5=bs;is5=bi;}
    else if (k8==6){sel6=bs;is6=bi;} else {sel7=bs;is7=bi;}
  }
  if (ml==0){
    int grow = row0 + mrow;
    const double sc_inv = 0.08838834764831845;
    double mx = sel0;
    double e0 = exp((sel0-mx)*sc_inv), e1 = exp((sel1-mx)*sc_inv);
    double e2 = exp((sel2-mx)*sc_inv), e3 = exp((sel3-mx)*sc_inv);
    double e4 = exp((sel4-mx)*sc_inv), e5 = exp((sel5-mx)*sc_inv);
    double e6 = exp((sel6-mx)*sc_inv), e7 = exp((sel7-mx)*sc_inv);
    double sum = e0+e1+e2+e3+e4+e5+e6+e7;
    float w0=(float)(e0/sum),w1=(float)(e1/sum),w2=(float)(e2/sum),w3=(float)(e3/sum);
    float w4=(float)(e4/sum),w5=(float)(e5/sum),w6=(float)(e6/sum),w7=(float)(e7/sum);
    size_t o = (size_t)grow*8;
    tw[o+0]=w0; tw[o+1]=w1; tw[o+2]=w2; tw[o+3]=w3;
    tw[o+4]=w4; tw[o+5]=w5; tw[o+6]=w6; tw[o+7]=w7;
    tidx[o+0]=is0; tidx[o+1]=is1; tidx[o+2]=is2; tidx[o+3]=is3;
    tidx[o+4]=is4; tidx[o+5]=is5; tidx[o+6]=is6; tidx[o+7]=is7;
    out4[o+0]=w0; out4[o+1]=w1; out4[o+2]=w2; out4[o+3]=w3;
    out4[o+4]=w4; out4[o+5]=w5; out4[o+6]=w6; out4[o+7]=w7;
    out3[o+0]=(float)is0; out3[o+1]=(float)is1;
    out3[o+2]=(float)is2; out3[o+3]=(float)is3;
    out3[o+4]=(float)is4; out3[o+5]=(float)is5;
    out3[o+6]=(float)is6; out3[o+7]=(float)is7;
  }
}

// ============ scores fallback (round-7 f32 path, used if ws too small) ============
__global__ __launch_bounds__(512) void k_scores(const float* __restrict__ Qm, const float* __restrict__ Km,
                                                float* __restrict__ tw, int* __restrict__ tidx,
                                                float* __restrict__ out3, float* __restrict__ out4){
  __shared__ float Qt[32][132];
  __shared__ float Kt[512][20];
  __shared__ int candI[8][4][16];
  const int t = threadIdx.x;
  const int rg = t>>6, c = t&63;
  const int row0 = blockIdx.x*32;
  #pragma unroll
  for (int p=0;p<2;p++){
    int f = p*512+t; int r = f>>5, rq = f&31;
    float4 v = *(const float4*)&Qm[(size_t)(row0+r)*128 + rq*4];
    *(float4*)&Qt[r][rq*4] = v;
  }
  float ts[4][8]; int ti[4][8]; float thr[4];
  #pragma unroll
  for (int i=0;i<4;i++){
    thr[i] = -3.0e38f;
    #pragma unroll
    for (int k=0;k<8;k++){ ts[i][k] = -3.0e38f; ti[i][k] = 0x7fffffff; }
  }
  __syncthreads();
  #pragma unroll 1
  for (int nt=0;nt<64;nt++){
    const int nb = nt*512;
    float acc[4][8];
    #pragma unroll
    for (int i=0;i<4;i++){
      #pragma unroll
      for (int j=0;j<8;j++) acc[i][j]=0.f;
    }
    #pragma unroll 1
    for (int rc=0;rc<8;rc++){
      #pragma unroll
      for (int p=0;p<4;p++){
        int f = p*512+t; int nn = f>>2, rq = f&3;
        float4 v = *(const float4*)&Km[(size_t)(nb+nn)*128 + rc*16 + rq*4];
        *(float4*)&Kt[nn][rq*4] = v;
      }
      __syncthreads();
      #pragma unroll
      for (int r4=0;r4<4;r4++){
        float4 qv[4]; float4 kv[8];
        #pragma unroll
        for (int i=0;i<4;i++) qv[i] = *(const float4*)&Qt[rg*4+i][rc*16+r4*4];
        #pragma unroll
        for (int j=0;j<8;j++) kv[j] = *(const float4*)&Kt[c+64*j][r4*4];
        #pragma unroll
        for (int i=0;i<4;i++){
          #pragma unroll
          for (int j=0;j<8;j++){
            acc[i][j] += qv[i].x*kv[j].x;
            acc[i][j] += qv[i].y*kv[j].y;
            acc[i][j] += qv[i].z*kv[j].z;
            acc[i][j] += qv[i].w*kv[j].w;
          }
        }
      }
      __syncthreads();
    }
    #pragma unroll
    for (int i=0;i<4;i++){
      #pragma unroll
      for (int j=0;j<8;j++){
        float s = acc[i][j];
        if (s > thr[i]){
          int n = nb + c + 64*j;
          float mn = ts[i][0]; int mp = 0;
          #pragma unroll
          for (int k=1;k<8;k++){ bool lt = ts[i][k] < mn; mn = lt ? ts[i][k] : mn; mp = lt ? k : mp; }
          #pragma unroll
          for (int k=0;k<8;k++) if (k==mp){ ts[i][k] = s; ti[i][k] = n; }
          float nm = ts[i][0];
          #pragma unroll
          for (int k=1;k<8;k++) nm = fminf(nm, ts[i][k]);
          thr[i] = nm;
        }
      }
    }
  }
  #pragma unroll
  for (int i=0;i<4;i++){
    #pragma unroll 1
    for (int k=0;k<16;k++){
      float bs = ts[i][0]; int bi = ti[i][0];
      #pragma unroll
      for (int q=1;q<8;q++){
        bool bt = (ts[i][q] > bs) || (ts[i][q]==bs && ti[i][q] < bi);
        bs = bt ? ts[i][q] : bs; bi = bt ? ti[i][q] : bi;
      }
      #pragma unroll
      for (int off=1; off<64; off<<=1){
        float os = __shfl_xor(bs, off); int oi = __shfl_xor(bi, off);
        bool bt = (os > bs) || (os==bs && oi < bi);
        bs = bt ? os : bs; bi = bt ? oi : bi;
      }
      #pragma unroll
      for (int q=0;q<8;q++){
        if (ti[i][q]==bi){ ts[i][q] = -3.0e38f; ti[i][q] = 0x7fffffff; }
      }
      if (c==0) candI[rg][i][k] = bi;
    }
  }
  __syncthreads();
  const int ri = c>>4, rk = c&15;
  const int kidx = candI[rg][ri][rk];
  const float* kr = Km + (size_t)kidx*128;
  const float* qrow = &Qt[rg*4+ri][0];
  double sd = 0.0;
  #pragma unroll 1
  for (int d4=0; d4<32; d4++){
    float4 kv = *(const float4*)&kr[d4*4];
    sd += (double)qrow[d4*4+0]*(double)kv.x;
    sd += (double)qrow[d4*4+1]*(double)kv.y;
    sd += (double)qrow[d4*4+2]*(double)kv.z;
    sd += (double)qrow[d4*4+3]*(double)kv.w;
  }
  double cs = sd; int ci = kidx;
  double sel0,sel1,sel2,sel3,sel4,sel5,sel6,sel7;
  int is0,is1,is2,is3,is4,is5,is6,is7;
  #pragma unroll
  for (int k8=0;k8<8;k8++){
    double bs = cs; int bi = ci;
    #pragma unroll
    for (int off=1; off<16; off<<=1){
      double os = __shfl_xor(bs, off, 16); int oi = __shfl_xor(bi, off, 16);
      bool bt = (os > bs) || (os==bs && oi < bi);
      bs = bt ? os : bs; bi = bt ? oi : bi;
    }
    if (ci==bi) cs = -1.0e300;
    if (k8==0){sel0=bs;is0=bi;} else if (k8==1){sel1=bs;is1=bi;}
    else if (k8==2){sel2=bs;is2=bi;} else if (k8==3){sel3=bs;is3=bi;}
    else if (k8==4){sel4=bs;is4=bi;} else if (k8==5){sel5=bs;is5=bi;}
    else if (k8==6){sel6=bs;is6=bi;} else {sel7=bs;is7=bi;}
  }
  if (rk==0){
    int grow = row0 + rg*4 + ri;
    const double sc_inv = 0.08838834764831845;
    double mx = sel0;
    double e0 = exp((sel0-mx)*sc_inv), e1 = exp((sel1-mx)*sc_inv);
    double e2 = exp((sel2-mx)*sc_inv), e3 = exp((sel3-mx)*sc_inv);
    double e4 = exp((sel4-mx)*sc_inv), e5 = exp((sel5-mx)*sc_inv);
    double e6 = exp((sel6-mx)*sc_inv), e7 = exp((sel7-mx)*sc_inv);
    double sum = e0+e1+e2+e3+e4+e5+e6+e7;
    float w0=(float)(e0/sum),w1=(float)(e1/sum),w2=(float)(e2/sum),w3=(float)(e3/sum);
    float w4=(float)(e4/sum),w5=(float)(e5/sum),w6=(float)(e6/sum),w7=(float)(e7/sum);
    size_t o = (size_t)grow*8;
    tw[o+0]=w0; tw[o+1]=w1; tw[o+2]=w2; tw[o+3]=w3;
    tw[o+4]=w4; tw[o+5]=w5; tw[o+6]=w6; tw[o+7]=w7;
    tidx[o+0]=is0; tidx[o+1]=is1; tidx[o+2]=is2; tidx[o+3]=is3;
    tidx[o+4]=is4; tidx[o+5]=is5; tidx[o+6]=is6; tidx[o+7]=is7;
    out4[o+0]=w0; out4[o+1]=w1; out4[o+2]=w2; out4[o+3]=w3;
    out4[o+4]=w4; out4[o+5]=w5; out4[o+6]=w6; out4[o+7]=w7;
    out3[o+0]=(float)is0; out3[o+1]=(float)is1;
    out3[o+2]=(float)is2; out3[o+3]=(float)is3;
    out3[o+4]=(float)is4; out3[o+5]=(float)is5;
    out3[o+6]=(float)is6; out3[o+7]=(float)is7;
  }
}

// ============ gather + weighted sum -> output (float32) ============
__global__ __launch_bounds__(256) void k_gather(const float* __restrict__ V, const int* __restrict__ tidx,
                                                const float* __restrict__ tw, float* __restrict__ out0){
  int row = blockIdx.x; int t = threadIdx.x;
  __shared__ int li[8]; __shared__ float lw[8];
  if (t<8){
    int idx = tidx[(size_t)row*8+t];
    idx = idx < 0 ? 0 : (idx > (NK_-1) ? (NK_-1) : idx);
    li[t] = idx;
  } else if (t<16){
    float w = tw[(size_t)row*8 + t-8];
    w = fminf(fmaxf(w, 0.f), 1.f);
    lw[t-8] = w;
  }
  __syncthreads();
  float4 a = {0,0,0,0};
  #pragma unroll
  for (int k=0;k<8;k++){
    float4 v = ((const float4*)V)[(size_t)li[k]*256 + t];
    float w = lw[k];
    a.x += w*v.x; a.y += w*v.y; a.z += w*v.z; a.w += w*v.w;
  }
  ((float4*)(out0 + (size_t)row*1024))[t] = a;
}

extern "C" void kernel_launch(void* const* d_in, const int* in_sizes, int n_in,
                              void* d_out, int out_size, void* d_ws, size_t ws_size,
                              hipStream_t stream) {
  const float* x    = (const float*)d_in[0];
  const float* A    = (const float*)d_in[1];
  const float* Bm   = (const float*)d_in[2];
  const float* Wimp = (const float*)d_in[3];
  const float* Wr   = (const float*)d_in[4];
  const float* comp = (const float*)d_in[5];
  const float* Kmat = (const float*)d_in[6];
  const float* V    = (const float*)d_in[7];
  float* out = (float*)d_out;               // OUTPUT IS FLOAT32
  float* ws = (float*)d_ws;

  float* xB    = ws + OFF_XB;
  float* tp    = ws + OFF_TP;
  float* Apow  = ws + OFF_APOW;
  float* P     = ws + OFF_P;
  float* hproj = ws + OFF_HPROJ;
  float* logit = ws + OFF_LOGIT;
  float* imp   = ws + OFF_IMP;
  float* nw    = ws + OFF_NW;
  float* scb   = ws + OFF_SC;
  float* Qb    = ws + OFF_Q;        // aliases xB+tp (both dead by the time k_Q runs)
  int*   tidx  = (int*)(ws + OFF_TIDX);
  float* tw    = ws + OFF_TW;
  ushort* khi  = (ushort*)(ws + OFF_KHI);

  const bool use_mfma = (ws_size >= WS_NEED_MFMA);

  k_init_apow<<<32,256,0,stream>>>(A, Apow);
  if (use_mfma) k_split<<<4096,256,0,stream>>>(Kmat, khi);
  k_matstage<<<1 ,256,0,stream>>>(Apow, 2 ,1 ,1);
  k_matstage<<<2 ,256,0,stream>>>(Apow, 3 ,2 ,1);
  k_matstage<<<4 ,256,0,stream>>>(Apow, 5 ,4 ,1);
  k_matstage<<<8 ,256,0,stream>>>(Apow, 9 ,8 ,1);
  k_matstage<<<16,256,0,stream>>>(Apow, 17,16,1);
  k_matstage<<<32,256,0,stream>>>(Apow, 33,32,1);
  k_xbr<<<256,256,0,stream>>>(x, Bm, Wr, xB, tp);
  k_P<<<32,256,0,stream>>>(xB, Apow, P);
  k_scan<<<1,256,0,stream>>>(Apow, P, Wimp, hproj);
  k_implogit<<<8192,256,0,stream>>>(x, hproj, logit);
  k_softS<<<4,1024,0,stream>>>(logit, imp, out + O_IMP);
  k_nw<<<4,256,0,stream>>>(imp, tp, nw, out + O_NW);
  k_sc<<<128,256,0,stream>>>(nw, comp, scb);
  k_Q<<<256,256,0,stream>>>(x, scb, Qb);
  if (use_mfma)
    k_scores_mfma<<<256,512,0,stream>>>(Qb, khi, Kmat, tw, tidx, out + O_TIDX, out + O_TW);
  else
    k_scores<<<256,512,0,stream>>>(Qb, Kmat, tw, tidx, out + O_TIDX, out + O_TW);
  k_gather<<<8192,256,0,stream>>>(V, tidx, tw, out + O_OUT);
}